// Round 4
// baseline (1122.961 us; speedup 1.0000x reference)
//
#include <hip/hip_runtime.h>
#include <math.h>

#define B_ 128
#define T_ 8
#define P_ 49
#define H_ 64
#define N_ 343
#define THRESH 0.6f
#define NSLOPE 0.2f

// workspace layout (float offsets) — total 14,330,624 floats = 57.3 MB
#define OFF_WM1T 0
#define OFF_WM2T 8192
#define OFF_WG1T 12288
#define OFF_WG2T 16384
#define OFF_SPAT 20480          // B*128 spatial mean accumulator
#define OFF_SPEC 36864          // B*64 spectral mean accumulator
#define OFF_SSRC 45056          // B*N
#define OFF_SDST 88960          // B*N
#define OFF_SSORT 132864        // B*344 sorted ssrc
#define OFF_SUFD 176896         // B*344
#define OFF_PRED 220928         // B*344
#define OFF_NODE 264960         // B*N*64
#define OFF_SUFE 3074816        // B*344*64 (overlays what used to be Xfn)
#define OFF_PREE 5892864        // B*344*64
#define OFF_XW   8710912        // B*N*64
#define OFF_OUT1 11520768       // B*N*64
// Xfn/Xtn live in SUFE/PREE slots until k_spec completes (k_sort runs after)

__global__ void k_prep(const float* __restrict__ Wm1, const float* __restrict__ Wm2,
                       const float* __restrict__ Wg1, const float* __restrict__ Wg2,
                       float* __restrict__ Wm1T, float* __restrict__ Wm2T,
                       float* __restrict__ Wg1T, float* __restrict__ Wg2T) {
    int t = blockIdx.x * 256 + threadIdx.x;
    if (t < 8192) { int o = t >> 7, i = t & 127; Wm1T[i * 64 + o] = Wm1[t]; }
    if (t < 4096) {
        int r = t >> 6, c = t & 63;
        Wm2T[c * 64 + r] = Wm2[t];
        Wg1T[c * 64 + r] = Wg1[t];
        Wg2T[c * 64 + r] = Wg2[t];
    }
}

// one wave per (b,n): node MLP + normalized Xf/Xt rows
__global__ __launch_bounds__(256) void k_node(
    const float* __restrict__ reps, const float* __restrict__ Wm1T, const float* __restrict__ bm1,
    const float* __restrict__ Wm2T, const float* __restrict__ bm2,
    float* __restrict__ node, float* __restrict__ Xfn, float* __restrict__ Xtn)
{
    __shared__ float cat[4][128];
    __shared__ float h1s[4][64];
    int wv = threadIdx.x >> 6, ln = threadIdx.x & 63;
    int idx = blockIdx.x * 4 + wv;            // grid covers B*N exactly
    int b = idx / N_, n = idx - b * N_;
    int f = n / P_, p = n - f * P_;
    const float* xf = reps + (((size_t)b * T_ + f) * P_ + p) * H_;
    float vf = xf[ln], vt = xf[P_ * H_ + ln];
    cat[wv][ln] = vf; cat[wv][64 + ln] = vt;
    float nf = vf * vf, nt = vt * vt;
#pragma unroll
    for (int s = 1; s < 64; s <<= 1) { nf += __shfl_xor(nf, s); nt += __shfl_xor(nt, s); }
    nf = sqrtf(nf) + 1e-4f; nt = sqrtf(nt) + 1e-4f;
    size_t row = (size_t)idx * H_;
    Xfn[row + ln] = vf / nf;
    Xtn[row + ln] = vt / nt;
    __syncthreads();
    float a = bm1[ln];
#pragma unroll 8
    for (int i = 0; i < 128; i++) a += cat[wv][i] * Wm1T[i * 64 + ln];
    h1s[wv][ln] = fmaxf(a, 0.f);
    __syncthreads();
    float nd = bm2[ln];
#pragma unroll 8
    for (int o = 0; o < 64; o++) nd += h1s[wv][o] * Wm2T[o * 64 + ln];
    node[row + ln] = nd;
}

// h-sliced spectral kernel: 4 lanes per row (16 channels each), 64 rows per block.
// grid = B*6. Partial dots combined with shfl_xor(16/32).
#define JC 32
__global__ __launch_bounds__(256) void k_spec(
    const float* __restrict__ Xfn, const float* __restrict__ Xtn, const float* __restrict__ node,
    const float* __restrict__ Ws1, const float* __restrict__ bs1,
    const float* __restrict__ Ws2, const float* __restrict__ bs2,
    float* __restrict__ spectral)
{
    __shared__ __align__(16) float smem[8704];  // union: staging 6144 | aggL 4352 + h1L 4352
    float* shf = smem;            // [JC*64]
    float* sht = smem + 2048;
    float* shn = smem + 4096;
    int tid = threadIdx.x;
    int b = blockIdx.x / 6, ic = blockIdx.x % 6;
    int lane = tid & 63, wv = tid >> 6;
    int isub = lane & 15, slice = lane >> 4;
    int i = ic * 64 + wv * 16 + isub;
    bool valid = i < N_;
    int ri = valid ? i : 0;
    const float* xfb = Xfn + (size_t)b * N_ * 64;
    const float* xtb = Xtn + (size_t)b * N_ * 64;
    const float* ndb = node + (size_t)b * N_ * 64;

    float xfi[16], xti[16], agg[16];
    {
        const float4* pf = (const float4*)(xfb + (size_t)ri * 64 + slice * 16);
        const float4* pt = (const float4*)(xtb + (size_t)ri * 64 + slice * 16);
#pragma unroll
        for (int q = 0; q < 4; q++) {
            float4 a = pf[q], c = pt[q];
            xfi[4*q] = a.x; xfi[4*q+1] = a.y; xfi[4*q+2] = a.z; xfi[4*q+3] = a.w;
            xti[4*q] = c.x; xti[4*q+1] = c.y; xti[4*q+2] = c.z; xti[4*q+3] = c.w;
        }
    }
#pragma unroll
    for (int h = 0; h < 16; h++) agg[h] = 0.f;

    for (int c = 0; c < 11; ++c) {
        int j0 = c * JC, cnt = min(JC, N_ - j0);
        __syncthreads();
        for (int t = tid; t < cnt * 16; t += 256) {
            ((float4*)shf)[t] = ((const float4*)(xfb + (size_t)j0 * 64))[t];
            ((float4*)sht)[t] = ((const float4*)(xtb + (size_t)j0 * 64))[t];
            ((float4*)shn)[t] = ((const float4*)(ndb + (size_t)j0 * 64))[t];
        }
        __syncthreads();
        for (int jl = 0; jl < cnt; ++jl) {
            const float* fr = shf + jl * 64 + slice * 16;
            const float* tr = sht + jl * 64 + slice * 16;
            float sf = 0.f, st = 0.f;
#pragma unroll
            for (int h = 0; h < 16; h++) { sf += xfi[h] * fr[h]; st += xti[h] * tr[h]; }
            sf += __shfl_xor(sf, 16); sf += __shfl_xor(sf, 32);
            st += __shfl_xor(st, 16); st += __shfl_xor(st, 32);
            float s = fmaxf(sf, st);
            if (s > THRESH) {
                const float* nr = shn + jl * 64 + slice * 16;
#pragma unroll
                for (int h = 0; h < 16; h++) agg[h] += s * nr[h];
            }
        }
    }
    // MLP phase — reuse smem: aggL[64][68], h1L[64][68]
    __syncthreads();
    float* aggL = smem;
    float* h1L  = smem + 4352;
    int iL = wv * 16 + isub;
#pragma unroll
    for (int h = 0; h < 16; h++) aggL[iL * 68 + slice * 16 + h] = agg[h];
    __syncthreads();
    float h1v[16];
#pragma unroll
    for (int o = 0; o < 16; ++o) {
        int oo = slice * 16 + o;
        float a = bs1[oo];
        const float4* wr = (const float4*)(Ws1 + oo * 64);
        const float4* ar = (const float4*)(aggL + iL * 68);
#pragma unroll
        for (int h4 = 0; h4 < 16; ++h4) {
            float4 w = wr[h4], v = ar[h4];
            a += w.x * v.x + w.y * v.y + w.z * v.z + w.w * v.w;
        }
        h1v[o] = fmaxf(a, 0.f);
    }
    __syncthreads();
#pragma unroll
    for (int o = 0; o < 16; o++) h1L[iL * 68 + slice * 16 + o] = h1v[o];
    __syncthreads();
    float h2v[16];
#pragma unroll
    for (int h = 0; h < 16; ++h) {
        int hh = slice * 16 + h;
        float a = bs2[hh];
        const float4* wr = (const float4*)(Ws2 + hh * 64);
        const float4* hr = (const float4*)(h1L + iL * 68);
#pragma unroll
        for (int o4 = 0; o4 < 16; ++o4) {
            float4 w = wr[o4], v = hr[o4];
            a += w.x * v.x + w.y * v.y + w.z * v.z + w.w * v.w;
        }
        h2v[h] = valid ? a : 0.f;
    }
#pragma unroll
    for (int h = 0; h < 16; ++h) {
        float a = h2v[h];
        a += __shfl_xor(a, 1); a += __shfl_xor(a, 2);
        a += __shfl_xor(a, 4); a += __shfl_xor(a, 8);
        if (isub == 0) atomicAdd(&spectral[b * 64 + slice * 16 + h], a);
    }
}

// one wave per (b,n): xw = x @ WgT, plus attention scalars
__global__ __launch_bounds__(256) void k_xw(
    const float* __restrict__ x, const float* __restrict__ WgT,
    const float* __restrict__ as_, const float* __restrict__ ad_,
    float* __restrict__ xw, float* __restrict__ ssrc, float* __restrict__ sdst)
{
    __shared__ float xs[4][64];
    int wv = threadIdx.x >> 6, ln = threadIdx.x & 63;
    int idx = blockIdx.x * 4 + wv;
    size_t row = (size_t)idx * H_;
    xs[wv][ln] = x[row + ln];
    __syncthreads();
    float a = 0.f;
#pragma unroll 8
    for (int h = 0; h < 64; h++) a += xs[wv][h] * WgT[h * 64 + ln];
    xw[row + ln] = a;
    float ps = a * as_[ln], pd = a * ad_[ln];
#pragma unroll
    for (int s = 1; s < 64; s <<= 1) { ps += __shfl_xor(ps, s); pd += __shfl_xor(pd, s); }
    if (ln == 0) { ssrc[idx] = ps; sdst[idx] = pd; }
}

// per-batch: bitonic sort of s_src + suffix sums of exp(s)·xw and prefix sums of exp(.2s)·xw
__global__ __launch_bounds__(256) void k_sort(
    const float* __restrict__ ssrc, const float* __restrict__ xw,
    float* __restrict__ ssort, float* __restrict__ SufE, float* __restrict__ PreE,
    float* __restrict__ SufD, float* __restrict__ PreD)
{
    __shared__ float sv[512];
    __shared__ int   si[512];
    int tid = threadIdx.x, b = blockIdx.x;
    for (int q = tid; q < 512; q += 256) {
        sv[q] = (q < N_) ? ssrc[b * N_ + q] : 3.0e38f;
        si[q] = q;
    }
    __syncthreads();
    for (int k = 2; k <= 512; k <<= 1)
        for (int j = k >> 1; j > 0; j >>= 1) {
            for (int e = tid; e < 512; e += 256) {
                int l = e ^ j;
                if (l > e) {
                    float a = sv[e], c = sv[l];
                    bool up = ((e & k) == 0);
                    if (up ? (a > c) : (a < c)) {
                        sv[e] = c; sv[l] = a;
                        int t = si[e]; si[e] = si[l]; si[l] = t;
                    }
                }
            }
            __syncthreads();
        }
    int wv = tid >> 6, h = tid & 63;
    size_t base = (size_t)b * 344;
    if (wv == 0) {
        SufE[(base + 343) * 64 + h] = 0.f;
        if (h == 0) SufD[base + 343] = 0.f;
        float r = 0.f, rd = 0.f;
        for (int q = 342; q >= 0; --q) {
            float e = __expf(sv[q]);
            r += e * xw[((size_t)b * N_ + si[q]) * 64 + h];
            rd += e;
            SufE[(base + q) * 64 + h] = r;
            if (h == 0) SufD[base + q] = rd;
        }
    } else if (wv == 1) {
        float r = 0.f, rd = 0.f;
        for (int q = 0; q < N_; ++q) {
            PreE[(base + q) * 64 + h] = r;
            if (h == 0) PreD[base + q] = rd;
            float e = __expf(0.2f * sv[q]);
            r += e * xw[((size_t)b * N_ + si[q]) * 64 + h];
            rd += e;
        }
        PreE[(base + 343) * 64 + h] = r;
        if (h == 0) PreD[base + 343] = rd;
    } else if (wv == 2) {
        for (int q = h; q < N_; q += 64) ssort[base + q] = sv[q];
    }
}

// wave per (b,i): exact GAT row via sorted prefix/suffix sums + head mix + l2norm + relu
template <int STORE>
__global__ __launch_bounds__(256) void k_gatfin(
    const float* __restrict__ sdst, const float* __restrict__ ssort,
    const float* __restrict__ SufE, const float* __restrict__ PreE,
    const float* __restrict__ SufD, const float* __restrict__ PreD,
    const float* __restrict__ bg, const float* __restrict__ hw, const float* __restrict__ hb,
    float* __restrict__ outrows, float* __restrict__ spatial, int soff)
{
    int wv = threadIdx.x >> 6, ln = threadIdx.x & 63;
    int idx = blockIdx.x * 4 + wv;           // grid covers B*N exactly
    int b = idx / N_;
    float di = sdst[idx];
    const float* ss = ssort + (size_t)b * 344;
    float key = -di;
    int lo = 0, hi = N_;
    while (lo < hi) { int mid = (lo + hi) >> 1; if (ss[mid] >= key) hi = mid; else lo = mid + 1; }
    int p = lo;
    float ed = __expf(di), e2 = __expf(0.2f * di);
    size_t base = (size_t)b * 344 + p;
    float acc = ed * SufE[base * 64 + ln] + e2 * PreE[base * 64 + ln];
    float den = ed * SufD[base] + e2 * PreD[base];
    float g = acc / den + bg[ln];
    // head mix: y[k,e] = sum_d g[k*16+d]*hw[(k*16+e)*16+d] + hb
    int k = ln >> 4;
    float y = hb[ln];
    const float* hwr = hw + ln * 16;
#pragma unroll
    for (int d = 0; d < 16; ++d) y += hwr[d] * __shfl(g, (k << 4) | d);
    float ssum = y * y;
#pragma unroll
    for (int s = 1; s < 64; s <<= 1) ssum += __shfl_xor(ssum, s);
    float rr = 1.f / fmaxf(sqrtf(ssum), 1e-12f);
    y = fmaxf(y * rr, 0.f);
    if (STORE) outrows[(size_t)idx * 64 + ln] = y;
    atomicAdd(&spatial[b * 128 + soff + ln], y);
}

__global__ void k_final(const float* __restrict__ spatial, const float* __restrict__ spectral,
                        const float* __restrict__ Wf, const float* __restrict__ bf_,
                        float* __restrict__ out)
{
    int b = blockIdx.x, ln = threadIdx.x;  // 64 threads
    float inv = 1.f / (float)N_;
    float e0 = spatial[b * 128 + ln] * inv;
    float e1 = spatial[b * 128 + 64 + ln] * inv;
    float e2 = spectral[b * 64 + ln] * inv;
#pragma unroll
    for (int c = 0; c < 2; c++) {
        float a = e0 * Wf[c * 192 + ln] + e1 * Wf[c * 192 + 64 + ln] + e2 * Wf[c * 192 + 128 + ln];
#pragma unroll
        for (int s = 1; s < 64; s <<= 1) a += __shfl_xor(a, s);
        if (ln == 0) out[b * 2 + c] = a + bf_[c];
    }
}

extern "C" void kernel_launch(void* const* d_in, const int* in_sizes, int n_in,
                              void* d_out, int out_size, void* d_ws, size_t ws_size,
                              hipStream_t stream)
{
    const float* reps = (const float*)d_in[0];
    const float* Wm1  = (const float*)d_in[1];
    const float* bm1  = (const float*)d_in[2];
    const float* Wm2  = (const float*)d_in[3];
    const float* bm2  = (const float*)d_in[4];
    const float* Wg1  = (const float*)d_in[5];
    const float* a1s  = (const float*)d_in[6];
    const float* a1d  = (const float*)d_in[7];
    const float* bg1  = (const float*)d_in[8];
    const float* hw1  = (const float*)d_in[9];
    const float* hb1  = (const float*)d_in[10];
    const float* Wg2  = (const float*)d_in[11];
    const float* a2s  = (const float*)d_in[12];
    const float* a2d  = (const float*)d_in[13];
    const float* bg2  = (const float*)d_in[14];
    const float* hw3  = (const float*)d_in[15];
    const float* hb3  = (const float*)d_in[16];
    const float* Ws1  = (const float*)d_in[17];
    const float* bs1  = (const float*)d_in[18];
    const float* Ws2  = (const float*)d_in[19];
    const float* bs2  = (const float*)d_in[20];
    const float* Wf   = (const float*)d_in[21];
    const float* bf_  = (const float*)d_in[22];

    float* ws = (float*)d_ws;
    float* Wm1T = ws + OFF_WM1T;
    float* Wm2T = ws + OFF_WM2T;
    float* Wg1T = ws + OFF_WG1T;
    float* Wg2T = ws + OFF_WG2T;
    float* spat = ws + OFF_SPAT;
    float* spec = ws + OFF_SPEC;
    float* ssrc = ws + OFF_SSRC;
    float* sdst = ws + OFF_SDST;
    float* ssort= ws + OFF_SSORT;
    float* SufD = ws + OFF_SUFD;
    float* PreD = ws + OFF_PRED;
    float* node = ws + OFF_NODE;
    float* SufE = ws + OFF_SUFE;   // doubles as Xfn until k_spec is done
    float* PreE = ws + OFF_PREE;   // doubles as Xtn until k_spec is done
    float* xwb  = ws + OFF_XW;
    float* out1 = ws + OFF_OUT1;
    float* Xfn = SufE;
    float* Xtn = PreE;

    hipMemsetAsync(spat, 0, (16384 + 8192) * sizeof(float), stream);
    k_prep<<<32, 256, 0, stream>>>(Wm1, Wm2, Wg1, Wg2, Wm1T, Wm2T, Wg1T, Wg2T);
    k_node<<<(B_ * N_) / 4, 256, 0, stream>>>(reps, Wm1T, bm1, Wm2T, bm2, node, Xfn, Xtn);
    k_spec<<<B_ * 6, 256, 0, stream>>>(Xfn, Xtn, node, Ws1, bs1, Ws2, bs2, spec);
    // ---- GAT layer 1 ----
    k_xw<<<(B_ * N_) / 4, 256, 0, stream>>>(node, Wg1T, a1s, a1d, xwb, ssrc, sdst);
    k_sort<<<B_, 256, 0, stream>>>(ssrc, xwb, ssort, SufE, PreE, SufD, PreD);
    k_gatfin<1><<<(B_ * N_) / 4, 256, 0, stream>>>(sdst, ssort, SufE, PreE, SufD, PreD,
                                                   bg1, hw1, hb1, out1, spat, 0);
    // ---- GAT layer 2 ----
    k_xw<<<(B_ * N_) / 4, 256, 0, stream>>>(out1, Wg2T, a2s, a2d, xwb, ssrc, sdst);
    k_sort<<<B_, 256, 0, stream>>>(ssrc, xwb, ssort, SufE, PreE, SufD, PreD);
    k_gatfin<0><<<(B_ * N_) / 4, 256, 0, stream>>>(sdst, ssort, SufE, PreE, SufD, PreD,
                                                   bg2, hw3, hb3, nullptr, spat, 64);
    k_final<<<B_, 64, 0, stream>>>(spat, spec, Wf, bf_, (float*)d_out);
}

// Round 5
// 649.529 us; speedup vs baseline: 1.7289x; 1.7289x over previous
//
#include <hip/hip_runtime.h>
#include <math.h>

#define B_ 128
#define T_ 8
#define P_ 49
#define H_ 64
#define N_ 343
#define THRESH 0.6f
#define NSLOPE 0.2f

// workspace layout (float offsets) — total 14,338,816 floats = 57.4 MB
#define OFF_WM1T 0
#define OFF_WM2T 8192
#define OFF_WG1T 12288
#define OFF_WG2T 16384
#define OFF_WS1T 20480
#define OFF_WS2T 24576
#define OFF_SPAT 28672          // B*128 spatial mean accumulator
#define OFF_SPEC 45056          // B*64 spectral mean accumulator
#define OFF_SSRC 53248          // B*N
#define OFF_SDST 97152          // B*N
#define OFF_SSORT 141056        // B*344
#define OFF_SUFD 185088         // B*344
#define OFF_PRED 229120         // B*344
#define OFF_NODE 273152         // B*N*64
#define OFF_SUFE 3083008        // B*344*64 (overlays Xfn until k_sim done)
#define OFF_PREE 5901056        // B*344*64 (overlays Xtn until k_sim done)
#define OFF_XW   8719104        // B*N*64 (overlays agg: k_smlp reads agg before k_xw writes)
#define OFF_OUT1 11528960       // B*N*64

__global__ void k_prep(const float* __restrict__ Wm1, const float* __restrict__ Wm2,
                       const float* __restrict__ Wg1, const float* __restrict__ Wg2,
                       const float* __restrict__ Ws1, const float* __restrict__ Ws2,
                       float* __restrict__ Wm1T, float* __restrict__ Wm2T,
                       float* __restrict__ Wg1T, float* __restrict__ Wg2T,
                       float* __restrict__ Ws1T, float* __restrict__ Ws2T) {
    int t = blockIdx.x * 256 + threadIdx.x;
    if (t < 8192) { int o = t >> 7, i = t & 127; Wm1T[i * 64 + o] = Wm1[t]; }
    if (t < 4096) {
        int r = t >> 6, c = t & 63;
        Wm2T[c * 64 + r] = Wm2[t];
        Wg1T[c * 64 + r] = Wg1[t];
        Wg2T[c * 64 + r] = Wg2[t];
        Ws1T[c * 64 + r] = Ws1[t];   // Ws1T[h][o] = Ws1[o][h]
        Ws2T[c * 64 + r] = Ws2[t];   // Ws2T[o][h] = Ws2[h][o]
    }
}

// one wave per (b,n): node MLP + normalized Xf/Xt rows
__global__ __launch_bounds__(256) void k_node(
    const float* __restrict__ reps, const float* __restrict__ Wm1T, const float* __restrict__ bm1,
    const float* __restrict__ Wm2T, const float* __restrict__ bm2,
    float* __restrict__ node, float* __restrict__ Xfn, float* __restrict__ Xtn)
{
    __shared__ float cat[4][128];
    __shared__ float h1s[4][64];
    int wv = threadIdx.x >> 6, ln = threadIdx.x & 63;
    int idx = blockIdx.x * 4 + wv;            // grid covers B*N exactly
    int b = idx / N_, n = idx - b * N_;
    int f = n / P_, p = n - f * P_;
    const float* xf = reps + (((size_t)b * T_ + f) * P_ + p) * H_;
    float vf = xf[ln], vt = xf[P_ * H_ + ln];
    cat[wv][ln] = vf; cat[wv][64 + ln] = vt;
    float nf = vf * vf, nt = vt * vt;
#pragma unroll
    for (int s = 1; s < 64; s <<= 1) { nf += __shfl_xor(nf, s); nt += __shfl_xor(nt, s); }
    nf = sqrtf(nf) + 1e-4f; nt = sqrtf(nt) + 1e-4f;
    size_t row = (size_t)idx * H_;
    Xfn[row + ln] = vf / nf;
    Xtn[row + ln] = vt / nt;
    __syncthreads();
    float a = bm1[ln];
#pragma unroll 8
    for (int i = 0; i < 128; i++) a += cat[wv][i] * Wm1T[i * 64 + ln];
    h1s[wv][ln] = fmaxf(a, 0.f);
    __syncthreads();
    float nd = bm2[ln];
#pragma unroll 8
    for (int o = 0; o < 64; o++) nd += h1s[wv][o] * Wm2T[o * 64 + ln];
    node[row + ln] = nd;
}

// similarity + thresholded aggregation only. Thread = (i, 16-channel slice).
// Block: 512 thr = 8 waves; wave = 16 i's x 4 slices (lane = isub*4 + slice).
// grid = B*3 (i-chunks of 128). Low register footprint; no MLP here.
#define JC 32
__global__ __launch_bounds__(512, 4) void k_sim(
    const float* __restrict__ Xfn, const float* __restrict__ Xtn,
    const float* __restrict__ node, float* __restrict__ aggO)
{
    __shared__ __align__(16) float shf[JC * 64];
    __shared__ __align__(16) float sht[JC * 64];
    int tid = threadIdx.x;
    int b = blockIdx.x / 3, ic = blockIdx.x % 3;
    int wv = tid >> 6, lane = tid & 63;
    int isub = lane >> 2, slice = lane & 3;
    int i = ic * 128 + wv * 16 + isub;
    bool valid = i < N_;
    int ri = valid ? i : 0;
    const float* xfb = Xfn + (size_t)b * N_ * 64;
    const float* xtb = Xtn + (size_t)b * N_ * 64;
    const float* ndb = node + (size_t)b * N_ * 64;

    float xfi[16], xti[16], agg[16];
    {
        const float4* pf = (const float4*)(xfb + (size_t)ri * 64 + slice * 16);
        const float4* pt = (const float4*)(xtb + (size_t)ri * 64 + slice * 16);
#pragma unroll
        for (int q = 0; q < 4; q++) {
            float4 a = pf[q], c = pt[q];
            xfi[4*q] = a.x; xfi[4*q+1] = a.y; xfi[4*q+2] = a.z; xfi[4*q+3] = a.w;
            xti[4*q] = c.x; xti[4*q+1] = c.y; xti[4*q+2] = c.z; xti[4*q+3] = c.w;
        }
    }
#pragma unroll
    for (int h = 0; h < 16; h++) agg[h] = 0.f;

#pragma unroll 1
    for (int c = 0; c < 11; ++c) {
        int j0 = c * JC, cnt = min(JC, N_ - j0);
        __syncthreads();
        for (int t = tid; t < cnt * 16; t += 512) {
            ((float4*)shf)[t] = ((const float4*)(xfb + (size_t)j0 * 64))[t];
            ((float4*)sht)[t] = ((const float4*)(xtb + (size_t)j0 * 64))[t];
        }
        __syncthreads();
        for (int jl = 0; jl < cnt; ++jl) {
            const float4* fr = (const float4*)(shf + jl * 64 + slice * 16);
            const float4* tr = (const float4*)(sht + jl * 64 + slice * 16);
            float sf = 0.f, st = 0.f;
#pragma unroll
            for (int q = 0; q < 4; q++) {
                float4 fv = fr[q], tv = tr[q];
                sf += xfi[4*q] * fv.x + xfi[4*q+1] * fv.y + xfi[4*q+2] * fv.z + xfi[4*q+3] * fv.w;
                st += xti[4*q] * tv.x + xti[4*q+1] * tv.y + xti[4*q+2] * tv.z + xti[4*q+3] * tv.w;
            }
            sf += __shfl_xor(sf, 1); sf += __shfl_xor(sf, 2);
            st += __shfl_xor(st, 1); st += __shfl_xor(st, 2);
            float s = fmaxf(sf, st);
            if (s > THRESH) {
                const float4* nr = (const float4*)(ndb + (size_t)(j0 + jl) * 64 + slice * 16);
#pragma unroll
                for (int q = 0; q < 4; q++) {
                    float4 nv = nr[q];
                    agg[4*q]   += s * nv.x; agg[4*q+1] += s * nv.y;
                    agg[4*q+2] += s * nv.z; agg[4*q+3] += s * nv.w;
                }
            }
        }
    }
    if (valid) {
        float4* ao = (float4*)(aggO + (size_t)(b * N_ + i) * 64 + slice * 16);
#pragma unroll
        for (int q = 0; q < 4; q++)
            ao[q] = make_float4(agg[4*q], agg[4*q+1], agg[4*q+2], agg[4*q+3]);
    }
}

// spectral MLP: wave per row (k_xw pattern), atomic mean accumulate
__global__ __launch_bounds__(256) void k_smlp(
    const float* __restrict__ aggI, const float* __restrict__ Ws1T, const float* __restrict__ bs1,
    const float* __restrict__ Ws2T, const float* __restrict__ bs2, float* __restrict__ spectral)
{
    __shared__ float xs[4][64];
    __shared__ float h1s[4][64];
    int wv = threadIdx.x >> 6, ln = threadIdx.x & 63;
    int idx = blockIdx.x * 4 + wv;
    int b = idx / N_;
    xs[wv][ln] = aggI[(size_t)idx * 64 + ln];
    __syncthreads();
    float a = bs1[ln];
#pragma unroll 8
    for (int h = 0; h < 64; h++) a += xs[wv][h] * Ws1T[h * 64 + ln];
    h1s[wv][ln] = fmaxf(a, 0.f);
    __syncthreads();
    float a2 = bs2[ln];
#pragma unroll 8
    for (int o = 0; o < 64; o++) a2 += h1s[wv][o] * Ws2T[o * 64 + ln];
    atomicAdd(&spectral[b * 64 + ln], a2);
}

// one wave per (b,n): xw = x @ WgT, plus attention scalars
__global__ __launch_bounds__(256) void k_xw(
    const float* __restrict__ x, const float* __restrict__ WgT,
    const float* __restrict__ as_, const float* __restrict__ ad_,
    float* __restrict__ xw, float* __restrict__ ssrc, float* __restrict__ sdst)
{
    __shared__ float xs[4][64];
    int wv = threadIdx.x >> 6, ln = threadIdx.x & 63;
    int idx = blockIdx.x * 4 + wv;
    size_t row = (size_t)idx * H_;
    xs[wv][ln] = x[row + ln];
    __syncthreads();
    float a = 0.f;
#pragma unroll 8
    for (int h = 0; h < 64; h++) a += xs[wv][h] * WgT[h * 64 + ln];
    xw[row + ln] = a;
    float ps = a * as_[ln], pd = a * ad_[ln];
#pragma unroll
    for (int s = 1; s < 64; s <<= 1) { ps += __shfl_xor(ps, s); pd += __shfl_xor(pd, s); }
    if (ln == 0) { ssrc[idx] = ps; sdst[idx] = pd; }
}

// per-batch: bitonic sort + PARALLEL segmented suffix/prefix weighted scans.
// 1024 thr = 16 segment-waves x 64 h-lanes.
#define NSEG 16
#define SEGSZ 22
__global__ __launch_bounds__(1024) void k_sortscan(
    const float* __restrict__ ssrc, const float* __restrict__ xw,
    float* __restrict__ ssort, float* __restrict__ SufE, float* __restrict__ PreE,
    float* __restrict__ SufD, float* __restrict__ PreD)
{
    __shared__ float sv[512];
    __shared__ int   si[512];
    __shared__ float w1L[344], w2L[344];
    __shared__ float segT[NSEG * 64];
    __shared__ float segD[NSEG];
    int tid = threadIdx.x, b = blockIdx.x;
    for (int q = tid; q < 512; q += 1024) {
        sv[q] = (q < N_) ? ssrc[b * N_ + q] : 3.0e38f;
        si[q] = q;
    }
    __syncthreads();
    for (int k = 2; k <= 512; k <<= 1)
        for (int j = k >> 1; j > 0; j >>= 1) {
            for (int e = tid; e < 512; e += 1024) {
                int l = e ^ j;
                if (l > e) {
                    float a = sv[e], c = sv[l];
                    bool up = ((e & k) == 0);
                    if (up ? (a > c) : (a < c)) {
                        sv[e] = c; sv[l] = a;
                        int t = si[e]; si[e] = si[l]; si[l] = t;
                    }
                }
            }
            __syncthreads();
        }
    if (tid < N_) {
        float v = sv[tid];
        w1L[tid] = __expf(v);
        w2L[tid] = __expf(0.2f * v);
        ssort[(size_t)b * 344 + tid] = v;
    }
    __syncthreads();
    int t = tid >> 6, h = tid & 63;
    int qs = t * SEGSZ, qe = min(qs + SEGSZ, N_);
    const float* xwb = xw + (size_t)b * N_ * 64;
    size_t base = (size_t)b * 344;
    // ---- suffix sums with w1 = exp(s) ----
    float r = 0.f, rd = 0.f;
    for (int q = qe - 1; q >= qs; --q) {
        float w = w1L[q];
        r += w * xwb[(size_t)si[q] * 64 + h];
        rd += w;
    }
    segT[t * 64 + h] = r; if (h == 0) segD[t] = rd;
    __syncthreads();
    float bsum = 0.f, bden = 0.f;
    for (int t2 = t + 1; t2 < NSEG; ++t2) { bsum += segT[t2 * 64 + h]; bden += segD[t2]; }
    r = bsum; rd = bden;
    for (int q = qe - 1; q >= qs; --q) {
        float w = w1L[q];
        r += w * xwb[(size_t)si[q] * 64 + h];
        rd += w;
        SufE[(base + q) * 64 + h] = r;
        if (h == 0) SufD[base + q] = rd;
    }
    if (t == 0) { SufE[(base + 343) * 64 + h] = 0.f; if (h == 0) SufD[base + 343] = 0.f; }
    __syncthreads();
    // ---- prefix sums with w2 = exp(0.2 s) ----
    r = 0.f; rd = 0.f;
    for (int q = qs; q < qe; ++q) {
        float w = w2L[q];
        r += w * xwb[(size_t)si[q] * 64 + h];
        rd += w;
    }
    segT[t * 64 + h] = r; if (h == 0) segD[t] = rd;
    __syncthreads();
    bsum = 0.f; bden = 0.f;
    for (int t2 = 0; t2 < t; ++t2) { bsum += segT[t2 * 64 + h]; bden += segD[t2]; }
    r = bsum; rd = bden;
    for (int q = qs; q < qe; ++q) {
        PreE[(base + q) * 64 + h] = r;
        if (h == 0) PreD[base + q] = rd;
        float w = w2L[q];
        r += w * xwb[(size_t)si[q] * 64 + h];
        rd += w;
    }
    if (t == NSEG - 1) { PreE[(base + 343) * 64 + h] = r; if (h == 0) PreD[base + 343] = rd; }
}

// wave per (b,i): exact GAT row via sorted prefix/suffix sums + head mix + l2norm + relu
template <int STORE>
__global__ __launch_bounds__(256) void k_gatfin(
    const float* __restrict__ sdst, const float* __restrict__ ssort,
    const float* __restrict__ SufE, const float* __restrict__ PreE,
    const float* __restrict__ SufD, const float* __restrict__ PreD,
    const float* __restrict__ bg, const float* __restrict__ hw, const float* __restrict__ hb,
    float* __restrict__ outrows, float* __restrict__ spatial, int soff)
{
    int wv = threadIdx.x >> 6, ln = threadIdx.x & 63;
    int idx = blockIdx.x * 4 + wv;           // grid covers B*N exactly
    int b = idx / N_;
    float di = sdst[idx];
    const float* ss = ssort + (size_t)b * 344;
    float key = -di;
    int lo = 0, hi = N_;
    while (lo < hi) { int mid = (lo + hi) >> 1; if (ss[mid] >= key) hi = mid; else lo = mid + 1; }
    int p = lo;
    float ed = __expf(di), e2 = __expf(0.2f * di);
    size_t base = (size_t)b * 344 + p;
    float acc = ed * SufE[base * 64 + ln] + e2 * PreE[base * 64 + ln];
    float den = ed * SufD[base] + e2 * PreD[base];
    float g = acc / den + bg[ln];
    // head mix: y[k,e] = sum_d g[k*16+d]*hw[(k*16+e)*16+d] + hb
    int k = ln >> 4;
    float y = hb[ln];
    const float* hwr = hw + ln * 16;
#pragma unroll
    for (int d = 0; d < 16; ++d) y += hwr[d] * __shfl(g, (k << 4) | d);
    float ssum = y * y;
#pragma unroll
    for (int s = 1; s < 64; s <<= 1) ssum += __shfl_xor(ssum, s);
    float rr = 1.f / fmaxf(sqrtf(ssum), 1e-12f);
    y = fmaxf(y * rr, 0.f);
    if (STORE) outrows[(size_t)idx * 64 + ln] = y;
    atomicAdd(&spatial[b * 128 + soff + ln], y);
}

__global__ void k_final(const float* __restrict__ spatial, const float* __restrict__ spectral,
                        const float* __restrict__ Wf, const float* __restrict__ bf_,
                        float* __restrict__ out)
{
    int b = blockIdx.x, ln = threadIdx.x;  // 64 threads
    float inv = 1.f / (float)N_;
    float e0 = spatial[b * 128 + ln] * inv;
    float e1 = spatial[b * 128 + 64 + ln] * inv;
    float e2 = spectral[b * 64 + ln] * inv;
#pragma unroll
    for (int c = 0; c < 2; c++) {
        float a = e0 * Wf[c * 192 + ln] + e1 * Wf[c * 192 + 64 + ln] + e2 * Wf[c * 192 + 128 + ln];
#pragma unroll
        for (int s = 1; s < 64; s <<= 1) a += __shfl_xor(a, s);
        if (ln == 0) out[b * 2 + c] = a + bf_[c];
    }
}

extern "C" void kernel_launch(void* const* d_in, const int* in_sizes, int n_in,
                              void* d_out, int out_size, void* d_ws, size_t ws_size,
                              hipStream_t stream)
{
    const float* reps = (const float*)d_in[0];
    const float* Wm1  = (const float*)d_in[1];
    const float* bm1  = (const float*)d_in[2];
    const float* Wm2  = (const float*)d_in[3];
    const float* bm2  = (const float*)d_in[4];
    const float* Wg1  = (const float*)d_in[5];
    const float* a1s  = (const float*)d_in[6];
    const float* a1d  = (const float*)d_in[7];
    const float* bg1  = (const float*)d_in[8];
    const float* hw1  = (const float*)d_in[9];
    const float* hb1  = (const float*)d_in[10];
    const float* Wg2  = (const float*)d_in[11];
    const float* a2s  = (const float*)d_in[12];
    const float* a2d  = (const float*)d_in[13];
    const float* bg2  = (const float*)d_in[14];
    const float* hw3  = (const float*)d_in[15];
    const float* hb3  = (const float*)d_in[16];
    const float* Ws1  = (const float*)d_in[17];
    const float* bs1  = (const float*)d_in[18];
    const float* Ws2  = (const float*)d_in[19];
    const float* bs2  = (const float*)d_in[20];
    const float* Wf   = (const float*)d_in[21];
    const float* bf_  = (const float*)d_in[22];

    float* ws = (float*)d_ws;
    float* Wm1T = ws + OFF_WM1T;
    float* Wm2T = ws + OFF_WM2T;
    float* Wg1T = ws + OFF_WG1T;
    float* Wg2T = ws + OFF_WG2T;
    float* Ws1T = ws + OFF_WS1T;
    float* Ws2T = ws + OFF_WS2T;
    float* spat = ws + OFF_SPAT;
    float* spec = ws + OFF_SPEC;
    float* ssrc = ws + OFF_SSRC;
    float* sdst = ws + OFF_SDST;
    float* ssort= ws + OFF_SSORT;
    float* SufD = ws + OFF_SUFD;
    float* PreD = ws + OFF_PRED;
    float* node = ws + OFF_NODE;
    float* SufE = ws + OFF_SUFE;   // doubles as Xfn until k_sim is done
    float* PreE = ws + OFF_PREE;   // doubles as Xtn until k_sim is done
    float* xwb  = ws + OFF_XW;     // doubles as agg (k_smlp reads before k_xw writes)
    float* out1 = ws + OFF_OUT1;
    float* Xfn = SufE;
    float* Xtn = PreE;
    float* agg = xwb;

    hipMemsetAsync(spat, 0, (16384 + 8192) * sizeof(float), stream);
    k_prep<<<32, 256, 0, stream>>>(Wm1, Wm2, Wg1, Wg2, Ws1, Ws2,
                                   Wm1T, Wm2T, Wg1T, Wg2T, Ws1T, Ws2T);
    k_node<<<(B_ * N_) / 4, 256, 0, stream>>>(reps, Wm1T, bm1, Wm2T, bm2, node, Xfn, Xtn);
    k_sim<<<B_ * 3, 512, 0, stream>>>(Xfn, Xtn, node, agg);
    k_smlp<<<(B_ * N_) / 4, 256, 0, stream>>>(agg, Ws1T, bs1, Ws2T, bs2, spec);
    // ---- GAT layer 1 ----
    k_xw<<<(B_ * N_) / 4, 256, 0, stream>>>(node, Wg1T, a1s, a1d, xwb, ssrc, sdst);
    k_sortscan<<<B_, 1024, 0, stream>>>(ssrc, xwb, ssort, SufE, PreE, SufD, PreD);
    k_gatfin<1><<<(B_ * N_) / 4, 256, 0, stream>>>(sdst, ssort, SufE, PreE, SufD, PreD,
                                                   bg1, hw1, hb1, out1, spat, 0);
    // ---- GAT layer 2 ----
    k_xw<<<(B_ * N_) / 4, 256, 0, stream>>>(out1, Wg2T, a2s, a2d, xwb, ssrc, sdst);
    k_sortscan<<<B_, 1024, 0, stream>>>(ssrc, xwb, ssort, SufE, PreE, SufD, PreD);
    k_gatfin<0><<<(B_ * N_) / 4, 256, 0, stream>>>(sdst, ssort, SufE, PreE, SufD, PreD,
                                                   bg2, hw3, hb3, nullptr, spat, 64);
    k_final<<<B_, 64, 0, stream>>>(spat, spec, Wf, bf_, (float*)d_out);
}

// Round 6
// 489.914 us; speedup vs baseline: 2.2922x; 1.3258x over previous
//
#include <hip/hip_runtime.h>
#include <math.h>

#define B_ 128
#define T_ 8
#define P_ 49
#define H_ 64
#define N_ 343
#define THRESH 0.6f
#define NSLOPE 0.2f

typedef float  f32x4  __attribute__((ext_vector_type(4)));
typedef short  s16x4  __attribute__((ext_vector_type(4)));
typedef short  s16x8  __attribute__((ext_vector_type(8)));

// workspace layout (float offsets) — total 14,338,816 floats = 57.4 MB
#define OFF_WM1T 0
#define OFF_WM2T 8192
#define OFF_WG1T 12288
#define OFF_WG2T 16384
#define OFF_WS1T 20480
#define OFF_WS2T 24576
#define OFF_SPAT 28672          // B*128 spatial mean accumulator
#define OFF_SPEC 45056          // B*64 spectral mean accumulator
#define OFF_SSRC 53248          // B*N
#define OFF_SDST 97152          // B*N
#define OFF_SSORT 141056        // B*344
#define OFF_SUFD 185088         // B*344
#define OFF_PRED 229120         // B*344
#define OFF_NODE 273152         // B*N*64
#define OFF_SUFE 3083008        // B*344*64   (bf16 Xf16 lives here until k_sortscan L1)
#define OFF_PREE 5901056        // B*344*64   (bf16 Xt16 lives here until k_sortscan L1)
#define OFF_XW   8719104        // B*N*64     (agg overlay: k_smlp reads before k_xw writes)
#define OFF_OUT1 11528960       // B*N*64     (bf16 nodeT16 lives here until k_gatfin L1)

__device__ __forceinline__ unsigned short f2bf(float v) {
    union { float f; unsigned int u; } c; c.f = v;
    unsigned int r = c.u + 0x7FFFu + ((c.u >> 16) & 1u);
    return (unsigned short)(r >> 16);
}

__global__ void k_prep(const float* __restrict__ Wm1, const float* __restrict__ Wm2,
                       const float* __restrict__ Wg1, const float* __restrict__ Wg2,
                       const float* __restrict__ Ws1, const float* __restrict__ Ws2,
                       float* __restrict__ Wm1T, float* __restrict__ Wm2T,
                       float* __restrict__ Wg1T, float* __restrict__ Wg2T,
                       float* __restrict__ Ws1T, float* __restrict__ Ws2T,
                       unsigned short* __restrict__ gNT16) {
    int t = blockIdx.x * 256 + threadIdx.x;
    if (t < 8192) {
        int o = t >> 7, i = t & 127;
        Wm1T[i * 64 + o] = Wm1[t];
        gNT16[(size_t)t * 344 + 343] = 0;   // zero pad col of nodeT16 (j=343)
    }
    if (t < 4096) {
        int r = t >> 6, c = t & 63;
        Wm2T[c * 64 + r] = Wm2[t];
        Wg1T[c * 64 + r] = Wg1[t];
        Wg2T[c * 64 + r] = Wg2[t];
        Ws1T[c * 64 + r] = Ws1[t];
        Ws2T[c * 64 + r] = Ws2[t];
    }
}

// one wave per (b,n): node MLP + bf16 normalized rows + bf16 node^T
__global__ __launch_bounds__(256) void k_node(
    const float* __restrict__ reps, const float* __restrict__ Wm1T, const float* __restrict__ bm1,
    const float* __restrict__ Wm2T, const float* __restrict__ bm2,
    float* __restrict__ node,
    unsigned short* __restrict__ gXf16, unsigned short* __restrict__ gXt16,
    unsigned short* __restrict__ gNT16)
{
    __shared__ float cat[4][128];
    __shared__ float h1s[4][64];
    int wv = threadIdx.x >> 6, ln = threadIdx.x & 63;
    int idx = blockIdx.x * 4 + wv;            // grid covers B*N exactly
    int b = idx / N_, n = idx - b * N_;
    int f = n / P_, p = n - f * P_;
    const float* xf = reps + (((size_t)b * T_ + f) * P_ + p) * H_;
    float vf = xf[ln], vt = xf[P_ * H_ + ln];
    cat[wv][ln] = vf; cat[wv][64 + ln] = vt;
    float nf = vf * vf, nt = vt * vt;
#pragma unroll
    for (int s = 1; s < 64; s <<= 1) { nf += __shfl_xor(nf, s); nt += __shfl_xor(nt, s); }
    nf = sqrtf(nf) + 1e-4f; nt = sqrtf(nt) + 1e-4f;
    size_t row = (size_t)idx * H_;
    gXf16[row + ln] = f2bf(vf / nf);
    gXt16[row + ln] = f2bf(vt / nt);
    __syncthreads();
    float a = bm1[ln];
#pragma unroll 8
    for (int i = 0; i < 128; i++) a += cat[wv][i] * Wm1T[i * 64 + ln];
    h1s[wv][ln] = fmaxf(a, 0.f);
    __syncthreads();
    float nd = bm2[ln];
#pragma unroll 8
    for (int o = 0; o < 64; o++) nd += h1s[wv][o] * Wm2T[o * 64 + ln];
    node[row + ln] = nd;
    gNT16[((size_t)b * 64 + ln) * 344 + n] = f2bf(nd);   // transposed (scattered 2B)
}

// MFMA flash-style: Sf/St via swapped mfma(Xf_j, Xf_i) -> threshold -> P regs ARE the
// PV A-fragments -> agg += P * node. Only layout assumption: verified C/D map.
// Block: 256 thr = 4 waves; wave wv owns i-rows [itile*64+wv*16, +16). grid = B*6.
__global__ __launch_bounds__(256, 3) void k_sim_mfma(
    const unsigned short* __restrict__ gXf, const unsigned short* __restrict__ gXt,
    const unsigned short* __restrict__ gNT, float* __restrict__ aggO)
{
    __shared__ __align__(16) short sXf[64 * 72];
    __shared__ __align__(16) short sXt[64 * 72];
    __shared__ __align__(16) short sNT[64 * 72];
    int tid = threadIdx.x;
    int b = blockIdx.x / 6, itile = blockIdx.x % 6;
    int wv = tid >> 6, l = tid & 63;
    int kg = l >> 4, m = l & 15;
    int i0 = itile * 64 + wv * 16;
    const unsigned short* gXfb = gXf + (size_t)b * N_ * 64;
    const unsigned short* gXtb = gXt + (size_t)b * N_ * 64;
    const unsigned short* gNTb = gNT + (size_t)b * 64 * 344;

    // i-row register B-fragments (fixed for whole kernel)
    int ri = i0 + m; if (ri > N_ - 1) ri = N_ - 1;
    s16x8 xfiB[2], xtiB[2];
#pragma unroll
    for (int c2 = 0; c2 < 2; ++c2) {
        s16x4 flo = *(const s16x4*)(gXfb + (size_t)ri * 64 + 32 * c2 + 4 * kg);
        s16x4 fhi = *(const s16x4*)(gXfb + (size_t)ri * 64 + 32 * c2 + 16 + 4 * kg);
        s16x4 tlo = *(const s16x4*)(gXtb + (size_t)ri * 64 + 32 * c2 + 4 * kg);
        s16x4 thi = *(const s16x4*)(gXtb + (size_t)ri * 64 + 32 * c2 + 16 + 4 * kg);
        xfiB[c2] = __builtin_shufflevector(flo, fhi, 0, 1, 2, 3, 4, 5, 6, 7);
        xtiB[c2] = __builtin_shufflevector(tlo, thi, 0, 1, 2, 3, 4, 5, 6, 7);
    }

    f32x4 accPV[4];
#pragma unroll
    for (int ht = 0; ht < 4; ++ht) accPV[ht] = (f32x4){0.f, 0.f, 0.f, 0.f};

#pragma unroll 1
    for (int chunk = 0; chunk < 6; ++chunk) {
        int j0 = chunk * 64;
        __syncthreads();
        for (int s = tid; s < 512; s += 256) {
            int row = s >> 3, grp = s & 7;
            int j = j0 + row;
            s16x8 vf = {0, 0, 0, 0, 0, 0, 0, 0};
            s16x8 vt = {0, 0, 0, 0, 0, 0, 0, 0};
            s16x8 vn = {0, 0, 0, 0, 0, 0, 0, 0};
            if (j < N_) {
                vf = *(const s16x8*)(gXfb + (size_t)j * 64 + grp * 8);
                vt = *(const s16x8*)(gXtb + (size_t)j * 64 + grp * 8);
            }
            if (j0 + grp * 8 + 8 <= 344)
                vn = *(const s16x8*)(gNTb + (size_t)row * 344 + j0 + grp * 8);
            *(s16x8*)(&sXf[row * 72 + grp * 8]) = vf;
            *(s16x8*)(&sXt[row * 72 + grp * 8]) = vt;
            *(s16x8*)(&sNT[row * 72 + grp * 8]) = vn;
        }
        __syncthreads();
        int npair = (chunk == 5) ? 1 : 2;
#pragma unroll 1
        for (int pr = 0; pr < npair; ++pr) {
            s16x8 pa;
#pragma unroll
            for (int sub = 0; sub < 2; ++sub) {
                int arow = (pr * 2 + sub) * 16 + m;
                f32x4 sf = (f32x4){0.f, 0.f, 0.f, 0.f};
                f32x4 st = (f32x4){0.f, 0.f, 0.f, 0.f};
#pragma unroll
                for (int hc = 0; hc < 2; ++hc) {
                    int h0 = hc * 32;
                    s16x4 alo = *(const s16x4*)(&sXf[arow * 72 + h0 + 4 * kg]);
                    s16x4 ahi = *(const s16x4*)(&sXf[arow * 72 + h0 + 16 + 4 * kg]);
                    s16x8 av = __builtin_shufflevector(alo, ahi, 0, 1, 2, 3, 4, 5, 6, 7);
                    sf = __builtin_amdgcn_mfma_f32_16x16x32_bf16(av, xfiB[hc], sf, 0, 0, 0);
                    s16x4 blo = *(const s16x4*)(&sXt[arow * 72 + h0 + 4 * kg]);
                    s16x4 bhi = *(const s16x4*)(&sXt[arow * 72 + h0 + 16 + 4 * kg]);
                    s16x8 bv = __builtin_shufflevector(blo, bhi, 0, 1, 2, 3, 4, 5, 6, 7);
                    st = __builtin_amdgcn_mfma_f32_16x16x32_bf16(bv, xtiB[hc], st, 0, 0, 0);
                }
#pragma unroll
                for (int r = 0; r < 4; ++r) {
                    float v = fmaxf(sf[r], st[r]);
                    v = (v > THRESH) ? v : 0.f;
                    pa[sub * 4 + r] = (short)f2bf(v);
                }
            }
            int jl0 = pr * 32;
#pragma unroll
            for (int ht = 0; ht < 4; ++ht) {
                s16x4 nlo = *(const s16x4*)(&sNT[(ht * 16 + m) * 72 + jl0 + 4 * kg]);
                s16x4 nhi = *(const s16x4*)(&sNT[(ht * 16 + m) * 72 + jl0 + 16 + 4 * kg]);
                s16x8 nv = __builtin_shufflevector(nlo, nhi, 0, 1, 2, 3, 4, 5, 6, 7);
                accPV[ht] = __builtin_amdgcn_mfma_f32_16x16x32_bf16(pa, nv, accPV[ht], 0, 0, 0);
            }
        }
    }
#pragma unroll
    for (int ht = 0; ht < 4; ++ht)
#pragma unroll
        for (int r = 0; r < 4; ++r) {
            int iRow = i0 + 4 * kg + r;
            if (iRow < N_)
                aggO[((size_t)b * N_ + iRow) * 64 + ht * 16 + m] = accPV[ht][r];
        }
}

// spectral MLP: wave per row, atomic mean accumulate
__global__ __launch_bounds__(256) void k_smlp(
    const float* __restrict__ aggI, const float* __restrict__ Ws1T, const float* __restrict__ bs1,
    const float* __restrict__ Ws2T, const float* __restrict__ bs2, float* __restrict__ spectral)
{
    __shared__ float xs[4][64];
    __shared__ float h1s[4][64];
    int wv = threadIdx.x >> 6, ln = threadIdx.x & 63;
    int idx = blockIdx.x * 4 + wv;
    int b = idx / N_;
    xs[wv][ln] = aggI[(size_t)idx * 64 + ln];
    __syncthreads();
    float a = bs1[ln];
#pragma unroll 8
    for (int h = 0; h < 64; h++) a += xs[wv][h] * Ws1T[h * 64 + ln];
    h1s[wv][ln] = fmaxf(a, 0.f);
    __syncthreads();
    float a2 = bs2[ln];
#pragma unroll 8
    for (int o = 0; o < 64; o++) a2 += h1s[wv][o] * Ws2T[o * 64 + ln];
    atomicAdd(&spectral[b * 64 + ln], a2);
}

// one wave per (b,n): xw = x @ WgT, plus attention scalars
__global__ __launch_bounds__(256) void k_xw(
    const float* __restrict__ x, const float* __restrict__ WgT,
    const float* __restrict__ as_, const float* __restrict__ ad_,
    float* __restrict__ xw, float* __restrict__ ssrc, float* __restrict__ sdst)
{
    __shared__ float xs[4][64];
    int wv = threadIdx.x >> 6, ln = threadIdx.x & 63;
    int idx = blockIdx.x * 4 + wv;
    size_t row = (size_t)idx * H_;
    xs[wv][ln] = x[row + ln];
    __syncthreads();
    float a = 0.f;
#pragma unroll 8
    for (int h = 0; h < 64; h++) a += xs[wv][h] * WgT[h * 64 + ln];
    xw[row + ln] = a;
    float ps = a * as_[ln], pd = a * ad_[ln];
#pragma unroll
    for (int s = 1; s < 64; s <<= 1) { ps += __shfl_xor(ps, s); pd += __shfl_xor(pd, s); }
    if (ln == 0) { ssrc[idx] = ps; sdst[idx] = pd; }
}

// per-batch: bitonic sort + PARALLEL segmented suffix/prefix weighted scans.
#define NSEG 16
#define SEGSZ 22
__global__ __launch_bounds__(1024) void k_sortscan(
    const float* __restrict__ ssrc, const float* __restrict__ xw,
    float* __restrict__ ssort, float* __restrict__ SufE, float* __restrict__ PreE,
    float* __restrict__ SufD, float* __restrict__ PreD)
{
    __shared__ float sv[512];
    __shared__ int   si[512];
    __shared__ float w1L[344], w2L[344];
    __shared__ float segT[NSEG * 64];
    __shared__ float segD[NSEG];
    int tid = threadIdx.x, b = blockIdx.x;
    for (int q = tid; q < 512; q += 1024) {
        sv[q] = (q < N_) ? ssrc[b * N_ + q] : 3.0e38f;
        si[q] = q;
    }
    __syncthreads();
    for (int k = 2; k <= 512; k <<= 1)
        for (int j = k >> 1; j > 0; j >>= 1) {
            for (int e = tid; e < 512; e += 1024) {
                int l = e ^ j;
                if (l > e) {
                    float a = sv[e], c = sv[l];
                    bool up = ((e & k) == 0);
                    if (up ? (a > c) : (a < c)) {
                        sv[e] = c; sv[l] = a;
                        int t = si[e]; si[e] = si[l]; si[l] = t;
                    }
                }
            }
            __syncthreads();
        }
    if (tid < N_) {
        float v = sv[tid];
        w1L[tid] = __expf(v);
        w2L[tid] = __expf(0.2f * v);
        ssort[(size_t)b * 344 + tid] = v;
    }
    __syncthreads();
    int t = tid >> 6, h = tid & 63;
    int qs = t * SEGSZ, qe = min(qs + SEGSZ, N_);
    const float* xwb = xw + (size_t)b * N_ * 64;
    size_t base = (size_t)b * 344;
    float r = 0.f, rd = 0.f;
    for (int q = qe - 1; q >= qs; --q) {
        float w = w1L[q];
        r += w * xwb[(size_t)si[q] * 64 + h];
        rd += w;
    }
    segT[t * 64 + h] = r; if (h == 0) segD[t] = rd;
    __syncthreads();
    float bsum = 0.f, bden = 0.f;
    for (int t2 = t + 1; t2 < NSEG; ++t2) { bsum += segT[t2 * 64 + h]; bden += segD[t2]; }
    r = bsum; rd = bden;
    for (int q = qe - 1; q >= qs; --q) {
        float w = w1L[q];
        r += w * xwb[(size_t)si[q] * 64 + h];
        rd += w;
        SufE[(base + q) * 64 + h] = r;
        if (h == 0) SufD[base + q] = rd;
    }
    if (t == 0) { SufE[(base + 343) * 64 + h] = 0.f; if (h == 0) SufD[base + 343] = 0.f; }
    __syncthreads();
    r = 0.f; rd = 0.f;
    for (int q = qs; q < qe; ++q) {
        float w = w2L[q];
        r += w * xwb[(size_t)si[q] * 64 + h];
        rd += w;
    }
    segT[t * 64 + h] = r; if (h == 0) segD[t] = rd;
    __syncthreads();
    bsum = 0.f; bden = 0.f;
    for (int t2 = 0; t2 < t; ++t2) { bsum += segT[t2 * 64 + h]; bden += segD[t2]; }
    r = bsum; rd = bden;
    for (int q = qs; q < qe; ++q) {
        PreE[(base + q) * 64 + h] = r;
        if (h == 0) PreD[base + q] = rd;
        float w = w2L[q];
        r += w * xwb[(size_t)si[q] * 64 + h];
        rd += w;
    }
    if (t == NSEG - 1) { PreE[(base + 343) * 64 + h] = r; if (h == 0) PreD[base + 343] = rd; }
}

// wave per (b,i): exact GAT row via sorted prefix/suffix sums + head mix + l2norm + relu
template <int STORE>
__global__ __launch_bounds__(256) void k_gatfin(
    const float* __restrict__ sdst, const float* __restrict__ ssort,
    const float* __restrict__ SufE, const float* __restrict__ PreE,
    const float* __restrict__ SufD, const float* __restrict__ PreD,
    const float* __restrict__ bg, const float* __restrict__ hw, const float* __restrict__ hb,
    float* __restrict__ outrows, float* __restrict__ spatial, int soff)
{
    int wv = threadIdx.x >> 6, ln = threadIdx.x & 63;
    int idx = blockIdx.x * 4 + wv;           // grid covers B*N exactly
    int b = idx / N_;
    float di = sdst[idx];
    const float* ss = ssort + (size_t)b * 344;
    float key = -di;
    int lo = 0, hi = N_;
    while (lo < hi) { int mid = (lo + hi) >> 1; if (ss[mid] >= key) hi = mid; else lo = mid + 1; }
    int p = lo;
    float ed = __expf(di), e2 = __expf(0.2f * di);
    size_t base = (size_t)b * 344 + p;
    float acc = ed * SufE[base * 64 + ln] + e2 * PreE[base * 64 + ln];
    float den = ed * SufD[base] + e2 * PreD[base];
    float g = acc / den + bg[ln];
    int k = ln >> 4;
    float y = hb[ln];
    const float* hwr = hw + ln * 16;
#pragma unroll
    for (int d = 0; d < 16; ++d) y += hwr[d] * __shfl(g, (k << 4) | d);
    float ssum = y * y;
#pragma unroll
    for (int s = 1; s < 64; s <<= 1) ssum += __shfl_xor(ssum, s);
    float rr = 1.f / fmaxf(sqrtf(ssum), 1e-12f);
    y = fmaxf(y * rr, 0.f);
    if (STORE) outrows[(size_t)idx * 64 + ln] = y;
    atomicAdd(&spatial[b * 128 + soff + ln], y);
}

__global__ void k_final(const float* __restrict__ spatial, const float* __restrict__ spectral,
                        const float* __restrict__ Wf, const float* __restrict__ bf_,
                        float* __restrict__ out)
{
    int b = blockIdx.x, ln = threadIdx.x;  // 64 threads
    float inv = 1.f / (float)N_;
    float e0 = spatial[b * 128 + ln] * inv;
    float e1 = spatial[b * 128 + 64 + ln] * inv;
    float e2 = spectral[b * 64 + ln] * inv;
#pragma unroll
    for (int c = 0; c < 2; c++) {
        float a = e0 * Wf[c * 192 + ln] + e1 * Wf[c * 192 + 64 + ln] + e2 * Wf[c * 192 + 128 + ln];
#pragma unroll
        for (int s = 1; s < 64; s <<= 1) a += __shfl_xor(a, s);
        if (ln == 0) out[b * 2 + c] = a + bf_[c];
    }
}

extern "C" void kernel_launch(void* const* d_in, const int* in_sizes, int n_in,
                              void* d_out, int out_size, void* d_ws, size_t ws_size,
                              hipStream_t stream)
{
    const float* reps = (const float*)d_in[0];
    const float* Wm1  = (const float*)d_in[1];
    const float* bm1  = (const float*)d_in[2];
    const float* Wm2  = (const float*)d_in[3];
    const float* bm2  = (const float*)d_in[4];
    const float* Wg1  = (const float*)d_in[5];
    const float* a1s  = (const float*)d_in[6];
    const float* a1d  = (const float*)d_in[7];
    const float* bg1  = (const float*)d_in[8];
    const float* hw1  = (const float*)d_in[9];
    const float* hb1  = (const float*)d_in[10];
    const float* Wg2  = (const float*)d_in[11];
    const float* a2s  = (const float*)d_in[12];
    const float* a2d  = (const float*)d_in[13];
    const float* bg2  = (const float*)d_in[14];
    const float* hw3  = (const float*)d_in[15];
    const float* hb3  = (const float*)d_in[16];
    const float* Ws1  = (const float*)d_in[17];
    const float* bs1  = (const float*)d_in[18];
    const float* Ws2  = (const float*)d_in[19];
    const float* bs2  = (const float*)d_in[20];
    const float* Wf   = (const float*)d_in[21];
    const float* bf_  = (const float*)d_in[22];

    float* ws = (float*)d_ws;
    float* Wm1T = ws + OFF_WM1T;
    float* Wm2T = ws + OFF_WM2T;
    float* Wg1T = ws + OFF_WG1T;
    float* Wg2T = ws + OFF_WG2T;
    float* Ws1T = ws + OFF_WS1T;
    float* Ws2T = ws + OFF_WS2T;
    float* spat = ws + OFF_SPAT;
    float* spec = ws + OFF_SPEC;
    float* ssrc = ws + OFF_SSRC;
    float* sdst = ws + OFF_SDST;
    float* ssort= ws + OFF_SSORT;
    float* SufD = ws + OFF_SUFD;
    float* PreD = ws + OFF_PRED;
    float* node = ws + OFF_NODE;
    float* SufE = ws + OFF_SUFE;
    float* PreE = ws + OFF_PREE;
    float* xwb  = ws + OFF_XW;
    float* out1 = ws + OFF_OUT1;
    // bf16 overlays (freed before their host regions are written)
    unsigned short* gXf16 = (unsigned short*)(ws + OFF_SUFE);   // until k_sortscan L1
    unsigned short* gXt16 = (unsigned short*)(ws + OFF_PREE);   // until k_sortscan L1
    unsigned short* gNT16 = (unsigned short*)(ws + OFF_OUT1);   // until k_gatfin L1
    float* agg = xwb;                                           // until k_xw L1

    hipMemsetAsync(spat, 0, (16384 + 8192) * sizeof(float), stream);
    k_prep<<<32, 256, 0, stream>>>(Wm1, Wm2, Wg1, Wg2, Ws1, Ws2,
                                   Wm1T, Wm2T, Wg1T, Wg2T, Ws1T, Ws2T, gNT16);
    k_node<<<(B_ * N_) / 4, 256, 0, stream>>>(reps, Wm1T, bm1, Wm2T, bm2,
                                              node, gXf16, gXt16, gNT16);
    k_sim_mfma<<<B_ * 6, 256, 0, stream>>>(gXf16, gXt16, gNT16, agg);
    k_smlp<<<(B_ * N_) / 4, 256, 0, stream>>>(agg, Ws1T, bs1, Ws2T, bs2, spec);
    // ---- GAT layer 1 ----
    k_xw<<<(B_ * N_) / 4, 256, 0, stream>>>(node, Wg1T, a1s, a1d, xwb, ssrc, sdst);
    k_sortscan<<<B_, 1024, 0, stream>>>(ssrc, xwb, ssort, SufE, PreE, SufD, PreD);
    k_gatfin<1><<<(B_ * N_) / 4, 256, 0, stream>>>(sdst, ssort, SufE, PreE, SufD, PreD,
                                                   bg1, hw1, hb1, out1, spat, 0);
    // ---- GAT layer 2 ----
    k_xw<<<(B_ * N_) / 4, 256, 0, stream>>>(out1, Wg2T, a2s, a2d, xwb, ssrc, sdst);
    k_sortscan<<<B_, 1024, 0, stream>>>(ssrc, xwb, ssort, SufE, PreE, SufD, PreD);
    k_gatfin<0><<<(B_ * N_) / 4, 256, 0, stream>>>(sdst, ssort, SufE, PreE, SufD, PreD,
                                                   bg2, hw3, hb3, nullptr, spat, 64);
    k_final<<<B_, 64, 0, stream>>>(spat, spec, Wf, bf_, (float*)d_out);
}

// Round 7
// 463.167 us; speedup vs baseline: 2.4245x; 1.0577x over previous
//
#include <hip/hip_runtime.h>
#include <math.h>

#define B_ 128
#define T_ 8
#define P_ 49
#define H_ 64
#define N_ 343
#define THRESH 0.6f
#define NSLOPE 0.2f

typedef float  f32x4  __attribute__((ext_vector_type(4)));
typedef short  s16x4  __attribute__((ext_vector_type(4)));
typedef short  s16x8  __attribute__((ext_vector_type(8)));

// workspace layout (float offsets) — total 14,338,816 floats = 57.4 MB
#define OFF_WM1T 0
#define OFF_WM2T 8192
#define OFF_WG1T 12288
#define OFF_WG2T 16384
#define OFF_WS1T 20480
#define OFF_WS2T 24576
#define OFF_SPAT 28672          // B*128 spatial mean accumulator
#define OFF_SPEC 45056          // B*64 spectral mean accumulator
#define OFF_SSRC 53248          // B*N
#define OFF_SDST 97152          // B*N
#define OFF_SSORT 141056        // B*344
#define OFF_SUFD 185088         // B*344
#define OFF_PRED 229120         // B*344
#define OFF_NODE 273152         // B*N*64
#define OFF_SUFE 3083008        // B*344*64   (bf16 Xf16 overlay until k_sortscan L1)
#define OFF_PREE 5901056        // B*344*64   (bf16 Xt16 overlay until k_sortscan L1)
#define OFF_XW   8719104        // B*N*64     (node16 overlay -> agg overlay -> xw)
#define OFF_OUT1 11528960       // B*N*64     (bf16 nodeT16 overlay until k_gatfin L1)

__device__ __forceinline__ unsigned short f2bf(float v) {
    union { float f; unsigned int u; } c; c.f = v;
    unsigned int r = c.u + 0x7FFFu + ((c.u >> 16) & 1u);
    return (unsigned short)(r >> 16);
}

__global__ void k_prep(const float* __restrict__ Wm1, const float* __restrict__ Wm2,
                       const float* __restrict__ Wg1, const float* __restrict__ Wg2,
                       const float* __restrict__ Ws1, const float* __restrict__ Ws2,
                       float* __restrict__ Wm1T, float* __restrict__ Wm2T,
                       float* __restrict__ Wg1T, float* __restrict__ Wg2T,
                       float* __restrict__ Ws1T, float* __restrict__ Ws2T) {
    int t = blockIdx.x * 256 + threadIdx.x;
    if (t < 8192) { int o = t >> 7, i = t & 127; Wm1T[i * 64 + o] = Wm1[t]; }
    if (t < 4096) {
        int r = t >> 6, c = t & 63;
        Wm2T[c * 64 + r] = Wm2[t];
        Wg1T[c * 64 + r] = Wg1[t];
        Wg2T[c * 64 + r] = Wg2[t];
        Ws1T[c * 64 + r] = Ws1[t];
        Ws2T[c * 64 + r] = Ws2[t];
    }
}

#define NODE_NB 1024
// grid-stride waves-per-row node MLP; weights LDS-resident; coalesced bf16 outputs
__global__ __launch_bounds__(256) void k_node(
    const float* __restrict__ reps, const float* __restrict__ Wm1T, const float* __restrict__ bm1,
    const float* __restrict__ Wm2T, const float* __restrict__ bm2,
    float* __restrict__ node,
    unsigned short* __restrict__ gXf16, unsigned short* __restrict__ gXt16,
    unsigned short* __restrict__ gN16)
{
    __shared__ float sW1[8192];   // 32 KB
    __shared__ float sW2[4096];   // 16 KB
    __shared__ float cat[4][128];
    __shared__ float h1s[4][64];
    int tid = threadIdx.x;
    for (int t = tid; t < 2048; t += 256) ((float4*)sW1)[t] = ((const float4*)Wm1T)[t];
    for (int t = tid; t < 1024; t += 256) ((float4*)sW2)[t] = ((const float4*)Wm2T)[t];
    __syncthreads();
    int wv = tid >> 6, ln = tid & 63;
    float bias1 = bm1[ln], bias2 = bm2[ln];
    for (int g = blockIdx.x; g < (B_ * N_) / 4; g += NODE_NB) {
        int idx = g * 4 + wv;
        int b = idx / N_, n = idx - b * N_;
        int f = n / P_, p = n - f * P_;
        const float* xf = reps + (((size_t)b * T_ + f) * P_ + p) * H_;
        float vf = xf[ln], vt = xf[P_ * H_ + ln];
        cat[wv][ln] = vf; cat[wv][64 + ln] = vt;
        float nf = vf * vf, nt = vt * vt;
#pragma unroll
        for (int s = 1; s < 64; s <<= 1) { nf += __shfl_xor(nf, s); nt += __shfl_xor(nt, s); }
        nf = sqrtf(nf) + 1e-4f; nt = sqrtf(nt) + 1e-4f;
        size_t row = (size_t)idx * H_;
        gXf16[row + ln] = f2bf(vf / nf);
        gXt16[row + ln] = f2bf(vt / nt);
        float a0 = 0.f, a1 = 0.f, a2 = 0.f, a3 = 0.f;
#pragma unroll 4
        for (int i = 0; i < 128; i += 4) {
            a0 += cat[wv][i]     * sW1[i * 64 + ln];
            a1 += cat[wv][i + 1] * sW1[(i + 1) * 64 + ln];
            a2 += cat[wv][i + 2] * sW1[(i + 2) * 64 + ln];
            a3 += cat[wv][i + 3] * sW1[(i + 3) * 64 + ln];
        }
        h1s[wv][ln] = fmaxf(bias1 + (a0 + a1) + (a2 + a3), 0.f);
        float c0 = 0.f, c1 = 0.f, c2 = 0.f, c3 = 0.f;
#pragma unroll 4
        for (int o = 0; o < 64; o += 4) {
            c0 += h1s[wv][o]     * sW2[o * 64 + ln];
            c1 += h1s[wv][o + 1] * sW2[(o + 1) * 64 + ln];
            c2 += h1s[wv][o + 2] * sW2[(o + 2) * 64 + ln];
            c3 += h1s[wv][o + 3] * sW2[(o + 3) * 64 + ln];
        }
        float nd = bias2 + (c0 + c1) + (c2 + c3);
        node[row + ln] = nd;
        gN16[row + ln] = f2bf(nd);
    }
}

// LDS-tile transpose: node16 [b][n][64] -> nodeT16 [b][64][344] (both sides coalesced)
__global__ __launch_bounds__(256) void k_tr(
    const unsigned short* __restrict__ g16, unsigned short* __restrict__ gT16)
{
    __shared__ unsigned short tile[64][72];
    int b = blockIdx.x / 6, jt = blockIdx.x % 6;
    int j0 = jt * 64;
    int tid = threadIdx.x;
    const unsigned short* gb = g16 + (size_t)b * N_ * 64;
    for (int s = tid; s < 512; s += 256) {
        int row = s >> 3, grp = s & 7;
        int j = j0 + row;
        s16x8 v = {0, 0, 0, 0, 0, 0, 0, 0};
        if (j < N_) v = *(const s16x8*)(gb + (size_t)j * 64 + grp * 8);
        *(s16x8*)(&tile[row][grp * 8]) = v;
    }
    __syncthreads();
    for (int s = tid; s < 512; s += 256) {
        int h = s >> 3, grp = s & 7;
        int jj0 = grp * 8;
        if (j0 + jj0 + 8 <= 344) {
            s16x8 v;
#pragma unroll
            for (int k = 0; k < 8; ++k) v[k] = tile[jj0 + k][h];
            *(s16x8*)(gT16 + ((size_t)b * 64 + h) * 344 + j0 + jj0) = v;
        }
    }
}

// MFMA flash-style sim+aggregate (unchanged from R6)
__global__ __launch_bounds__(256, 3) void k_sim_mfma(
    const unsigned short* __restrict__ gXf, const unsigned short* __restrict__ gXt,
    const unsigned short* __restrict__ gNT, float* __restrict__ aggO)
{
    __shared__ __align__(16) short sXf[64 * 72];
    __shared__ __align__(16) short sXt[64 * 72];
    __shared__ __align__(16) short sNT[64 * 72];
    int tid = threadIdx.x;
    int b = blockIdx.x / 6, itile = blockIdx.x % 6;
    int wv = tid >> 6, l = tid & 63;
    int kg = l >> 4, m = l & 15;
    int i0 = itile * 64 + wv * 16;
    const unsigned short* gXfb = gXf + (size_t)b * N_ * 64;
    const unsigned short* gXtb = gXt + (size_t)b * N_ * 64;
    const unsigned short* gNTb = gNT + (size_t)b * 64 * 344;

    int ri = i0 + m; if (ri > N_ - 1) ri = N_ - 1;
    s16x8 xfiB[2], xtiB[2];
#pragma unroll
    for (int c2 = 0; c2 < 2; ++c2) {
        s16x4 flo = *(const s16x4*)(gXfb + (size_t)ri * 64 + 32 * c2 + 4 * kg);
        s16x4 fhi = *(const s16x4*)(gXfb + (size_t)ri * 64 + 32 * c2 + 16 + 4 * kg);
        s16x4 tlo = *(const s16x4*)(gXtb + (size_t)ri * 64 + 32 * c2 + 4 * kg);
        s16x4 thi = *(const s16x4*)(gXtb + (size_t)ri * 64 + 32 * c2 + 16 + 4 * kg);
        xfiB[c2] = __builtin_shufflevector(flo, fhi, 0, 1, 2, 3, 4, 5, 6, 7);
        xtiB[c2] = __builtin_shufflevector(tlo, thi, 0, 1, 2, 3, 4, 5, 6, 7);
    }

    f32x4 accPV[4];
#pragma unroll
    for (int ht = 0; ht < 4; ++ht) accPV[ht] = (f32x4){0.f, 0.f, 0.f, 0.f};

#pragma unroll 1
    for (int chunk = 0; chunk < 6; ++chunk) {
        int j0 = chunk * 64;
        __syncthreads();
        for (int s = tid; s < 512; s += 256) {
            int row = s >> 3, grp = s & 7;
            int j = j0 + row;
            s16x8 vf = {0, 0, 0, 0, 0, 0, 0, 0};
            s16x8 vt = {0, 0, 0, 0, 0, 0, 0, 0};
            s16x8 vn = {0, 0, 0, 0, 0, 0, 0, 0};
            if (j < N_) {
                vf = *(const s16x8*)(gXfb + (size_t)j * 64 + grp * 8);
                vt = *(const s16x8*)(gXtb + (size_t)j * 64 + grp * 8);
            }
            if (j0 + grp * 8 + 8 <= 344)
                vn = *(const s16x8*)(gNTb + (size_t)row * 344 + j0 + grp * 8);
            *(s16x8*)(&sXf[row * 72 + grp * 8]) = vf;
            *(s16x8*)(&sXt[row * 72 + grp * 8]) = vt;
            *(s16x8*)(&sNT[row * 72 + grp * 8]) = vn;
        }
        __syncthreads();
        int npair = (chunk == 5) ? 1 : 2;
#pragma unroll 1
        for (int pr = 0; pr < npair; ++pr) {
            s16x8 pa;
#pragma unroll
            for (int sub = 0; sub < 2; ++sub) {
                int arow = (pr * 2 + sub) * 16 + m;
                f32x4 sf = (f32x4){0.f, 0.f, 0.f, 0.f};
                f32x4 st = (f32x4){0.f, 0.f, 0.f, 0.f};
#pragma unroll
                for (int hc = 0; hc < 2; ++hc) {
                    int h0 = hc * 32;
                    s16x4 alo = *(const s16x4*)(&sXf[arow * 72 + h0 + 4 * kg]);
                    s16x4 ahi = *(const s16x4*)(&sXf[arow * 72 + h0 + 16 + 4 * kg]);
                    s16x8 av = __builtin_shufflevector(alo, ahi, 0, 1, 2, 3, 4, 5, 6, 7);
                    sf = __builtin_amdgcn_mfma_f32_16x16x32_bf16(av, xfiB[hc], sf, 0, 0, 0);
                    s16x4 blo = *(const s16x4*)(&sXt[arow * 72 + h0 + 4 * kg]);
                    s16x4 bhi = *(const s16x4*)(&sXt[arow * 72 + h0 + 16 + 4 * kg]);
                    s16x8 bv = __builtin_shufflevector(blo, bhi, 0, 1, 2, 3, 4, 5, 6, 7);
                    st = __builtin_amdgcn_mfma_f32_16x16x32_bf16(bv, xtiB[hc], st, 0, 0, 0);
                }
#pragma unroll
                for (int r = 0; r < 4; ++r) {
                    float v = fmaxf(sf[r], st[r]);
                    v = (v > THRESH) ? v : 0.f;
                    pa[sub * 4 + r] = (short)f2bf(v);
                }
            }
            int jl0 = pr * 32;
#pragma unroll
            for (int ht = 0; ht < 4; ++ht) {
                s16x4 nlo = *(const s16x4*)(&sNT[(ht * 16 + m) * 72 + jl0 + 4 * kg]);
                s16x4 nhi = *(const s16x4*)(&sNT[(ht * 16 + m) * 72 + jl0 + 16 + 4 * kg]);
                s16x8 nv = __builtin_shufflevector(nlo, nhi, 0, 1, 2, 3, 4, 5, 6, 7);
                accPV[ht] = __builtin_amdgcn_mfma_f32_16x16x32_bf16(pa, nv, accPV[ht], 0, 0, 0);
            }
        }
    }
#pragma unroll
    for (int ht = 0; ht < 4; ++ht)
#pragma unroll
        for (int r = 0; r < 4; ++r) {
            int iRow = i0 + 4 * kg + r;
            if (iRow < N_)
                aggO[((size_t)b * N_ + iRow) * 64 + ht * 16 + m] = accPV[ht][r];
        }
}

// spectral MLP: grid-stride, LDS weights, split accumulators
__global__ __launch_bounds__(256) void k_smlp(
    const float* __restrict__ aggI, const float* __restrict__ Ws1T, const float* __restrict__ bs1,
    const float* __restrict__ Ws2T, const float* __restrict__ bs2, float* __restrict__ spectral)
{
    __shared__ float sW1[4096];
    __shared__ float sW2[4096];
    __shared__ float xs[4][64];
    __shared__ float h1s[4][64];
    int tid = threadIdx.x;
    for (int t = tid; t < 1024; t += 256) {
        ((float4*)sW1)[t] = ((const float4*)Ws1T)[t];
        ((float4*)sW2)[t] = ((const float4*)Ws2T)[t];
    }
    __syncthreads();
    int wv = tid >> 6, ln = tid & 63;
    float bias1 = bs1[ln], bias2 = bs2[ln];
    for (int g = blockIdx.x; g < (B_ * N_) / 4; g += NODE_NB) {
        int idx = g * 4 + wv;
        int b = idx / N_;
        xs[wv][ln] = aggI[(size_t)idx * 64 + ln];
        float a0 = 0.f, a1 = 0.f, a2 = 0.f, a3 = 0.f;
#pragma unroll 4
        for (int h = 0; h < 64; h += 4) {
            a0 += xs[wv][h]     * sW1[h * 64 + ln];
            a1 += xs[wv][h + 1] * sW1[(h + 1) * 64 + ln];
            a2 += xs[wv][h + 2] * sW1[(h + 2) * 64 + ln];
            a3 += xs[wv][h + 3] * sW1[(h + 3) * 64 + ln];
        }
        h1s[wv][ln] = fmaxf(bias1 + (a0 + a1) + (a2 + a3), 0.f);
        float c0 = 0.f, c1 = 0.f, c2 = 0.f, c3 = 0.f;
#pragma unroll 4
        for (int o = 0; o < 64; o += 4) {
            c0 += h1s[wv][o]     * sW2[o * 64 + ln];
            c1 += h1s[wv][o + 1] * sW2[(o + 1) * 64 + ln];
            c2 += h1s[wv][o + 2] * sW2[(o + 2) * 64 + ln];
            c3 += h1s[wv][o + 3] * sW2[(o + 3) * 64 + ln];
        }
        atomicAdd(&spectral[b * 64 + ln], bias2 + (c0 + c1) + (c2 + c3));
    }
}

// xw = x @ WgT + attention scalars: grid-stride, LDS weights, split accumulators
__global__ __launch_bounds__(256) void k_xw(
    const float* __restrict__ x, const float* __restrict__ WgT,
    const float* __restrict__ as_, const float* __restrict__ ad_,
    float* __restrict__ xw, float* __restrict__ ssrc, float* __restrict__ sdst)
{
    __shared__ float sW[4096];
    __shared__ float xs[4][64];
    int tid = threadIdx.x;
    for (int t = tid; t < 1024; t += 256) ((float4*)sW)[t] = ((const float4*)WgT)[t];
    __syncthreads();
    int wv = tid >> 6, ln = tid & 63;
    float asv = as_[ln], adv = ad_[ln];
    for (int g = blockIdx.x; g < (B_ * N_) / 4; g += NODE_NB) {
        int idx = g * 4 + wv;
        size_t row = (size_t)idx * H_;
        xs[wv][ln] = x[row + ln];
        float a0 = 0.f, a1 = 0.f, a2 = 0.f, a3 = 0.f;
#pragma unroll 4
        for (int h = 0; h < 64; h += 4) {
            a0 += xs[wv][h]     * sW[h * 64 + ln];
            a1 += xs[wv][h + 1] * sW[(h + 1) * 64 + ln];
            a2 += xs[wv][h + 2] * sW[(h + 2) * 64 + ln];
            a3 += xs[wv][h + 3] * sW[(h + 3) * 64 + ln];
        }
        float a = (a0 + a1) + (a2 + a3);
        xw[row + ln] = a;
        float ps = a * asv, pd = a * adv;
#pragma unroll
        for (int s = 1; s < 64; s <<= 1) { ps += __shfl_xor(ps, s); pd += __shfl_xor(pd, s); }
        if (ln == 0) { ssrc[idx] = ps; sdst[idx] = pd; }
    }
}

// per-batch: bitonic sort + PARALLEL segmented suffix/prefix weighted scans.
#define NSEG 16
#define SEGSZ 22
__global__ __launch_bounds__(1024) void k_sortscan(
    const float* __restrict__ ssrc, const float* __restrict__ xw,
    float* __restrict__ ssort, float* __restrict__ SufE, float* __restrict__ PreE,
    float* __restrict__ SufD, float* __restrict__ PreD)
{
    __shared__ float sv[512];
    __shared__ int   si[512];
    __shared__ float w1L[344], w2L[344];
    __shared__ float segT[NSEG * 64];
    __shared__ float segD[NSEG];
    int tid = threadIdx.x, b = blockIdx.x;
    for (int q = tid; q < 512; q += 1024) {
        sv[q] = (q < N_) ? ssrc[b * N_ + q] : 3.0e38f;
        si[q] = q;
    }
    __syncthreads();
    for (int k = 2; k <= 512; k <<= 1)
        for (int j = k >> 1; j > 0; j >>= 1) {
            for (int e = tid; e < 512; e += 1024) {
                int l = e ^ j;
                if (l > e) {
                    float a = sv[e], c = sv[l];
                    bool up = ((e & k) == 0);
                    if (up ? (a > c) : (a < c)) {
                        sv[e] = c; sv[l] = a;
                        int t = si[e]; si[e] = si[l]; si[l] = t;
                    }
                }
            }
            __syncthreads();
        }
    if (tid < N_) {
        float v = sv[tid];
        w1L[tid] = __expf(v);
        w2L[tid] = __expf(0.2f * v);
        ssort[(size_t)b * 344 + tid] = v;
    }
    __syncthreads();
    int t = tid >> 6, h = tid & 63;
    int qs = t * SEGSZ, qe = min(qs + SEGSZ, N_);
    const float* xwb = xw + (size_t)b * N_ * 64;
    size_t base = (size_t)b * 344;
    float r = 0.f, rd = 0.f;
    for (int q = qe - 1; q >= qs; --q) {
        float w = w1L[q];
        r += w * xwb[(size_t)si[q] * 64 + h];
        rd += w;
    }
    segT[t * 64 + h] = r; if (h == 0) segD[t] = rd;
    __syncthreads();
    float bsum = 0.f, bden = 0.f;
    for (int t2 = t + 1; t2 < NSEG; ++t2) { bsum += segT[t2 * 64 + h]; bden += segD[t2]; }
    r = bsum; rd = bden;
    for (int q = qe - 1; q >= qs; --q) {
        float w = w1L[q];
        r += w * xwb[(size_t)si[q] * 64 + h];
        rd += w;
        SufE[(base + q) * 64 + h] = r;
        if (h == 0) SufD[base + q] = rd;
    }
    if (t == 0) { SufE[(base + 343) * 64 + h] = 0.f; if (h == 0) SufD[base + 343] = 0.f; }
    __syncthreads();
    r = 0.f; rd = 0.f;
    for (int q = qs; q < qe; ++q) {
        float w = w2L[q];
        r += w * xwb[(size_t)si[q] * 64 + h];
        rd += w;
    }
    segT[t * 64 + h] = r; if (h == 0) segD[t] = rd;
    __syncthreads();
    bsum = 0.f; bden = 0.f;
    for (int t2 = 0; t2 < t; ++t2) { bsum += segT[t2 * 64 + h]; bden += segD[t2]; }
    r = bsum; rd = bden;
    for (int q = qs; q < qe; ++q) {
        PreE[(base + q) * 64 + h] = r;
        if (h == 0) PreD[base + q] = rd;
        float w = w2L[q];
        r += w * xwb[(size_t)si[q] * 64 + h];
        rd += w;
    }
    if (t == NSEG - 1) { PreE[(base + 343) * 64 + h] = r; if (h == 0) PreD[base + 343] = rd; }
}

// wave per (b,i): exact GAT row via sorted prefix/suffix sums + head mix + l2norm + relu
template <int STORE>
__global__ __launch_bounds__(256) void k_gatfin(
    const float* __restrict__ sdst, const float* __restrict__ ssort,
    const float* __restrict__ SufE, const float* __restrict__ PreE,
    const float* __restrict__ SufD, const float* __restrict__ PreD,
    const float* __restrict__ bg, const float* __restrict__ hw, const float* __restrict__ hb,
    float* __restrict__ outrows, float* __restrict__ spatial, int soff)
{
    int wv = threadIdx.x >> 6, ln = threadIdx.x & 63;
    int idx = blockIdx.x * 4 + wv;           // grid covers B*N exactly
    int b = idx / N_;
    float di = sdst[idx];
    const float* ss = ssort + (size_t)b * 344;
    float key = -di;
    int lo = 0, hi = N_;
    while (lo < hi) { int mid = (lo + hi) >> 1; if (ss[mid] >= key) hi = mid; else lo = mid + 1; }
    int p = lo;
    float ed = __expf(di), e2 = __expf(0.2f * di);
    size_t base = (size_t)b * 344 + p;
    float acc = ed * SufE[base * 64 + ln] + e2 * PreE[base * 64 + ln];
    float den = ed * SufD[base] + e2 * PreD[base];
    float g = acc / den + bg[ln];
    int k = ln >> 4;
    float y = hb[ln];
    const float* hwr = hw + ln * 16;
#pragma unroll
    for (int d = 0; d < 16; ++d) y += hwr[d] * __shfl(g, (k << 4) | d);
    float ssum = y * y;
#pragma unroll
    for (int s = 1; s < 64; s <<= 1) ssum += __shfl_xor(ssum, s);
    float rr = 1.f / fmaxf(sqrtf(ssum), 1e-12f);
    y = fmaxf(y * rr, 0.f);
    if (STORE) outrows[(size_t)idx * 64 + ln] = y;
    atomicAdd(&spatial[b * 128 + soff + ln], y);
}

__global__ void k_final(const float* __restrict__ spatial, const float* __restrict__ spectral,
                        const float* __restrict__ Wf, const float* __restrict__ bf_,
                        float* __restrict__ out)
{
    int b = blockIdx.x, ln = threadIdx.x;  // 64 threads
    float inv = 1.f / (float)N_;
    float e0 = spatial[b * 128 + ln] * inv;
    float e1 = spatial[b * 128 + 64 + ln] * inv;
    float e2 = spectral[b * 64 + ln] * inv;
#pragma unroll
    for (int c = 0; c < 2; c++) {
        float a = e0 * Wf[c * 192 + ln] + e1 * Wf[c * 192 + 64 + ln] + e2 * Wf[c * 192 + 128 + ln];
#pragma unroll
        for (int s = 1; s < 64; s <<= 1) a += __shfl_xor(a, s);
        if (ln == 0) out[b * 2 + c] = a + bf_[c];
    }
}

extern "C" void kernel_launch(void* const* d_in, const int* in_sizes, int n_in,
                              void* d_out, int out_size, void* d_ws, size_t ws_size,
                              hipStream_t stream)
{
    const float* reps = (const float*)d_in[0];
    const float* Wm1  = (const float*)d_in[1];
    const float* bm1  = (const float*)d_in[2];
    const float* Wm2  = (const float*)d_in[3];
    const float* bm2  = (const float*)d_in[4];
    const float* Wg1  = (const float*)d_in[5];
    const float* a1s  = (const float*)d_in[6];
    const float* a1d  = (const float*)d_in[7];
    const float* bg1  = (const float*)d_in[8];
    const float* hw1  = (const float*)d_in[9];
    const float* hb1  = (const float*)d_in[10];
    const float* Wg2  = (const float*)d_in[11];
    const float* a2s  = (const float*)d_in[12];
    const float* a2d  = (const float*)d_in[13];
    const float* bg2  = (const float*)d_in[14];
    const float* hw3  = (const float*)d_in[15];
    const float* hb3  = (const float*)d_in[16];
    const float* Ws1  = (const float*)d_in[17];
    const float* bs1  = (const float*)d_in[18];
    const float* Ws2  = (const float*)d_in[19];
    const float* bs2  = (const float*)d_in[20];
    const float* Wf   = (const float*)d_in[21];
    const float* bf_  = (const float*)d_in[22];

    float* ws = (float*)d_ws;
    float* Wm1T = ws + OFF_WM1T;
    float* Wm2T = ws + OFF_WM2T;
    float* Wg1T = ws + OFF_WG1T;
    float* Wg2T = ws + OFF_WG2T;
    float* Ws1T = ws + OFF_WS1T;
    float* Ws2T = ws + OFF_WS2T;
    float* spat = ws + OFF_SPAT;
    float* spec = ws + OFF_SPEC;
    float* ssrc = ws + OFF_SSRC;
    float* sdst = ws + OFF_SDST;
    float* ssort= ws + OFF_SSORT;
    float* SufD = ws + OFF_SUFD;
    float* PreD = ws + OFF_PRED;
    float* node = ws + OFF_NODE;
    float* SufE = ws + OFF_SUFE;
    float* PreE = ws + OFF_PREE;
    float* xwb  = ws + OFF_XW;
    float* out1 = ws + OFF_OUT1;
    // bf16 overlays (each dead before its host region is written)
    unsigned short* gXf16 = (unsigned short*)(ws + OFF_SUFE);   // until k_sortscan L1
    unsigned short* gXt16 = (unsigned short*)(ws + OFF_PREE);   // until k_sortscan L1
    unsigned short* gN16  = (unsigned short*)(ws + OFF_XW);     // until k_tr (then agg overwrites)
    unsigned short* gNT16 = (unsigned short*)(ws + OFF_OUT1);   // until k_gatfin L1
    float* agg = xwb;                                           // until k_xw L1

    hipMemsetAsync(spat, 0, (16384 + 8192) * sizeof(float), stream);
    k_prep<<<32, 256, 0, stream>>>(Wm1, Wm2, Wg1, Wg2, Ws1, Ws2,
                                   Wm1T, Wm2T, Wg1T, Wg2T, Ws1T, Ws2T);
    k_node<<<NODE_NB, 256, 0, stream>>>(reps, Wm1T, bm1, Wm2T, bm2,
                                        node, gXf16, gXt16, gN16);
    k_tr<<<B_ * 6, 256, 0, stream>>>(gN16, gNT16);
    k_sim_mfma<<<B_ * 6, 256, 0, stream>>>(gXf16, gXt16, gNT16, agg);
    k_smlp<<<NODE_NB, 256, 0, stream>>>(agg, Ws1T, bs1, Ws2T, bs2, spec);
    // ---- GAT layer 1 ----
    k_xw<<<NODE_NB, 256, 0, stream>>>(node, Wg1T, a1s, a1d, xwb, ssrc, sdst);
    k_sortscan<<<B_, 1024, 0, stream>>>(ssrc, xwb, ssort, SufE, PreE, SufD, PreD);
    k_gatfin<1><<<(B_ * N_) / 4, 256, 0, stream>>>(sdst, ssort, SufE, PreE, SufD, PreD,
                                                   bg1, hw1, hb1, out1, spat, 0);
    // ---- GAT layer 2 ----
    k_xw<<<NODE_NB, 256, 0, stream>>>(out1, Wg2T, a2s, a2d, xwb, ssrc, sdst);
    k_sortscan<<<B_, 1024, 0, stream>>>(ssrc, xwb, ssort, SufE, PreE, SufD, PreD);
    k_gatfin<0><<<(B_ * N_) / 4, 256, 0, stream>>>(sdst, ssort, SufE, PreE, SufD, PreD,
                                                   bg2, hw3, hb3, nullptr, spat, 64);
    k_final<<<B_, 64, 0, stream>>>(spat, spec, Wf, bf_, (float*)d_out);
}

// Round 8
// 342.789 us; speedup vs baseline: 3.2760x; 1.3512x over previous
//
#include <hip/hip_runtime.h>
#include <math.h>

#define B_ 128
#define T_ 8
#define P_ 49
#define H_ 64
#define N_ 343
#define THRESH 0.6f
#define NSLOPE 0.2f

typedef float  f32x4  __attribute__((ext_vector_type(4)));
typedef short  s16x4  __attribute__((ext_vector_type(4)));
typedef short  s16x8  __attribute__((ext_vector_type(8)));
typedef unsigned short ushort_t;

// workspace layout (float offsets) — total 14,338,816 floats = 57.4 MB
#define OFF_WG2T 0              // 4096 f32 (k_xw L2)
#define OFF_WM1B 8192           // 8192 bf16 = 4096 floats
#define OFF_WM2B 12288          // 4096 bf16
#define OFF_WG1B 16384          // 4096 bf16
#define OFF_WS1B 20480          // 4096 bf16
#define OFF_WS2B 24576          // 4096 bf16
#define OFF_SPAT 28672          // B*128 spatial mean accumulator
#define OFF_SPEC 45056          // B*64 spectral mean accumulator
#define OFF_SSRC 53248          // B*N
#define OFF_SDST 97152          // B*N
#define OFF_SSORT 141056        // B*344
#define OFF_SUFD 185088         // B*344
#define OFF_PRED 229120         // B*344
#define OFF_SUFE 3083008        // B*344*64   (bf16 Xf16 overlay until k_sortscan L1)
#define OFF_PREE 5901056        // B*344*64   (bf16 Xt16 overlay until k_sortscan L1)
#define OFF_XW   8719104        // B*N*64     (xw f32; L1 written by k_node_mfma)
#define OFF_OUT1 11528960       // B*N*64     (bf16 nodeT16 overlay until k_gatfin L1)

__device__ __forceinline__ ushort_t f2bf(float v) {
    union { float f; unsigned int u; } c; c.f = v;
    unsigned int r = c.u + 0x7FFFu + ((c.u >> 16) & 1u);
    return (ushort_t)(r >> 16);
}
__device__ __forceinline__ s16x8 pack8(float4 a, float4 b, float s) {
    s16x8 r;
    r[0] = (short)f2bf(a.x * s); r[1] = (short)f2bf(a.y * s);
    r[2] = (short)f2bf(a.z * s); r[3] = (short)f2bf(a.w * s);
    r[4] = (short)f2bf(b.x * s); r[5] = (short)f2bf(b.y * s);
    r[6] = (short)f2bf(b.z * s); r[7] = (short)f2bf(b.w * s);
    return r;
}
__device__ __forceinline__ float dot4(float4 a) { return a.x*a.x + a.y*a.y + a.z*a.z + a.w*a.w; }

__global__ void k_prep(const float* __restrict__ Wm1, const float* __restrict__ Wm2,
                       const float* __restrict__ Wg1, const float* __restrict__ Wg2,
                       const float* __restrict__ Ws1, const float* __restrict__ Ws2,
                       float* __restrict__ Wg2T,
                       ushort_t* __restrict__ gWm1b, ushort_t* __restrict__ gWm2b,
                       ushort_t* __restrict__ gWg1b, ushort_t* __restrict__ gWs1b,
                       ushort_t* __restrict__ gWs2b) {
    int t = blockIdx.x * 256 + threadIdx.x;
    if (t < 8192) gWm1b[t] = f2bf(Wm1[t]);
    if (t < 4096) {
        int r = t >> 6, c = t & 63;
        Wg2T[c * 64 + r] = Wg2[t];
        gWm2b[t] = f2bf(Wm2[t]);
        gWg1b[t] = f2bf(Wg1[t]);
        gWs1b[t] = f2bf(Ws1[t]);
        gWs2b[t] = f2bf(Ws2[t]);
    }
}

// MFMA node pipeline: cat -> MLP1 -> MLP2 -> xw1 GEMM + attention dots.
// Recipe (verified in k_sim): mfma(A from LDS rows X, B from reg-rows Y):
//   D at lane(kg,m), reg r  =  sum_k X[Abase+4kg+r][k] * Y[Bbase+m][k]
#define CATS 136
__global__ __launch_bounds__(256) void k_node_mfma(
    const float* __restrict__ reps,
    const ushort_t* __restrict__ gWm1b, const float* __restrict__ bm1,
    const ushort_t* __restrict__ gWm2b, const float* __restrict__ bm2,
    const ushort_t* __restrict__ gWg1b, const float* __restrict__ a1s, const float* __restrict__ a1d,
    ushort_t* __restrict__ gXf16, ushort_t* __restrict__ gXt16, ushort_t* __restrict__ gNT16,
    float* __restrict__ xw, float* __restrict__ ssrc, float* __restrict__ sdst)
{
    __shared__ __align__(16) ushort_t sCat[64 * CATS];   // 17408 B (cat bf16, later node bf16)
    __shared__ __align__(16) ushort_t sW1[64 * CATS];    // Wm1 rows [o][k]
    __shared__ __align__(16) ushort_t sW2[64 * 72];      // Wm2 rows
    __shared__ __align__(16) ushort_t sWg[64 * 72];      // Wg1 rows
    __shared__ __align__(16) ushort_t hL[64 * 72];       // h1 bf16
    int tid = threadIdx.x;
    int b = blockIdx.x / 6, itile = blockIdx.x % 6;
    int i0 = itile * 64;

    for (int t = tid; t < 64 * 16; t += 256) {
        int row = t >> 4, grp = t & 15;
        *(s16x8*)&sW1[row * CATS + grp * 8] = *(const s16x8*)(gWm1b + row * 128 + grp * 8);
    }
    for (int t = tid; t < 64 * 8; t += 256) {
        int row = t >> 3, grp = t & 7;
        *(s16x8*)&sW2[row * 72 + grp * 8] = *(const s16x8*)(gWm2b + row * 64 + grp * 8);
        *(s16x8*)&sWg[row * 72 + grp * 8] = *(const s16x8*)(gWg1b + row * 64 + grp * 8);
    }
    {   // reps load + normalize + cat fill: thread = (row, 16-ch slice)
        int r = tid >> 2, slice = tid & 3;
        int n = i0 + r;
        bool valid = n < N_;
        int nn = valid ? n : N_ - 1;
        int f = nn / P_, p = nn - f * P_;
        const float* xfp = reps + (((size_t)b * T_ + f) * P_ + p) * H_ + slice * 16;
        const float* xtp = xfp + P_ * H_;
        float4 f0 = ((const float4*)xfp)[0], f1 = ((const float4*)xfp)[1];
        float4 f2 = ((const float4*)xfp)[2], f3 = ((const float4*)xfp)[3];
        float4 t0 = ((const float4*)xtp)[0], t1 = ((const float4*)xtp)[1];
        float4 t2 = ((const float4*)xtp)[2], t3 = ((const float4*)xtp)[3];
        float sfs = dot4(f0) + dot4(f1) + dot4(f2) + dot4(f3);
        float sts = dot4(t0) + dot4(t1) + dot4(t2) + dot4(t3);
        sfs += __shfl_xor(sfs, 1); sfs += __shfl_xor(sfs, 2);
        sts += __shfl_xor(sts, 1); sts += __shfl_xor(sts, 2);
        float rf = 1.f / (sqrtf(sfs) + 1e-4f);
        float rt = 1.f / (sqrtf(sts) + 1e-4f);
        if (valid) {
            ushort_t* pf = gXf16 + ((size_t)b * N_ + n) * 64 + slice * 16;
            ushort_t* pt = gXt16 + ((size_t)b * N_ + n) * 64 + slice * 16;
            *(s16x8*)pf       = pack8(f0, f1, rf);
            *(s16x8*)(pf + 8) = pack8(f2, f3, rf);
            *(s16x8*)pt       = pack8(t0, t1, rt);
            *(s16x8*)(pt + 8) = pack8(t2, t3, rt);
        }
        *(s16x8*)&sCat[r * CATS + slice * 16]      = pack8(f0, f1, 1.f);
        *(s16x8*)&sCat[r * CATS + slice * 16 + 8]  = pack8(f2, f3, 1.f);
        *(s16x8*)&sCat[r * CATS + 64 + slice * 16]     = pack8(t0, t1, 1.f);
        *(s16x8*)&sCat[r * CATS + 64 + slice * 16 + 8] = pack8(t2, t3, 1.f);
    }
    __syncthreads();

    int w = tid >> 6, l = tid & 63, kg = l >> 4, m = l & 15;
    int R = w * 16;
    // ---- MLP1: cat(128) @ Wm1 rows ----
    f32x4 acc1[4];
#pragma unroll
    for (int ht = 0; ht < 4; ++ht) acc1[ht] = (f32x4){0.f, 0.f, 0.f, 0.f};
#pragma unroll
    for (int kc = 0; kc < 4; ++kc) {
        s16x4 alo = *(const s16x4*)&sCat[(R + m) * CATS + kc * 32 + 4 * kg];
        s16x4 ahi = *(const s16x4*)&sCat[(R + m) * CATS + kc * 32 + 16 + 4 * kg];
        s16x8 av = __builtin_shufflevector(alo, ahi, 0, 1, 2, 3, 4, 5, 6, 7);
#pragma unroll
        for (int ht = 0; ht < 4; ++ht) {
            s16x4 blo = *(const s16x4*)&sW1[(ht * 16 + m) * CATS + kc * 32 + 4 * kg];
            s16x4 bhi = *(const s16x4*)&sW1[(ht * 16 + m) * CATS + kc * 32 + 16 + 4 * kg];
            s16x8 bv = __builtin_shufflevector(blo, bhi, 0, 1, 2, 3, 4, 5, 6, 7);
            acc1[ht] = __builtin_amdgcn_mfma_f32_16x16x32_bf16(av, bv, acc1[ht], 0, 0, 0);
        }
    }
#pragma unroll
    for (int ht = 0; ht < 4; ++ht) {
        float b1 = bm1[ht * 16 + m];
#pragma unroll
        for (int r = 0; r < 4; ++r)
            hL[(R + 4 * kg + r) * 72 + ht * 16 + m] = f2bf(fmaxf(acc1[ht][r] + b1, 0.f));
    }
    __syncthreads();
    // ---- MLP2: h1(64) @ Wm2 rows ----
    f32x4 acc2[4];
#pragma unroll
    for (int ht = 0; ht < 4; ++ht) acc2[ht] = (f32x4){0.f, 0.f, 0.f, 0.f};
#pragma unroll
    for (int kc = 0; kc < 2; ++kc) {
        s16x4 alo = *(const s16x4*)&hL[(R + m) * 72 + kc * 32 + 4 * kg];
        s16x4 ahi = *(const s16x4*)&hL[(R + m) * 72 + kc * 32 + 16 + 4 * kg];
        s16x8 av = __builtin_shufflevector(alo, ahi, 0, 1, 2, 3, 4, 5, 6, 7);
#pragma unroll
        for (int ht = 0; ht < 4; ++ht) {
            s16x4 blo = *(const s16x4*)&sW2[(ht * 16 + m) * 72 + kc * 32 + 4 * kg];
            s16x4 bhi = *(const s16x4*)&sW2[(ht * 16 + m) * 72 + kc * 32 + 16 + 4 * kg];
            s16x8 bv = __builtin_shufflevector(blo, bhi, 0, 1, 2, 3, 4, 5, 6, 7);
            acc2[ht] = __builtin_amdgcn_mfma_f32_16x16x32_bf16(av, bv, acc2[ht], 0, 0, 0);
        }
    }
    __syncthreads();   // all waves done reading sCat (MLP1) before overwrite
#pragma unroll
    for (int ht = 0; ht < 4; ++ht) {
        float b2 = bm2[ht * 16 + m];
        int ibase = i0 + R + 4 * kg;
        ushort_t nb[4];
#pragma unroll
        for (int r = 0; r < 4; ++r) {
            nb[r] = f2bf(acc2[ht][r] + b2);
            sCat[(R + 4 * kg + r) * CATS + ht * 16 + m] = nb[r];
        }
        ushort_t* dst = gNT16 + ((size_t)b * 64 + ht * 16 + m) * 344 + ibase;
        if (ibase + 3 < N_) {
            s16x4 v; v[0] = (short)nb[0]; v[1] = (short)nb[1]; v[2] = (short)nb[2]; v[3] = (short)nb[3];
            *(s16x4*)dst = v;
        } else {
#pragma unroll
            for (int r = 0; r < 4; ++r) if (ibase + r < N_) dst[r] = nb[r];
        }
    }
    __syncthreads();
    // ---- XW: node(64) @ Wg1 rows + attention dots ----
    f32x4 acc3[4];
#pragma unroll
    for (int ht = 0; ht < 4; ++ht) acc3[ht] = (f32x4){0.f, 0.f, 0.f, 0.f};
#pragma unroll
    for (int kc = 0; kc < 2; ++kc) {
        s16x4 alo = *(const s16x4*)&sCat[(R + m) * CATS + kc * 32 + 4 * kg];
        s16x4 ahi = *(const s16x4*)&sCat[(R + m) * CATS + kc * 32 + 16 + 4 * kg];
        s16x8 av = __builtin_shufflevector(alo, ahi, 0, 1, 2, 3, 4, 5, 6, 7);
#pragma unroll
        for (int ht = 0; ht < 4; ++ht) {
            s16x4 blo = *(const s16x4*)&sWg[(ht * 16 + m) * 72 + kc * 32 + 4 * kg];
            s16x4 bhi = *(const s16x4*)&sWg[(ht * 16 + m) * 72 + kc * 32 + 16 + 4 * kg];
            s16x8 bv = __builtin_shufflevector(blo, bhi, 0, 1, 2, 3, 4, 5, 6, 7);
            acc3[ht] = __builtin_amdgcn_mfma_f32_16x16x32_bf16(av, bv, acc3[ht], 0, 0, 0);
        }
    }
    float a1sv[4], a1dv[4];
#pragma unroll
    for (int ht = 0; ht < 4; ++ht) { a1sv[ht] = a1s[ht * 16 + m]; a1dv[ht] = a1d[ht * 16 + m]; }
#pragma unroll
    for (int r = 0; r < 4; ++r) {
        int i = i0 + R + 4 * kg + r;
        float sr = acc3[0][r] * a1sv[0] + acc3[1][r] * a1sv[1] + acc3[2][r] * a1sv[2] + acc3[3][r] * a1sv[3];
        float dr = acc3[0][r] * a1dv[0] + acc3[1][r] * a1dv[1] + acc3[2][r] * a1dv[2] + acc3[3][r] * a1dv[3];
        sr += __shfl_xor(sr, 1); sr += __shfl_xor(sr, 2);
        sr += __shfl_xor(sr, 4); sr += __shfl_xor(sr, 8);
        dr += __shfl_xor(dr, 1); dr += __shfl_xor(dr, 2);
        dr += __shfl_xor(dr, 4); dr += __shfl_xor(dr, 8);
        if (m == 0 && i < N_) { ssrc[b * N_ + i] = sr; sdst[b * N_ + i] = dr; }
#pragma unroll
        for (int ht = 0; ht < 4; ++ht)
            if (i < N_) xw[((size_t)b * N_ + i) * 64 + ht * 16 + m] = acc3[ht][r];
    }
}

// MFMA flash-style sim + aggregate + FUSED spectral MLP (atomicAdd into spec)
__global__ __launch_bounds__(256, 3) void k_sim_mfma(
    const ushort_t* __restrict__ gXf, const ushort_t* __restrict__ gXt,
    const ushort_t* __restrict__ gNT,
    const ushort_t* __restrict__ gWs1b, const float* __restrict__ bs1,
    const ushort_t* __restrict__ gWs2b, const float* __restrict__ bs2,
    float* __restrict__ spec)
{
    __shared__ __align__(16) short sXf[64 * 72];
    __shared__ __align__(16) short sXt[64 * 72];
    __shared__ __align__(16) short sNT[64 * 72];
    int tid = threadIdx.x;
    int b = blockIdx.x / 6, itile = blockIdx.x % 6;
    int wv = tid >> 6, l = tid & 63;
    int kg = l >> 4, m = l & 15;
    int i0 = itile * 64;
    const ushort_t* gXfb = gXf + (size_t)b * N_ * 64;
    const ushort_t* gXtb = gXt + (size_t)b * N_ * 64;
    const ushort_t* gNTb = gNT + (size_t)b * 64 * 344;

    int ri = i0 + wv * 16 + m; if (ri > N_ - 1) ri = N_ - 1;
    s16x8 xfiB[2], xtiB[2];
#pragma unroll
    for (int c2 = 0; c2 < 2; ++c2) {
        s16x4 flo = *(const s16x4*)(gXfb + (size_t)ri * 64 + 32 * c2 + 4 * kg);
        s16x4 fhi = *(const s16x4*)(gXfb + (size_t)ri * 64 + 32 * c2 + 16 + 4 * kg);
        s16x4 tlo = *(const s16x4*)(gXtb + (size_t)ri * 64 + 32 * c2 + 4 * kg);
        s16x4 thi = *(const s16x4*)(gXtb + (size_t)ri * 64 + 32 * c2 + 16 + 4 * kg);
        xfiB[c2] = __builtin_shufflevector(flo, fhi, 0, 1, 2, 3, 4, 5, 6, 7);
        xtiB[c2] = __builtin_shufflevector(tlo, thi, 0, 1, 2, 3, 4, 5, 6, 7);
    }

    f32x4 accPV[4];
#pragma unroll
    for (int ht = 0; ht < 4; ++ht) accPV[ht] = (f32x4){0.f, 0.f, 0.f, 0.f};

#pragma unroll 1
    for (int chunk = 0; chunk < 6; ++chunk) {
        int j0 = chunk * 64;
        __syncthreads();
        for (int s = tid; s < 512; s += 256) {
            int row = s >> 3, grp = s & 7;
            int j = j0 + row;
            s16x8 vf = {0, 0, 0, 0, 0, 0, 0, 0};
            s16x8 vt = {0, 0, 0, 0, 0, 0, 0, 0};
            s16x8 vn = {0, 0, 0, 0, 0, 0, 0, 0};
            if (j < N_) {
                vf = *(const s16x8*)(gXfb + (size_t)j * 64 + grp * 8);
                vt = *(const s16x8*)(gXtb + (size_t)j * 64 + grp * 8);
            }
            if (j0 + grp * 8 + 8 <= 344)
                vn = *(const s16x8*)(gNTb + (size_t)row * 344 + j0 + grp * 8);
            *(s16x8*)(&sXf[row * 72 + grp * 8]) = vf;
            *(s16x8*)(&sXt[row * 72 + grp * 8]) = vt;
            *(s16x8*)(&sNT[row * 72 + grp * 8]) = vn;
        }
        __syncthreads();
        int npair = (chunk == 5) ? 1 : 2;
#pragma unroll 1
        for (int pr = 0; pr < npair; ++pr) {
            s16x8 pa;
#pragma unroll
            for (int sub = 0; sub < 2; ++sub) {
                int arow = (pr * 2 + sub) * 16 + m;
                f32x4 sf = (f32x4){0.f, 0.f, 0.f, 0.f};
                f32x4 st = (f32x4){0.f, 0.f, 0.f, 0.f};
#pragma unroll
                for (int hc = 0; hc < 2; ++hc) {
                    int h0 = hc * 32;
                    s16x4 alo = *(const s16x4*)(&sXf[arow * 72 + h0 + 4 * kg]);
                    s16x4 ahi = *(const s16x4*)(&sXf[arow * 72 + h0 + 16 + 4 * kg]);
                    s16x8 av = __builtin_shufflevector(alo, ahi, 0, 1, 2, 3, 4, 5, 6, 7);
                    sf = __builtin_amdgcn_mfma_f32_16x16x32_bf16(av, xfiB[hc], sf, 0, 0, 0);
                    s16x4 blo = *(const s16x4*)(&sXt[arow * 72 + h0 + 4 * kg]);
                    s16x4 bhi = *(const s16x4*)(&sXt[arow * 72 + h0 + 16 + 4 * kg]);
                    s16x8 bv = __builtin_shufflevector(blo, bhi, 0, 1, 2, 3, 4, 5, 6, 7);
                    st = __builtin_amdgcn_mfma_f32_16x16x32_bf16(bv, xtiB[hc], st, 0, 0, 0);
                }
#pragma unroll
                for (int r = 0; r < 4; ++r) {
                    float v = fmaxf(sf[r], st[r]);
                    v = (v > THRESH) ? v : 0.f;
                    pa[sub * 4 + r] = (short)f2bf(v);
                }
            }
            int jl0 = pr * 32;
#pragma unroll
            for (int ht = 0; ht < 4; ++ht) {
                s16x4 nlo = *(const s16x4*)(&sNT[(ht * 16 + m) * 72 + jl0 + 4 * kg]);
                s16x4 nhi = *(const s16x4*)(&sNT[(ht * 16 + m) * 72 + jl0 + 16 + 4 * kg]);
                s16x8 nv = __builtin_shufflevector(nlo, nhi, 0, 1, 2, 3, 4, 5, 6, 7);
                accPV[ht] = __builtin_amdgcn_mfma_f32_16x16x32_bf16(pa, nv, accPV[ht], 0, 0, 0);
            }
        }
    }
    // ---- fused spectral MLP epilogue ----
    __syncthreads();
    for (int t = tid; t < 64 * 8; t += 256) {      // Ws1 rows -> sXt
        int row = t >> 3, grp = t & 7;
        *(s16x8*)&sXt[row * 72 + grp * 8] = *(const s16x8*)(gWs1b + row * 64 + grp * 8);
    }
    int R = wv * 16;
#pragma unroll
    for (int ht = 0; ht < 4; ++ht)
#pragma unroll
        for (int r = 0; r < 4; ++r)
            sXf[(R + 4 * kg + r) * 72 + ht * 16 + m] = (short)f2bf(accPV[ht][r]);
    __syncthreads();
    f32x4 h4[4];
#pragma unroll
    for (int ht = 0; ht < 4; ++ht) h4[ht] = (f32x4){0.f, 0.f, 0.f, 0.f};
#pragma unroll
    for (int kc = 0; kc < 2; ++kc) {
        s16x4 alo = *(const s16x4*)&sXf[(R + m) * 72 + kc * 32 + 4 * kg];
        s16x4 ahi = *(const s16x4*)&sXf[(R + m) * 72 + kc * 32 + 16 + 4 * kg];
        s16x8 av = __builtin_shufflevector(alo, ahi, 0, 1, 2, 3, 4, 5, 6, 7);
#pragma unroll
        for (int ht = 0; ht < 4; ++ht) {
            s16x4 blo = *(const s16x4*)&sXt[(ht * 16 + m) * 72 + kc * 32 + 4 * kg];
            s16x4 bhi = *(const s16x4*)&sXt[(ht * 16 + m) * 72 + kc * 32 + 16 + 4 * kg];
            s16x8 bv = __builtin_shufflevector(blo, bhi, 0, 1, 2, 3, 4, 5, 6, 7);
            h4[ht] = __builtin_amdgcn_mfma_f32_16x16x32_bf16(av, bv, h4[ht], 0, 0, 0);
        }
    }
#pragma unroll
    for (int ht = 0; ht < 4; ++ht) {
        float b1 = bs1[ht * 16 + m];
#pragma unroll
        for (int r = 0; r < 4; ++r)
            sNT[(R + 4 * kg + r) * 72 + ht * 16 + m] = (short)f2bf(fmaxf(h4[ht][r] + b1, 0.f));
    }
    __syncthreads();
    for (int t = tid; t < 64 * 8; t += 256) {      // Ws2 rows -> sXt
        int row = t >> 3, grp = t & 7;
        *(s16x8*)&sXt[row * 72 + grp * 8] = *(const s16x8*)(gWs2b + row * 64 + grp * 8);
    }
    __syncthreads();
    f32x4 sp4[4];
#pragma unroll
    for (int ht = 0; ht < 4; ++ht) sp4[ht] = (f32x4){0.f, 0.f, 0.f, 0.f};
#pragma unroll
    for (int kc = 0; kc < 2; ++kc) {
        s16x4 alo = *(const s16x4*)&sNT[(R + m) * 72 + kc * 32 + 4 * kg];
        s16x4 ahi = *(const s16x4*)&sNT[(R + m) * 72 + kc * 32 + 16 + 4 * kg];
        s16x8 av = __builtin_shufflevector(alo, ahi, 0, 1, 2, 3, 4, 5, 6, 7);
#pragma unroll
        for (int ht = 0; ht < 4; ++ht) {
            s16x4 blo = *(const s16x4*)&sXt[(ht * 16 + m) * 72 + kc * 32 + 4 * kg];
            s16x4 bhi = *(const s16x4*)&sXt[(ht * 16 + m) * 72 + kc * 32 + 16 + 4 * kg];
            s16x8 bv = __builtin_shufflevector(blo, bhi, 0, 1, 2, 3, 4, 5, 6, 7);
            sp4[ht] = __builtin_amdgcn_mfma_f32_16x16x32_bf16(av, bv, sp4[ht], 0, 0, 0);
        }
    }
#pragma unroll
    for (int ht = 0; ht < 4; ++ht) {
        float b2 = bs2[ht * 16 + m];
        float s = 0.f;
#pragma unroll
        for (int r = 0; r < 4; ++r) {
            int i = i0 + R + 4 * kg + r;
            s += (i < N_) ? (sp4[ht][r] + b2) : 0.f;
        }
        s += __shfl_xor(s, 16); s += __shfl_xor(s, 32);
        if (l < 16) atomicAdd(&spec[b * 64 + ht * 16 + m], s);
    }
}

#define NODE_NB 1024
// xw = x @ WgT + attention scalars (layer 2, f32 VALU)
__global__ __launch_bounds__(256) void k_xw(
    const float* __restrict__ x, const float* __restrict__ WgT,
    const float* __restrict__ as_, const float* __restrict__ ad_,
    float* __restrict__ xw, float* __restrict__ ssrc, float* __restrict__ sdst)
{
    __shared__ float sW[4096];
    __shared__ float xs[4][64];
    int tid = threadIdx.x;
    for (int t = tid; t < 1024; t += 256) ((float4*)sW)[t] = ((const float4*)WgT)[t];
    __syncthreads();
    int wv = tid >> 6, ln = tid & 63;
    float asv = as_[ln], adv = ad_[ln];
    for (int g = blockIdx.x; g < (B_ * N_) / 4; g += NODE_NB) {
        int idx = g * 4 + wv;
        size_t row = (size_t)idx * H_;
        xs[wv][ln] = x[row + ln];
        float a0 = 0.f, a1 = 0.f, a2 = 0.f, a3 = 0.f;
#pragma unroll 4
        for (int h = 0; h < 64; h += 4) {
            a0 += xs[wv][h]     * sW[h * 64 + ln];
            a1 += xs[wv][h + 1] * sW[(h + 1) * 64 + ln];
            a2 += xs[wv][h + 2] * sW[(h + 2) * 64 + ln];
            a3 += xs[wv][h + 3] * sW[(h + 3) * 64 + ln];
        }
        float a = (a0 + a1) + (a2 + a3);
        xw[row + ln] = a;
        float ps = a * asv, pd = a * adv;
#pragma unroll
        for (int s = 1; s < 64; s <<= 1) { ps += __shfl_xor(ps, s); pd += __shfl_xor(pd, s); }
        if (ln == 0) { ssrc[idx] = ps; sdst[idx] = pd; }
    }
}

// per-batch: bitonic sort + PARALLEL segmented suffix/prefix weighted scans.
#define NSEG 16
#define SEGSZ 22
__global__ __launch_bounds__(1024) void k_sortscan(
    const float* __restrict__ ssrc, const float* __restrict__ xw,
    float* __restrict__ ssort, float* __restrict__ SufE, float* __restrict__ PreE,
    float* __restrict__ SufD, float* __restrict__ PreD)
{
    __shared__ float sv[512];
    __shared__ int   si[512];
    __shared__ float w1L[344], w2L[344];
    __shared__ float segT[NSEG * 64];
    __shared__ float segD[NSEG];
    int tid = threadIdx.x, b = blockIdx.x;
    for (int q = tid; q < 512; q += 1024) {
        sv[q] = (q < N_) ? ssrc[b * N_ + q] : 3.0e38f;
        si[q] = q;
    }
    __syncthreads();
    for (int k = 2; k <= 512; k <<= 1)
        for (int j = k >> 1; j > 0; j >>= 1) {
            for (int e = tid; e < 512; e += 1024) {
                int l = e ^ j;
                if (l > e) {
                    float a = sv[e], c = sv[l];
                    bool up = ((e & k) == 0);
                    if (up ? (a > c) : (a < c)) {
                        sv[e] = c; sv[l] = a;
                        int t = si[e]; si[e] = si[l]; si[l] = t;
                    }
                }
            }
            __syncthreads();
        }
    if (tid < N_) {
        float v = sv[tid];
        w1L[tid] = __expf(v);
        w2L[tid] = __expf(0.2f * v);
        ssort[(size_t)b * 344 + tid] = v;
    }
    __syncthreads();
    int t = tid >> 6, h = tid & 63;
    int qs = t * SEGSZ, qe = min(qs + SEGSZ, N_);
    const float* xwb = xw + (size_t)b * N_ * 64;
    size_t base = (size_t)b * 344;
    float r = 0.f, rd = 0.f;
    for (int q = qe - 1; q >= qs; --q) {
        float w = w1L[q];
        r += w * xwb[(size_t)si[q] * 64 + h];
        rd += w;
    }
    segT[t * 64 + h] = r; if (h == 0) segD[t] = rd;
    __syncthreads();
    float bsum = 0.f, bden = 0.f;
    for (int t2 = t + 1; t2 < NSEG; ++t2) { bsum += segT[t2 * 64 + h]; bden += segD[t2]; }
    r = bsum; rd = bden;
    for (int q = qe - 1; q >= qs; --q) {
        float w = w1L[q];
        r += w * xwb[(size_t)si[q] * 64 + h];
        rd += w;
        SufE[(base + q) * 64 + h] = r;
        if (h == 0) SufD[base + q] = rd;
    }
    if (t == 0) { SufE[(base + 343) * 64 + h] = 0.f; if (h == 0) SufD[base + 343] = 0.f; }
    __syncthreads();
    r = 0.f; rd = 0.f;
    for (int q = qs; q < qe; ++q) {
        float w = w2L[q];
        r += w * xwb[(size_t)si[q] * 64 + h];
        rd += w;
    }
    segT[t * 64 + h] = r; if (h == 0) segD[t] = rd;
    __syncthreads();
    bsum = 0.f; bden = 0.f;
    for (int t2 = 0; t2 < t; ++t2) { bsum += segT[t2 * 64 + h]; bden += segD[t2]; }
    r = bsum; rd = bden;
    for (int q = qs; q < qe; ++q) {
        PreE[(base + q) * 64 + h] = r;
        if (h == 0) PreD[base + q] = rd;
        float w = w2L[q];
        r += w * xwb[(size_t)si[q] * 64 + h];
        rd += w;
    }
    if (t == NSEG - 1) { PreE[(base + 343) * 64 + h] = r; if (h == 0) PreD[base + 343] = rd; }
}

// wave per (b,i): exact GAT row via sorted prefix/suffix sums + head mix + l2norm + relu
template <int STORE>
__global__ __launch_bounds__(256) void k_gatfin(
    const float* __restrict__ sdst, const float* __restrict__ ssort,
    const float* __restrict__ SufE, const float* __restrict__ PreE,
    const float* __restrict__ SufD, const float* __restrict__ PreD,
    const float* __restrict__ bg, const float* __restrict__ hw, const float* __restrict__ hb,
    float* __restrict__ outrows, float* __restrict__ spatial, int soff)
{
    int wv = threadIdx.x >> 6, ln = threadIdx.x & 63;
    int idx = blockIdx.x * 4 + wv;           // grid covers B*N exactly
    int b = idx / N_;
    float di = sdst[idx];
    const float* ss = ssort + (size_t)b * 344;
    float key = -di;
    int lo = 0, hi = N_;
    while (lo < hi) { int mid = (lo + hi) >> 1; if (ss[mid] >= key) hi = mid; else lo = mid + 1; }
    int p = lo;
    float ed = __expf(di), e2 = __expf(0.2f * di);
    size_t base = (size_t)b * 344 + p;
    float acc = ed * SufE[base * 64 + ln] + e2 * PreE[base * 64 + ln];
    float den = ed * SufD[base] + e2 * PreD[base];
    float g = acc / den + bg[ln];
    int k = ln >> 4;
    float y = hb[ln];
    const float* hwr = hw + ln * 16;
#pragma unroll
    for (int d = 0; d < 16; ++d) y += hwr[d] * __shfl(g, (k << 4) | d);
    float ssum = y * y;
#pragma unroll
    for (int s = 1; s < 64; s <<= 1) ssum += __shfl_xor(ssum, s);
    float rr = 1.f / fmaxf(sqrtf(ssum), 1e-12f);
    y = fmaxf(y * rr, 0.f);
    if (STORE) outrows[(size_t)idx * 64 + ln] = y;
    atomicAdd(&spatial[b * 128 + soff + ln], y);
}

__global__ void k_final(const float* __restrict__ spatial, const float* __restrict__ spectral,
                        const float* __restrict__ Wf, const float* __restrict__ bf_,
                        float* __restrict__ out)
{
    int b = blockIdx.x, ln = threadIdx.x;  // 64 threads
    float inv = 1.f / (float)N_;
    float e0 = spatial[b * 128 + ln] * inv;
    float e1 = spatial[b * 128 + 64 + ln] * inv;
    float e2 = spectral[b * 64 + ln] * inv;
#pragma unroll
    for (int c = 0; c < 2; c++) {
        float a = e0 * Wf[c * 192 + ln] + e1 * Wf[c * 192 + 64 + ln] + e2 * Wf[c * 192 + 128 + ln];
#pragma unroll
        for (int s = 1; s < 64; s <<= 1) a += __shfl_xor(a, s);
        if (ln == 0) out[b * 2 + c] = a + bf_[c];
    }
}

extern "C" void kernel_launch(void* const* d_in, const int* in_sizes, int n_in,
                              void* d_out, int out_size, void* d_ws, size_t ws_size,
                              hipStream_t stream)
{
    const float* reps = (const float*)d_in[0];
    const float* Wm1  = (const float*)d_in[1];
    const float* bm1  = (const float*)d_in[2];
    const float* Wm2  = (const float*)d_in[3];
    const float* bm2  = (const float*)d_in[4];
    const float* Wg1  = (const float*)d_in[5];
    const float* a1s  = (const float*)d_in[6];
    const float* a1d  = (const float*)d_in[7];
    const float* bg1  = (const float*)d_in[8];
    const float* hw1  = (const float*)d_in[9];
    const float* hb1  = (const float*)d_in[10];
    const float* Wg2  = (const float*)d_in[11];
    const float* a2s  = (const float*)d_in[12];
    const float* a2d  = (const float*)d_in[13];
    const float* bg2  = (const float*)d_in[14];
    const float* hw3  = (const float*)d_in[15];
    const float* hb3  = (const float*)d_in[16];
    const float* Ws1  = (const float*)d_in[17];
    const float* bs1  = (const float*)d_in[18];
    const float* Ws2  = (const float*)d_in[19];
    const float* bs2  = (const float*)d_in[20];
    const float* Wf   = (const float*)d_in[21];
    const float* bf_  = (const float*)d_in[22];

    float* ws = (float*)d_ws;
    float* Wg2T = ws + OFF_WG2T;
    ushort_t* gWm1b = (ushort_t*)(ws + OFF_WM1B);
    ushort_t* gWm2b = (ushort_t*)(ws + OFF_WM2B);
    ushort_t* gWg1b = (ushort_t*)(ws + OFF_WG1B);
    ushort_t* gWs1b = (ushort_t*)(ws + OFF_WS1B);
    ushort_t* gWs2b = (ushort_t*)(ws + OFF_WS2B);
    float* spat = ws + OFF_SPAT;
    float* spec = ws + OFF_SPEC;
    float* ssrc = ws + OFF_SSRC;
    float* sdst = ws + OFF_SDST;
    float* ssort= ws + OFF_SSORT;
    float* SufD = ws + OFF_SUFD;
    float* PreD = ws + OFF_PRED;
    float* SufE = ws + OFF_SUFE;
    float* PreE = ws + OFF_PREE;
    float* xwb  = ws + OFF_XW;
    float* out1 = ws + OFF_OUT1;
    // bf16 overlays (each dead before its host region is written)
    ushort_t* gXf16 = (ushort_t*)(ws + OFF_SUFE);   // until k_sortscan L1
    ushort_t* gXt16 = (ushort_t*)(ws + OFF_PREE);   // until k_sortscan L1
    ushort_t* gNT16 = (ushort_t*)(ws + OFF_OUT1);   // until k_gatfin L1

    hipMemsetAsync(spat, 0, (16384 + 8192) * sizeof(float), stream);
    k_prep<<<32, 256, 0, stream>>>(Wm1, Wm2, Wg1, Wg2, Ws1, Ws2,
                                   Wg2T, gWm1b, gWm2b, gWg1b, gWs1b, gWs2b);
    k_node_mfma<<<B_ * 6, 256, 0, stream>>>(reps, gWm1b, bm1, gWm2b, bm2,
                                            gWg1b, a1s, a1d,
                                            gXf16, gXt16, gNT16, xwb, ssrc, sdst);
    k_sim_mfma<<<B_ * 6, 256, 0, stream>>>(gXf16, gXt16, gNT16,
                                           gWs1b, bs1, gWs2b, bs2, spec);
    // ---- GAT layer 1 (xw/ssrc/sdst already produced by k_node_mfma) ----
    k_sortscan<<<B_, 1024, 0, stream>>>(ssrc, xwb, ssort, SufE, PreE, SufD, PreD);
    k_gatfin<1><<<(B_ * N_) / 4, 256, 0, stream>>>(sdst, ssort, SufE, PreE, SufD, PreD,
                                                   bg1, hw1, hb1, out1, spat, 0);
    // ---- GAT layer 2 ----
    k_xw<<<NODE_NB, 256, 0, stream>>>(out1, Wg2T, a2s, a2d, xwb, ssrc, sdst);
    k_sortscan<<<B_, 1024, 0, stream>>>(ssrc, xwb, ssort, SufE, PreE, SufD, PreD);
    k_gatfin<0><<<(B_ * N_) / 4, 256, 0, stream>>>(sdst, ssort, SufE, PreE, SufD, PreD,
                                                   bg2, hw3, hb3, nullptr, spat, 64);
    k_final<<<B_, 64, 0, stream>>>(spat, spec, Wf, bf_, (float*)d_out);
}

// Round 10
// 287.795 us; speedup vs baseline: 3.9020x; 1.1911x over previous
//
#include <hip/hip_runtime.h>
#include <math.h>

#define B_ 128
#define T_ 8
#define P_ 49
#define H_ 64
#define N_ 343
#define THRESH 0.6f
#define NSLOPE 0.2f

typedef float  f32x4  __attribute__((ext_vector_type(4)));
typedef short  s16x4  __attribute__((ext_vector_type(4)));
typedef short  s16x8  __attribute__((ext_vector_type(8)));
typedef unsigned short ushort_t;

// workspace layout (float offsets) — total 14,338,816 floats = 57.4 MB
#define OFF_WG2T 0              // 4096 f32
#define OFF_WM1B 8192           // 8192 bf16 = 4096 floats
#define OFF_WM2B 12288
#define OFF_WG1B 16384
#define OFF_WS1B 20480
#define OFF_WS2B 24576
#define OFF_SPAT 28672          // B*128 spatial mean accumulator
#define OFF_SPEC 45056          // B*64 spectral mean accumulator
#define OFF_SSRC 53248          // B*N
#define OFF_SDST 97152          // B*N
#define OFF_SSORT 141056        // B*344
#define OFF_SUFD 185088         // B*344
#define OFF_PRED 229120         // B*344
#define OFF_SUFE 3083008        // B*344*64   (bf16 Xf16 overlay until k_sortscan L1)
#define OFF_PREE 5901056        // B*344*64   (bf16 Xt16 overlay until k_sortscan L1)
#define OFF_XW   8719104        // B*N*64     (xw f32, L1 by k_node_mfma, L2 by k_gatfuse)
#define OFF_OUT1 11528960       // B*N*64     (bf16 nodeT16 overlay; out1 no longer needed)

__device__ __forceinline__ ushort_t f2bf(float v) {
    union { float f; unsigned int u; } c; c.f = v;
    unsigned int r = c.u + 0x7FFFu + ((c.u >> 16) & 1u);
    return (ushort_t)(r >> 16);
}
__device__ __forceinline__ s16x8 pack8(float4 a, float4 b, float s) {
    s16x8 r;
    r[0] = (short)f2bf(a.x * s); r[1] = (short)f2bf(a.y * s);
    r[2] = (short)f2bf(a.z * s); r[3] = (short)f2bf(a.w * s);
    r[4] = (short)f2bf(b.x * s); r[5] = (short)f2bf(b.y * s);
    r[6] = (short)f2bf(b.z * s); r[7] = (short)f2bf(b.w * s);
    return r;
}
__device__ __forceinline__ float dot4(float4 a) { return a.x*a.x + a.y*a.y + a.z*a.z + a.w*a.w; }

__global__ void k_prep(const float* __restrict__ Wm1, const float* __restrict__ Wm2,
                       const float* __restrict__ Wg1, const float* __restrict__ Wg2,
                       const float* __restrict__ Ws1, const float* __restrict__ Ws2,
                       float* __restrict__ Wg2T,
                       ushort_t* __restrict__ gWm1b, ushort_t* __restrict__ gWm2b,
                       ushort_t* __restrict__ gWg1b, ushort_t* __restrict__ gWs1b,
                       ushort_t* __restrict__ gWs2b) {
    int t = blockIdx.x * 256 + threadIdx.x;
    if (t < 8192) gWm1b[t] = f2bf(Wm1[t]);
    if (t < 4096) {
        int r = t >> 6, c = t & 63;
        Wg2T[c * 64 + r] = Wg2[t];
        gWm2b[t] = f2bf(Wm2[t]);
        gWg1b[t] = f2bf(Wg1[t]);
        gWs1b[t] = f2bf(Ws1[t]);
        gWs2b[t] = f2bf(Ws2[t]);
    }
}

// MFMA node pipeline: cat -> MLP1 -> MLP2 -> xw1 GEMM + attention dots. (verified R8)
#define CATS 136
__global__ __launch_bounds__(256) void k_node_mfma(
    const float* __restrict__ reps,
    const ushort_t* __restrict__ gWm1b, const float* __restrict__ bm1,
    const ushort_t* __restrict__ gWm2b, const float* __restrict__ bm2,
    const ushort_t* __restrict__ gWg1b, const float* __restrict__ a1s, const float* __restrict__ a1d,
    ushort_t* __restrict__ gXf16, ushort_t* __restrict__ gXt16, ushort_t* __restrict__ gNT16,
    float* __restrict__ xw, float* __restrict__ ssrc, float* __restrict__ sdst)
{
    __shared__ __align__(16) ushort_t sCat[64 * CATS];
    __shared__ __align__(16) ushort_t sW1[64 * CATS];
    __shared__ __align__(16) ushort_t sW2[64 * 72];
    __shared__ __align__(16) ushort_t sWg[64 * 72];
    __shared__ __align__(16) ushort_t hL[64 * 72];
    int tid = threadIdx.x;
    int b = blockIdx.x / 6, itile = blockIdx.x % 6;
    int i0 = itile * 64;

    for (int t = tid; t < 64 * 16; t += 256) {
        int row = t >> 4, grp = t & 15;
        *(s16x8*)&sW1[row * CATS + grp * 8] = *(const s16x8*)(gWm1b + row * 128 + grp * 8);
    }
    for (int t = tid; t < 64 * 8; t += 256) {
        int row = t >> 3, grp = t & 7;
        *(s16x8*)&sW2[row * 72 + grp * 8] = *(const s16x8*)(gWm2b + row * 64 + grp * 8);
        *(s16x8*)&sWg[row * 72 + grp * 8] = *(const s16x8*)(gWg1b + row * 64 + grp * 8);
    }
    {
        int r = tid >> 2, slice = tid & 3;
        int n = i0 + r;
        bool valid = n < N_;
        int nn = valid ? n : N_ - 1;
        int f = nn / P_, p = nn - f * P_;
        const float* xfp = reps + (((size_t)b * T_ + f) * P_ + p) * H_ + slice * 16;
        const float* xtp = xfp + P_ * H_;
        float4 f0 = ((const float4*)xfp)[0], f1 = ((const float4*)xfp)[1];
        float4 f2 = ((const float4*)xfp)[2], f3 = ((const float4*)xfp)[3];
        float4 t0 = ((const float4*)xtp)[0], t1 = ((const float4*)xtp)[1];
        float4 t2 = ((const float4*)xtp)[2], t3 = ((const float4*)xtp)[3];
        float sfs = dot4(f0) + dot4(f1) + dot4(f2) + dot4(f3);
        float sts = dot4(t0) + dot4(t1) + dot4(t2) + dot4(t3);
        sfs += __shfl_xor(sfs, 1); sfs += __shfl_xor(sfs, 2);
        sts += __shfl_xor(sts, 1); sts += __shfl_xor(sts, 2);
        float rf = 1.f / (sqrtf(sfs) + 1e-4f);
        float rt = 1.f / (sqrtf(sts) + 1e-4f);
        if (valid) {
            ushort_t* pf = gXf16 + ((size_t)b * N_ + n) * 64 + slice * 16;
            ushort_t* pt = gXt16 + ((size_t)b * N_ + n) * 64 + slice * 16;
            *(s16x8*)pf       = pack8(f0, f1, rf);
            *(s16x8*)(pf + 8) = pack8(f2, f3, rf);
            *(s16x8*)pt       = pack8(t0, t1, rt);
            *(s16x8*)(pt + 8) = pack8(t2, t3, rt);
        }
        *(s16x8*)&sCat[r * CATS + slice * 16]      = pack8(f0, f1, 1.f);
        *(s16x8*)&sCat[r * CATS + slice * 16 + 8]  = pack8(f2, f3, 1.f);
        *(s16x8*)&sCat[r * CATS + 64 + slice * 16]     = pack8(t0, t1, 1.f);
        *(s16x8*)&sCat[r * CATS + 64 + slice * 16 + 8] = pack8(t2, t3, 1.f);
    }
    __syncthreads();

    int w = tid >> 6, l = tid & 63, kg = l >> 4, m = l & 15;
    int R = w * 16;
    f32x4 acc1[4];
#pragma unroll
    for (int ht = 0; ht < 4; ++ht) acc1[ht] = (f32x4){0.f, 0.f, 0.f, 0.f};
#pragma unroll
    for (int kc = 0; kc < 4; ++kc) {
        s16x4 alo = *(const s16x4*)&sCat[(R + m) * CATS + kc * 32 + 4 * kg];
        s16x4 ahi = *(const s16x4*)&sCat[(R + m) * CATS + kc * 32 + 16 + 4 * kg];
        s16x8 av = __builtin_shufflevector(alo, ahi, 0, 1, 2, 3, 4, 5, 6, 7);
#pragma unroll
        for (int ht = 0; ht < 4; ++ht) {
            s16x4 blo = *(const s16x4*)&sW1[(ht * 16 + m) * CATS + kc * 32 + 4 * kg];
            s16x4 bhi = *(const s16x4*)&sW1[(ht * 16 + m) * CATS + kc * 32 + 16 + 4 * kg];
            s16x8 bv = __builtin_shufflevector(blo, bhi, 0, 1, 2, 3, 4, 5, 6, 7);
            acc1[ht] = __builtin_amdgcn_mfma_f32_16x16x32_bf16(av, bv, acc1[ht], 0, 0, 0);
        }
    }
#pragma unroll
    for (int ht = 0; ht < 4; ++ht) {
        float b1 = bm1[ht * 16 + m];
#pragma unroll
        for (int r = 0; r < 4; ++r)
            hL[(R + 4 * kg + r) * 72 + ht * 16 + m] = f2bf(fmaxf(acc1[ht][r] + b1, 0.f));
    }
    __syncthreads();
    f32x4 acc2[4];
#pragma unroll
    for (int ht = 0; ht < 4; ++ht) acc2[ht] = (f32x4){0.f, 0.f, 0.f, 0.f};
#pragma unroll
    for (int kc = 0; kc < 2; ++kc) {
        s16x4 alo = *(const s16x4*)&hL[(R + m) * 72 + kc * 32 + 4 * kg];
        s16x4 ahi = *(const s16x4*)&hL[(R + m) * 72 + kc * 32 + 16 + 4 * kg];
        s16x8 av = __builtin_shufflevector(alo, ahi, 0, 1, 2, 3, 4, 5, 6, 7);
#pragma unroll
        for (int ht = 0; ht < 4; ++ht) {
            s16x4 blo = *(const s16x4*)&sW2[(ht * 16 + m) * 72 + kc * 32 + 4 * kg];
            s16x4 bhi = *(const s16x4*)&sW2[(ht * 16 + m) * 72 + kc * 32 + 16 + 4 * kg];
            s16x8 bv = __builtin_shufflevector(blo, bhi, 0, 1, 2, 3, 4, 5, 6, 7);
            acc2[ht] = __builtin_amdgcn_mfma_f32_16x16x32_bf16(av, bv, acc2[ht], 0, 0, 0);
        }
    }
    __syncthreads();
#pragma unroll
    for (int ht = 0; ht < 4; ++ht) {
        float b2 = bm2[ht * 16 + m];
        int ibase = i0 + R + 4 * kg;
        ushort_t nb[4];
#pragma unroll
        for (int r = 0; r < 4; ++r) {
            nb[r] = f2bf(acc2[ht][r] + b2);
            sCat[(R + 4 * kg + r) * CATS + ht * 16 + m] = nb[r];
        }
        ushort_t* dst = gNT16 + ((size_t)b * 64 + ht * 16 + m) * 344 + ibase;
        if (ibase + 3 < N_) {
            s16x4 v; v[0] = (short)nb[0]; v[1] = (short)nb[1]; v[2] = (short)nb[2]; v[3] = (short)nb[3];
            *(s16x4*)dst = v;
        } else {
#pragma unroll
            for (int r = 0; r < 4; ++r) if (ibase + r < N_) dst[r] = nb[r];
        }
    }
    __syncthreads();
    f32x4 acc3[4];
#pragma unroll
    for (int ht = 0; ht < 4; ++ht) acc3[ht] = (f32x4){0.f, 0.f, 0.f, 0.f};
#pragma unroll
    for (int kc = 0; kc < 2; ++kc) {
        s16x4 alo = *(const s16x4*)&sCat[(R + m) * CATS + kc * 32 + 4 * kg];
        s16x4 ahi = *(const s16x4*)&sCat[(R + m) * CATS + kc * 32 + 16 + 4 * kg];
        s16x8 av = __builtin_shufflevector(alo, ahi, 0, 1, 2, 3, 4, 5, 6, 7);
#pragma unroll
        for (int ht = 0; ht < 4; ++ht) {
            s16x4 blo = *(const s16x4*)&sWg[(ht * 16 + m) * 72 + kc * 32 + 4 * kg];
            s16x4 bhi = *(const s16x4*)&sWg[(ht * 16 + m) * 72 + kc * 32 + 16 + 4 * kg];
            s16x8 bv = __builtin_shufflevector(blo, bhi, 0, 1, 2, 3, 4, 5, 6, 7);
            acc3[ht] = __builtin_amdgcn_mfma_f32_16x16x32_bf16(av, bv, acc3[ht], 0, 0, 0);
        }
    }
    float a1sv[4], a1dv[4];
#pragma unroll
    for (int ht = 0; ht < 4; ++ht) { a1sv[ht] = a1s[ht * 16 + m]; a1dv[ht] = a1d[ht * 16 + m]; }
#pragma unroll
    for (int r = 0; r < 4; ++r) {
        int i = i0 + R + 4 * kg + r;
        float sr = acc3[0][r] * a1sv[0] + acc3[1][r] * a1sv[1] + acc3[2][r] * a1sv[2] + acc3[3][r] * a1sv[3];
        float dr = acc3[0][r] * a1dv[0] + acc3[1][r] * a1dv[1] + acc3[2][r] * a1dv[2] + acc3[3][r] * a1dv[3];
        sr += __shfl_xor(sr, 1); sr += __shfl_xor(sr, 2);
        sr += __shfl_xor(sr, 4); sr += __shfl_xor(sr, 8);
        dr += __shfl_xor(dr, 1); dr += __shfl_xor(dr, 2);
        dr += __shfl_xor(dr, 4); dr += __shfl_xor(dr, 8);
        if (m == 0 && i < N_) { ssrc[b * N_ + i] = sr; sdst[b * N_ + i] = dr; }
#pragma unroll
        for (int ht = 0; ht < 4; ++ht)
            if (i < N_) xw[((size_t)b * N_ + i) * 64 + ht * 16 + m] = acc3[ht][r];
    }
}

// MFMA flash-style sim + aggregate + FUSED spectral MLP (verified R8)
__global__ __launch_bounds__(256, 3) void k_sim_mfma(
    const ushort_t* __restrict__ gXf, const ushort_t* __restrict__ gXt,
    const ushort_t* __restrict__ gNT,
    const ushort_t* __restrict__ gWs1b, const float* __restrict__ bs1,
    const ushort_t* __restrict__ gWs2b, const float* __restrict__ bs2,
    float* __restrict__ spec)
{
    __shared__ __align__(16) short sXf[64 * 72];
    __shared__ __align__(16) short sXt[64 * 72];
    __shared__ __align__(16) short sNT[64 * 72];
    int tid = threadIdx.x;
    int b = blockIdx.x / 6, itile = blockIdx.x % 6;
    int wv = tid >> 6, l = tid & 63;
    int kg = l >> 4, m = l & 15;
    int i0 = itile * 64;
    const ushort_t* gXfb = gXf + (size_t)b * N_ * 64;
    const ushort_t* gXtb = gXt + (size_t)b * N_ * 64;
    const ushort_t* gNTb = gNT + (size_t)b * 64 * 344;

    int ri = i0 + wv * 16 + m; if (ri > N_ - 1) ri = N_ - 1;
    s16x8 xfiB[2], xtiB[2];
#pragma unroll
    for (int c2 = 0; c2 < 2; ++c2) {
        s16x4 flo = *(const s16x4*)(gXfb + (size_t)ri * 64 + 32 * c2 + 4 * kg);
        s16x4 fhi = *(const s16x4*)(gXfb + (size_t)ri * 64 + 32 * c2 + 16 + 4 * kg);
        s16x4 tlo = *(const s16x4*)(gXtb + (size_t)ri * 64 + 32 * c2 + 4 * kg);
        s16x4 thi = *(const s16x4*)(gXtb + (size_t)ri * 64 + 32 * c2 + 16 + 4 * kg);
        xfiB[c2] = __builtin_shufflevector(flo, fhi, 0, 1, 2, 3, 4, 5, 6, 7);
        xtiB[c2] = __builtin_shufflevector(tlo, thi, 0, 1, 2, 3, 4, 5, 6, 7);
    }

    f32x4 accPV[4];
#pragma unroll
    for (int ht = 0; ht < 4; ++ht) accPV[ht] = (f32x4){0.f, 0.f, 0.f, 0.f};

#pragma unroll 1
    for (int chunk = 0; chunk < 6; ++chunk) {
        int j0 = chunk * 64;
        __syncthreads();
        for (int s = tid; s < 512; s += 256) {
            int row = s >> 3, grp = s & 7;
            int j = j0 + row;
            s16x8 vf = {0, 0, 0, 0, 0, 0, 0, 0};
            s16x8 vt = {0, 0, 0, 0, 0, 0, 0, 0};
            s16x8 vn = {0, 0, 0, 0, 0, 0, 0, 0};
            if (j < N_) {
                vf = *(const s16x8*)(gXfb + (size_t)j * 64 + grp * 8);
                vt = *(const s16x8*)(gXtb + (size_t)j * 64 + grp * 8);
            }
            if (j0 + grp * 8 + 8 <= 344)
                vn = *(const s16x8*)(gNTb + (size_t)row * 344 + j0 + grp * 8);
            *(s16x8*)(&sXf[row * 72 + grp * 8]) = vf;
            *(s16x8*)(&sXt[row * 72 + grp * 8]) = vt;
            *(s16x8*)(&sNT[row * 72 + grp * 8]) = vn;
        }
        __syncthreads();
        int npair = (chunk == 5) ? 1 : 2;
#pragma unroll 1
        for (int pr = 0; pr < npair; ++pr) {
            s16x8 pa;
#pragma unroll
            for (int sub = 0; sub < 2; ++sub) {
                int arow = (pr * 2 + sub) * 16 + m;
                f32x4 sf = (f32x4){0.f, 0.f, 0.f, 0.f};
                f32x4 st = (f32x4){0.f, 0.f, 0.f, 0.f};
#pragma unroll
                for (int hc = 0; hc < 2; ++hc) {
                    int h0 = hc * 32;
                    s16x4 alo = *(const s16x4*)(&sXf[arow * 72 + h0 + 4 * kg]);
                    s16x4 ahi = *(const s16x4*)(&sXf[arow * 72 + h0 + 16 + 4 * kg]);
                    s16x8 av = __builtin_shufflevector(alo, ahi, 0, 1, 2, 3, 4, 5, 6, 7);
                    sf = __builtin_amdgcn_mfma_f32_16x16x32_bf16(av, xfiB[hc], sf, 0, 0, 0);
                    s16x4 blo = *(const s16x4*)(&sXt[arow * 72 + h0 + 4 * kg]);
                    s16x4 bhi = *(const s16x4*)(&sXt[arow * 72 + h0 + 16 + 4 * kg]);
                    s16x8 bv = __builtin_shufflevector(blo, bhi, 0, 1, 2, 3, 4, 5, 6, 7);
                    st = __builtin_amdgcn_mfma_f32_16x16x32_bf16(bv, xtiB[hc], st, 0, 0, 0);
                }
#pragma unroll
                for (int r = 0; r < 4; ++r) {
                    float v = fmaxf(sf[r], st[r]);
                    v = (v > THRESH) ? v : 0.f;
                    pa[sub * 4 + r] = (short)f2bf(v);
                }
            }
            int jl0 = pr * 32;
#pragma unroll
            for (int ht = 0; ht < 4; ++ht) {
                s16x4 nlo = *(const s16x4*)(&sNT[(ht * 16 + m) * 72 + jl0 + 4 * kg]);
                s16x4 nhi = *(const s16x4*)(&sNT[(ht * 16 + m) * 72 + jl0 + 16 + 4 * kg]);
                s16x8 nv = __builtin_shufflevector(nlo, nhi, 0, 1, 2, 3, 4, 5, 6, 7);
                accPV[ht] = __builtin_amdgcn_mfma_f32_16x16x32_bf16(pa, nv, accPV[ht], 0, 0, 0);
            }
        }
    }
    __syncthreads();
    for (int t = tid; t < 64 * 8; t += 256) {
        int row = t >> 3, grp = t & 7;
        *(s16x8*)&sXt[row * 72 + grp * 8] = *(const s16x8*)(gWs1b + row * 64 + grp * 8);
    }
    int R = wv * 16;
#pragma unroll
    for (int ht = 0; ht < 4; ++ht)
#pragma unroll
        for (int r = 0; r < 4; ++r)
            sXf[(R + 4 * kg + r) * 72 + ht * 16 + m] = (short)f2bf(accPV[ht][r]);
    __syncthreads();
    f32x4 h4[4];
#pragma unroll
    for (int ht = 0; ht < 4; ++ht) h4[ht] = (f32x4){0.f, 0.f, 0.f, 0.f};
#pragma unroll
    for (int kc = 0; kc < 2; ++kc) {
        s16x4 alo = *(const s16x4*)&sXf[(R + m) * 72 + kc * 32 + 4 * kg];
        s16x4 ahi = *(const s16x4*)&sXf[(R + m) * 72 + kc * 32 + 16 + 4 * kg];
        s16x8 av = __builtin_shufflevector(alo, ahi, 0, 1, 2, 3, 4, 5, 6, 7);
#pragma unroll
        for (int ht = 0; ht < 4; ++ht) {
            s16x4 blo = *(const s16x4*)&sXt[(ht * 16 + m) * 72 + kc * 32 + 4 * kg];
            s16x4 bhi = *(const s16x4*)&sXt[(ht * 16 + m) * 72 + kc * 32 + 16 + 4 * kg];
            s16x8 bv = __builtin_shufflevector(blo, bhi, 0, 1, 2, 3, 4, 5, 6, 7);
            h4[ht] = __builtin_amdgcn_mfma_f32_16x16x32_bf16(av, bv, h4[ht], 0, 0, 0);
        }
    }
#pragma unroll
    for (int ht = 0; ht < 4; ++ht) {
        float b1 = bs1[ht * 16 + m];
#pragma unroll
        for (int r = 0; r < 4; ++r)
            sNT[(R + 4 * kg + r) * 72 + ht * 16 + m] = (short)f2bf(fmaxf(h4[ht][r] + b1, 0.f));
    }
    __syncthreads();
    for (int t = tid; t < 64 * 8; t += 256) {
        int row = t >> 3, grp = t & 7;
        *(s16x8*)&sXt[row * 72 + grp * 8] = *(const s16x8*)(gWs2b + row * 64 + grp * 8);
    }
    __syncthreads();
    f32x4 sp4[4];
#pragma unroll
    for (int ht = 0; ht < 4; ++ht) sp4[ht] = (f32x4){0.f, 0.f, 0.f, 0.f};
#pragma unroll
    for (int kc = 0; kc < 2; ++kc) {
        s16x4 alo = *(const s16x4*)&sNT[(R + m) * 72 + kc * 32 + 4 * kg];
        s16x4 ahi = *(const s16x4*)&sNT[(R + m) * 72 + kc * 32 + 16 + 4 * kg];
        s16x8 av = __builtin_shufflevector(alo, ahi, 0, 1, 2, 3, 4, 5, 6, 7);
#pragma unroll
        for (int ht = 0; ht < 4; ++ht) {
            s16x4 blo = *(const s16x4*)&sXt[(ht * 16 + m) * 72 + kc * 32 + 4 * kg];
            s16x4 bhi = *(const s16x4*)&sXt[(ht * 16 + m) * 72 + kc * 32 + 16 + 4 * kg];
            s16x8 bv = __builtin_shufflevector(blo, bhi, 0, 1, 2, 3, 4, 5, 6, 7);
            sp4[ht] = __builtin_amdgcn_mfma_f32_16x16x32_bf16(av, bv, sp4[ht], 0, 0, 0);
        }
    }
#pragma unroll
    for (int ht = 0; ht < 4; ++ht) {
        float b2 = bs2[ht * 16 + m];
        float s = 0.f;
#pragma unroll
        for (int r = 0; r < 4; ++r) {
            int i = i0 + R + 4 * kg + r;
            s += (i < N_) ? (sp4[ht][r] + b2) : 0.f;
        }
        s += __shfl_xor(s, 16); s += __shfl_xor(s, 32);
        if (l < 16) atomicAdd(&spec[b * 64 + ht * 16 + m], s);
    }
}

// per-batch: bitonic sort + PARALLEL segmented suffix/prefix weighted scans.
#define NSEG 16
#define SEGSZ 22
__global__ __launch_bounds__(1024) void k_sortscan(
    const float* __restrict__ ssrc, const float* __restrict__ xw,
    float* __restrict__ ssort, float* __restrict__ SufE, float* __restrict__ PreE,
    float* __restrict__ SufD, float* __restrict__ PreD)
{
    __shared__ float sv[512];
    __shared__ int   si[512];
    __shared__ float w1L[344], w2L[344];
    __shared__ float segT[NSEG * 64];
    __shared__ float segD[NSEG];
    int tid = threadIdx.x, b = blockIdx.x;
    for (int q = tid; q < 512; q += 1024) {
        sv[q] = (q < N_) ? ssrc[b * N_ + q] : 3.0e38f;
        si[q] = q;
    }
    __syncthreads();
    for (int k = 2; k <= 512; k <<= 1)
        for (int j = k >> 1; j > 0; j >>= 1) {
            for (int e = tid; e < 512; e += 1024) {
                int l = e ^ j;
                if (l > e) {
                    float a = sv[e], c = sv[l];
                    bool up = ((e & k) == 0);
                    if (up ? (a > c) : (a < c)) {
                        sv[e] = c; sv[l] = a;
                        int t = si[e]; si[e] = si[l]; si[l] = t;
                    }
                }
            }
            __syncthreads();
        }
    if (tid < N_) {
        float v = sv[tid];
        w1L[tid] = __expf(v);
        w2L[tid] = __expf(0.2f * v);
        ssort[(size_t)b * 344 + tid] = v;
    }
    __syncthreads();
    int t = tid >> 6, h = tid & 63;
    int qs = t * SEGSZ, qe = min(qs + SEGSZ, N_);
    const float* xwb = xw + (size_t)b * N_ * 64;
    size_t base = (size_t)b * 344;
    float r = 0.f, rd = 0.f;
    for (int q = qe - 1; q >= qs; --q) {
        float w = w1L[q];
        r += w * xwb[(size_t)si[q] * 64 + h];
        rd += w;
    }
    segT[t * 64 + h] = r; if (h == 0) segD[t] = rd;
    __syncthreads();
    float bsum = 0.f, bden = 0.f;
    for (int t2 = t + 1; t2 < NSEG; ++t2) { bsum += segT[t2 * 64 + h]; bden += segD[t2]; }
    r = bsum; rd = bden;
    for (int q = qe - 1; q >= qs; --q) {
        float w = w1L[q];
        r += w * xwb[(size_t)si[q] * 64 + h];
        rd += w;
        SufE[(base + q) * 64 + h] = r;
        if (h == 0) SufD[base + q] = rd;
    }
    if (t == 0) { SufE[(base + 343) * 64 + h] = 0.f; if (h == 0) SufD[base + 343] = 0.f; }
    __syncthreads();
    r = 0.f; rd = 0.f;
    for (int q = qs; q < qe; ++q) {
        float w = w2L[q];
        r += w * xwb[(size_t)si[q] * 64 + h];
        rd += w;
    }
    segT[t * 64 + h] = r; if (h == 0) segD[t] = rd;
    __syncthreads();
    bsum = 0.f; bden = 0.f;
    for (int t2 = 0; t2 < t; ++t2) { bsum += segT[t2 * 64 + h]; bden += segD[t2]; }
    r = bsum; rd = bden;
    for (int q = qs; q < qe; ++q) {
        PreE[(base + q) * 64 + h] = r;
        if (h == 0) PreD[base + q] = rd;
        float w = w2L[q];
        r += w * xwb[(size_t)si[q] * 64 + h];
        rd += w;
    }
    if (t == NSEG - 1) { PreE[(base + 343) * 64 + h] = r; if (h == 0) PreD[base + 343] = rd; }
}

// GAT finisher: block = (batch, 1/8 of rows). Per-block LDS spatial reduce -> 1 atomic/lane.
// FUSE_XW=1 additionally computes layer-2 xw/ssrc/sdst from y (out1 never materializes).
#define GSEG 8
#define GROWS 43
template <int FUSE_XW>
__global__ __launch_bounds__(256) void k_gatfuse(
    const float* __restrict__ sdst, const float* __restrict__ ssort,
    const float* __restrict__ SufE, const float* __restrict__ PreE,
    const float* __restrict__ SufD, const float* __restrict__ PreD,
    const float* __restrict__ bg, const float* __restrict__ hw, const float* __restrict__ hb,
    const float* __restrict__ WgT, const float* __restrict__ as_, const float* __restrict__ ad_,
    float* __restrict__ xw2, float* __restrict__ ssrc2, float* __restrict__ sdst2,
    float* __restrict__ spatial, int soff)
{
    __shared__ float sW[4096];     // FUSE_XW only
    __shared__ float xs[4][64];
    __shared__ float accL[4][64];
    __shared__ float ssL[344];
    int tid = threadIdx.x, wv = tid >> 6, ln = tid & 63;
    int b = blockIdx.x >> 3, seg = blockIdx.x & 7;
    if (FUSE_XW)
        for (int t = tid; t < 1024; t += 256) ((float4*)sW)[t] = ((const float4*)WgT)[t];
    for (int t = tid; t < N_; t += 256) ssL[t] = ssort[(size_t)b * 344 + t];
    __syncthreads();
    int start = seg * GROWS, end = min(start + GROWS, N_);
    float bgv = bg[ln], hbv = hb[ln];
    int k = ln >> 4;
    float asv = 0.f, adv = 0.f;
    if (FUSE_XW) { asv = as_[ln]; adv = ad_[ln]; }
    float hwr[16];
#pragma unroll
    for (int d = 0; d < 16; ++d) hwr[d] = hw[ln * 16 + d];
    float spacc = 0.f;
    for (int i = start + wv; i < end; i += 4) {
        int idx = b * N_ + i;
        float di = sdst[idx];
        float key = -di;
        int lo = 0, hi = N_;
        while (lo < hi) { int mid = (lo + hi) >> 1; if (ssL[mid] >= key) hi = mid; else lo = mid + 1; }
        int p = lo;
        float ed = __expf(di), e2 = __expf(0.2f * di);
        size_t base = (size_t)b * 344 + p;
        float acc = ed * SufE[base * 64 + ln] + e2 * PreE[base * 64 + ln];
        float den = ed * SufD[base] + e2 * PreD[base];
        float g = acc / den + bgv;
        float y = hbv;
#pragma unroll
        for (int d = 0; d < 16; ++d) y += hwr[d] * __shfl(g, (k << 4) | d);
        float ssum = y * y;
#pragma unroll
        for (int s = 1; s < 64; s <<= 1) ssum += __shfl_xor(ssum, s);
        float rr = 1.f / fmaxf(sqrtf(ssum), 1e-12f);
        y = fmaxf(y * rr, 0.f);
        spacc += y;
        if (FUSE_XW) {
            xs[wv][ln] = y;   // wave-private row; LDS w->r within wave is ordered
            float a0 = 0.f, a1 = 0.f, a2 = 0.f, a3 = 0.f;
#pragma unroll 4
            for (int h = 0; h < 64; h += 4) {
                a0 += xs[wv][h]     * sW[h * 64 + ln];
                a1 += xs[wv][h + 1] * sW[(h + 1) * 64 + ln];
                a2 += xs[wv][h + 2] * sW[(h + 2) * 64 + ln];
                a3 += xs[wv][h + 3] * sW[(h + 3) * 64 + ln];
            }
            float a = (a0 + a1) + (a2 + a3);
            xw2[(size_t)idx * 64 + ln] = a;
            float ps = a * asv, pd = a * adv;
#pragma unroll
            for (int s = 1; s < 64; s <<= 1) { ps += __shfl_xor(ps, s); pd += __shfl_xor(pd, s); }
            if (ln == 0) { ssrc2[idx] = ps; sdst2[idx] = pd; }
        }
    }
    accL[wv][ln] = spacc;
    __syncthreads();
    if (wv == 0) {
        float s = accL[0][ln] + accL[1][ln] + accL[2][ln] + accL[3][ln];
        atomicAdd(&spatial[b * 128 + soff + ln], s);
    }
}

__global__ void k_final(const float* __restrict__ spatial, const float* __restrict__ spectral,
                        const float* __restrict__ Wf, const float* __restrict__ bf_,
                        float* __restrict__ out)
{
    int b = blockIdx.x, ln = threadIdx.x;  // 64 threads
    float inv = 1.f / (float)N_;
    float e0 = spatial[b * 128 + ln] * inv;
    float e1 = spatial[b * 128 + 64 + ln] * inv;
    float e2 = spectral[b * 64 + ln] * inv;
#pragma unroll
    for (int c = 0; c < 2; c++) {
        float a = e0 * Wf[c * 192 + ln] + e1 * Wf[c * 192 + 64 + ln] + e2 * Wf[c * 192 + 128 + ln];
#pragma unroll
        for (int s = 1; s < 64; s <<= 1) a += __shfl_xor(a, s);
        if (ln == 0) out[b * 2 + c] = a + bf_[c];
    }
}

extern "C" void kernel_launch(void* const* d_in, const int* in_sizes, int n_in,
                              void* d_out, int out_size, void* d_ws, size_t ws_size,
                              hipStream_t stream)
{
    const float* reps = (const float*)d_in[0];
    const float* Wm1  = (const float*)d_in[1];
    const float* bm1  = (const float*)d_in[2];
    const float* Wm2  = (const float*)d_in[3];
    const float* bm2  = (const float*)d_in[4];
    const float* Wg1  = (const float*)d_in[5];
    const float* a1s  = (const float*)d_in[6];
    const float* a1d  = (const float*)d_in[7];
    const float* bg1  = (const float*)d_in[8];
    const float* hw1  = (const float*)d_in[9];
    const float* hb1  = (const float*)d_in[10];
    const float* Wg2  = (const float*)d_in[11];
    const float* a2s  = (const float*)d_in[12];
    const float* a2d  = (const float*)d_in[13];
    const float* bg2  = (const float*)d_in[14];
    const float* hw3  = (const float*)d_in[15];
    const float* hb3  = (const float*)d_in[16];
    const float* Ws1  = (const float*)d_in[17];
    const float* bs1  = (const float*)d_in[18];
    const float* Ws2  = (const float*)d_in[19];
    const float* bs2  = (const float*)d_in[20];
    const float* Wf   = (const float*)d_in[21];
    const float* bf_  = (const float*)d_in[22];

    float* ws = (float*)d_ws;
    float* Wg2T = ws + OFF_WG2T;
    ushort_t* gWm1b = (ushort_t*)(ws + OFF_WM1B);
    ushort_t* gWm2b = (ushort_t*)(ws + OFF_WM2B);
    ushort_t* gWg1b = (ushort_t*)(ws + OFF_WG1B);
    ushort_t* gWs1b = (ushort_t*)(ws + OFF_WS1B);
    ushort_t* gWs2b = (ushort_t*)(ws + OFF_WS2B);
    float* spat = ws + OFF_SPAT;
    float* spec = ws + OFF_SPEC;
    float* ssrc = ws + OFF_SSRC;
    float* sdst = ws + OFF_SDST;
    float* ssort= ws + OFF_SSORT;
    float* SufD = ws + OFF_SUFD;
    float* PreD = ws + OFF_PRED;
    float* SufE = ws + OFF_SUFE;
    float* PreE = ws + OFF_PREE;
    float* xwb  = ws + OFF_XW;
    ushort_t* gXf16 = (ushort_t*)(ws + OFF_SUFE);   // dead after k_sim (SufE overwrites)
    ushort_t* gXt16 = (ushort_t*)(ws + OFF_PREE);   // dead after k_sim
    ushort_t* gNT16 = (ushort_t*)(ws + OFF_OUT1);   // dead after k_sim

    hipMemsetAsync(spat, 0, (16384 + 8192) * sizeof(float), stream);
    k_prep<<<32, 256, 0, stream>>>(Wm1, Wm2, Wg1, Wg2, Ws1, Ws2,
                                   Wg2T, gWm1b, gWm2b, gWg1b, gWs1b, gWs2b);
    k_node_mfma<<<B_ * 6, 256, 0, stream>>>(reps, gWm1b, bm1, gWm2b, bm2,
                                            gWg1b, a1s, a1d,
                                            gXf16, gXt16, gNT16, xwb, ssrc, sdst);
    k_sim_mfma<<<B_ * 6, 256, 0, stream>>>(gXf16, gXt16, gNT16,
                                           gWs1b, bs1, gWs2b, bs2, spec);
    // ---- GAT layer 1 (xw/ssrc/sdst from k_node_mfma); fused layer-2 xw ----
    k_sortscan<<<B_, 1024, 0, stream>>>(ssrc, xwb, ssort, SufE, PreE, SufD, PreD);
    k_gatfuse<1><<<B_ * GSEG, 256, 0, stream>>>(sdst, ssort, SufE, PreE, SufD, PreD,
                                                bg1, hw1, hb1, Wg2T, a2s, a2d,
                                                xwb, ssrc, sdst, spat, 0);
    // ---- GAT layer 2 ----
    k_sortscan<<<B_, 1024, 0, stream>>>(ssrc, xwb, ssort, SufE, PreE, SufD, PreD);
    k_gatfuse<0><<<B_ * GSEG, 256, 0, stream>>>(sdst, ssort, SufE, PreE, SufD, PreD,
                                                bg2, hw3, hb3, nullptr, nullptr, nullptr,
                                                nullptr, nullptr, nullptr, spat, 64);
    k_final<<<B_, 64, 0, stream>>>(spat, spec, Wf, bf_, (float*)d_out);
}

// Round 12
// 262.915 us; speedup vs baseline: 4.2712x; 1.0946x over previous
//
#include <hip/hip_runtime.h>
#include <math.h>

#define B_ 128
#define T_ 8
#define P_ 49
#define H_ 64
#define N_ 343
#define THRESH 0.6f
#define NSLOPE 0.2f

typedef float  f32x4  __attribute__((ext_vector_type(4)));
typedef short  s16x4  __attribute__((ext_vector_type(4)));
typedef short  s16x8  __attribute__((ext_vector_type(8)));
typedef unsigned short ushort_t;

// workspace layout (float offsets) — total 14,338,816 floats = 57.4 MB
#define OFF_WG2T 0              // 4096 f32
#define OFF_WM1B 8192           // 8192 bf16 = 4096 floats
#define OFF_WM2B 12288
#define OFF_WG1B 16384
#define OFF_WS1B 20480
#define OFF_WS2B 24576
#define OFF_SPAT 28672          // B*128 spatial mean accumulator
#define OFF_SPEC 45056          // B*64 spectral mean accumulator
#define OFF_SSRC 53248          // B*N
#define OFF_SDST 97152          // B*N
#define OFF_SSORT 141056        // B*344
#define OFF_SUFD 185088         // B*344
#define OFF_PRED 229120         // B*344
#define OFF_SUFE 3083008        // B*344*64   (bf16 Xf16 overlay until k_sortscan L1)
#define OFF_PREE 5901056        // B*344*64   (bf16 Xt16 overlay until k_sortscan L1)
#define OFF_XW   8719104        // B*N*64     (xw f32, L1 by k_node_mfma, L2 by k_gatfuse)
#define OFF_OUT1 11528960       // B*N*64     (bf16 nodeT16 overlay; out1 no longer needed)

__device__ __forceinline__ ushort_t f2bf(float v) {
    union { float f; unsigned int u; } c; c.f = v;
    unsigned int r = c.u + 0x7FFFu + ((c.u >> 16) & 1u);
    return (ushort_t)(r >> 16);
}
__device__ __forceinline__ s16x8 pack8(float4 a, float4 b, float s) {
    s16x8 r;
    r[0] = (short)f2bf(a.x * s); r[1] = (short)f2bf(a.y * s);
    r[2] = (short)f2bf(a.z * s); r[3] = (short)f2bf(a.w * s);
    r[4] = (short)f2bf(b.x * s); r[5] = (short)f2bf(b.y * s);
    r[6] = (short)f2bf(b.z * s); r[7] = (short)f2bf(b.w * s);
    return r;
}
__device__ __forceinline__ float dot4(float4 a) { return a.x*a.x + a.y*a.y + a.z*a.z + a.w*a.w; }

__global__ void k_prep(const float* __restrict__ Wm1, const float* __restrict__ Wm2,
                       const float* __restrict__ Wg1, const float* __restrict__ Wg2,
                       const float* __restrict__ Ws1, const float* __restrict__ Ws2,
                       float* __restrict__ Wg2T,
                       ushort_t* __restrict__ gWm1b, ushort_t* __restrict__ gWm2b,
                       ushort_t* __restrict__ gWg1b, ushort_t* __restrict__ gWs1b,
                       ushort_t* __restrict__ gWs2b) {
    int t = blockIdx.x * 256 + threadIdx.x;
    if (t < 8192) gWm1b[t] = f2bf(Wm1[t]);
    if (t < 4096) {
        int r = t >> 6, c = t & 63;
        Wg2T[c * 64 + r] = Wg2[t];
        gWm2b[t] = f2bf(Wm2[t]);
        gWg1b[t] = f2bf(Wg1[t]);
        gWs1b[t] = f2bf(Ws1[t]);
        gWs2b[t] = f2bf(Ws2[t]);
    }
}

// MFMA node pipeline: cat -> MLP1 -> MLP2 -> xw1 GEMM + attention dots. (verified R8)
#define CATS 136
__global__ __launch_bounds__(256) void k_node_mfma(
    const float* __restrict__ reps,
    const ushort_t* __restrict__ gWm1b, const float* __restrict__ bm1,
    const ushort_t* __restrict__ gWm2b, const float* __restrict__ bm2,
    const ushort_t* __restrict__ gWg1b, const float* __restrict__ a1s, const float* __restrict__ a1d,
    ushort_t* __restrict__ gXf16, ushort_t* __restrict__ gXt16, ushort_t* __restrict__ gNT16,
    float* __restrict__ xw, float* __restrict__ ssrc, float* __restrict__ sdst)
{
    __shared__ __align__(16) ushort_t sCat[64 * CATS];
    __shared__ __align__(16) ushort_t sW1[64 * CATS];
    __shared__ __align__(16) ushort_t sW2[64 * 72];
    __shared__ __align__(16) ushort_t sWg[64 * 72];
    __shared__ __align__(16) ushort_t hL[64 * 72];
    int tid = threadIdx.x;
    int b = blockIdx.x / 6, itile = blockIdx.x % 6;
    int i0 = itile * 64;

    for (int t = tid; t < 64 * 16; t += 256) {
        int row = t >> 4, grp = t & 15;
        *(s16x8*)&sW1[row * CATS + grp * 8] = *(const s16x8*)(gWm1b + row * 128 + grp * 8);
    }
    for (int t = tid; t < 64 * 8; t += 256) {
        int row = t >> 3, grp = t & 7;
        *(s16x8*)&sW2[row * 72 + grp * 8] = *(const s16x8*)(gWm2b + row * 64 + grp * 8);
        *(s16x8*)&sWg[row * 72 + grp * 8] = *(const s16x8*)(gWg1b + row * 64 + grp * 8);
    }
    {
        int r = tid >> 2, slice = tid & 3;
        int n = i0 + r;
        bool valid = n < N_;
        int nn = valid ? n : N_ - 1;
        int f = nn / P_, p = nn - f * P_;
        const float* xfp = reps + (((size_t)b * T_ + f) * P_ + p) * H_ + slice * 16;
        const float* xtp = xfp + P_ * H_;
        float4 f0 = ((const float4*)xfp)[0], f1 = ((const float4*)xfp)[1];
        float4 f2 = ((const float4*)xfp)[2], f3 = ((const float4*)xfp)[3];
        float4 t0 = ((const float4*)xtp)[0], t1 = ((const float4*)xtp)[1];
        float4 t2 = ((const float4*)xtp)[2], t3 = ((const float4*)xtp)[3];
        float sfs = dot4(f0) + dot4(f1) + dot4(f2) + dot4(f3);
        float sts = dot4(t0) + dot4(t1) + dot4(t2) + dot4(t3);
        sfs += __shfl_xor(sfs, 1); sfs += __shfl_xor(sfs, 2);
        sts += __shfl_xor(sts, 1); sts += __shfl_xor(sts, 2);
        float rf = 1.f / (sqrtf(sfs) + 1e-4f);
        float rt = 1.f / (sqrtf(sts) + 1e-4f);
        if (valid) {
            ushort_t* pf = gXf16 + ((size_t)b * N_ + n) * 64 + slice * 16;
            ushort_t* pt = gXt16 + ((size_t)b * N_ + n) * 64 + slice * 16;
            *(s16x8*)pf       = pack8(f0, f1, rf);
            *(s16x8*)(pf + 8) = pack8(f2, f3, rf);
            *(s16x8*)pt       = pack8(t0, t1, rt);
            *(s16x8*)(pt + 8) = pack8(t2, t3, rt);
        }
        *(s16x8*)&sCat[r * CATS + slice * 16]      = pack8(f0, f1, 1.f);
        *(s16x8*)&sCat[r * CATS + slice * 16 + 8]  = pack8(f2, f3, 1.f);
        *(s16x8*)&sCat[r * CATS + 64 + slice * 16]     = pack8(t0, t1, 1.f);
        *(s16x8*)&sCat[r * CATS + 64 + slice * 16 + 8] = pack8(t2, t3, 1.f);
    }
    __syncthreads();

    int w = tid >> 6, l = tid & 63, kg = l >> 4, m = l & 15;
    int R = w * 16;
    f32x4 acc1[4];
#pragma unroll
    for (int ht = 0; ht < 4; ++ht) acc1[ht] = (f32x4){0.f, 0.f, 0.f, 0.f};
#pragma unroll
    for (int kc = 0; kc < 4; ++kc) {
        s16x4 alo = *(const s16x4*)&sCat[(R + m) * CATS + kc * 32 + 4 * kg];
        s16x4 ahi = *(const s16x4*)&sCat[(R + m) * CATS + kc * 32 + 16 + 4 * kg];
        s16x8 av = __builtin_shufflevector(alo, ahi, 0, 1, 2, 3, 4, 5, 6, 7);
#pragma unroll
        for (int ht = 0; ht < 4; ++ht) {
            s16x4 blo = *(const s16x4*)&sW1[(ht * 16 + m) * CATS + kc * 32 + 4 * kg];
            s16x4 bhi = *(const s16x4*)&sW1[(ht * 16 + m) * CATS + kc * 32 + 16 + 4 * kg];
            s16x8 bv = __builtin_shufflevector(blo, bhi, 0, 1, 2, 3, 4, 5, 6, 7);
            acc1[ht] = __builtin_amdgcn_mfma_f32_16x16x32_bf16(av, bv, acc1[ht], 0, 0, 0);
        }
    }
#pragma unroll
    for (int ht = 0; ht < 4; ++ht) {
        float b1 = bm1[ht * 16 + m];
#pragma unroll
        for (int r = 0; r < 4; ++r)
            hL[(R + 4 * kg + r) * 72 + ht * 16 + m] = f2bf(fmaxf(acc1[ht][r] + b1, 0.f));
    }
    __syncthreads();
    f32x4 acc2[4];
#pragma unroll
    for (int ht = 0; ht < 4; ++ht) acc2[ht] = (f32x4){0.f, 0.f, 0.f, 0.f};
#pragma unroll
    for (int kc = 0; kc < 2; ++kc) {
        s16x4 alo = *(const s16x4*)&hL[(R + m) * 72 + kc * 32 + 4 * kg];
        s16x4 ahi = *(const s16x4*)&hL[(R + m) * 72 + kc * 32 + 16 + 4 * kg];
        s16x8 av = __builtin_shufflevector(alo, ahi, 0, 1, 2, 3, 4, 5, 6, 7);
#pragma unroll
        for (int ht = 0; ht < 4; ++ht) {
            s16x4 blo = *(const s16x4*)&sW2[(ht * 16 + m) * 72 + kc * 32 + 4 * kg];
            s16x4 bhi = *(const s16x4*)&sW2[(ht * 16 + m) * 72 + kc * 32 + 16 + 4 * kg];
            s16x8 bv = __builtin_shufflevector(blo, bhi, 0, 1, 2, 3, 4, 5, 6, 7);
            acc2[ht] = __builtin_amdgcn_mfma_f32_16x16x32_bf16(av, bv, acc2[ht], 0, 0, 0);
        }
    }
    __syncthreads();
#pragma unroll
    for (int ht = 0; ht < 4; ++ht) {
        float b2 = bm2[ht * 16 + m];
        int ibase = i0 + R + 4 * kg;
        ushort_t nb[4];
#pragma unroll
        for (int r = 0; r < 4; ++r) {
            nb[r] = f2bf(acc2[ht][r] + b2);
            sCat[(R + 4 * kg + r) * CATS + ht * 16 + m] = nb[r];
        }
        ushort_t* dst = gNT16 + ((size_t)b * 64 + ht * 16 + m) * 344 + ibase;
        if (ibase + 3 < N_) {
            s16x4 v; v[0] = (short)nb[0]; v[1] = (short)nb[1]; v[2] = (short)nb[2]; v[3] = (short)nb[3];
            *(s16x4*)dst = v;
        } else {
#pragma unroll
            for (int r = 0; r < 4; ++r) if (ibase + r < N_) dst[r] = nb[r];
        }
    }
    __syncthreads();
    f32x4 acc3[4];
#pragma unroll
    for (int ht = 0; ht < 4; ++ht) acc3[ht] = (f32x4){0.f, 0.f, 0.f, 0.f};
#pragma unroll
    for (int kc = 0; kc < 2; ++kc) {
        s16x4 alo = *(const s16x4*)&sCat[(R + m) * CATS + kc * 32 + 4 * kg];
        s16x4 ahi = *(const s16x4*)&sCat[(R + m) * CATS + kc * 32 + 16 + 4 * kg];
        s16x8 av = __builtin_shufflevector(alo, ahi, 0, 1, 2, 3, 4, 5, 6, 7);
#pragma unroll
        for (int ht = 0; ht < 4; ++ht) {
            s16x4 blo = *(const s16x4*)&sWg[(ht * 16 + m) * 72 + kc * 32 + 4 * kg];
            s16x4 bhi = *(const s16x4*)&sWg[(ht * 16 + m) * 72 + kc * 32 + 16 + 4 * kg];
            s16x8 bv = __builtin_shufflevector(blo, bhi, 0, 1, 2, 3, 4, 5, 6, 7);
            acc3[ht] = __builtin_amdgcn_mfma_f32_16x16x32_bf16(av, bv, acc3[ht], 0, 0, 0);
        }
    }
    float a1sv[4], a1dv[4];
#pragma unroll
    for (int ht = 0; ht < 4; ++ht) { a1sv[ht] = a1s[ht * 16 + m]; a1dv[ht] = a1d[ht * 16 + m]; }
#pragma unroll
    for (int r = 0; r < 4; ++r) {
        int i = i0 + R + 4 * kg + r;
        float sr = acc3[0][r] * a1sv[0] + acc3[1][r] * a1sv[1] + acc3[2][r] * a1sv[2] + acc3[3][r] * a1sv[3];
        float dr = acc3[0][r] * a1dv[0] + acc3[1][r] * a1dv[1] + acc3[2][r] * a1dv[2] + acc3[3][r] * a1dv[3];
        sr += __shfl_xor(sr, 1); sr += __shfl_xor(sr, 2);
        sr += __shfl_xor(sr, 4); sr += __shfl_xor(sr, 8);
        dr += __shfl_xor(dr, 1); dr += __shfl_xor(dr, 2);
        dr += __shfl_xor(dr, 4); dr += __shfl_xor(dr, 8);
        if (m == 0 && i < N_) { ssrc[b * N_ + i] = sr; sdst[b * N_ + i] = dr; }
#pragma unroll
        for (int ht = 0; ht < 4; ++ht)
            if (i < N_) xw[((size_t)b * N_ + i) * 64 + ht * 16 + m] = acc3[ht][r];
    }
}

// MFMA flash-style sim + aggregate + FUSED spectral MLP (verified R8)
__global__ __launch_bounds__(256, 3) void k_sim_mfma(
    const ushort_t* __restrict__ gXf, const ushort_t* __restrict__ gXt,
    const ushort_t* __restrict__ gNT,
    const ushort_t* __restrict__ gWs1b, const float* __restrict__ bs1,
    const ushort_t* __restrict__ gWs2b, const float* __restrict__ bs2,
    float* __restrict__ spec)
{
    __shared__ __align__(16) short sXf[64 * 72];
    __shared__ __align__(16) short sXt[64 * 72];
    __shared__ __align__(16) short sNT[64 * 72];
    int tid = threadIdx.x;
    int b = blockIdx.x / 6, itile = blockIdx.x % 6;
    int wv = tid >> 6, l = tid & 63;
    int kg = l >> 4, m = l & 15;
    int i0 = itile * 64;
    const ushort_t* gXfb = gXf + (size_t)b * N_ * 64;
    const ushort_t* gXtb = gXt + (size_t)b * N_ * 64;
    const ushort_t* gNTb = gNT + (size_t)b * 64 * 344;

    int ri = i0 + wv * 16 + m; if (ri > N_ - 1) ri = N_ - 1;
    s16x8 xfiB[2], xtiB[2];
#pragma unroll
    for (int c2 = 0; c2 < 2; ++c2) {
        s16x4 flo = *(const s16x4*)(gXfb + (size_t)ri * 64 + 32 * c2 + 4 * kg);
        s16x4 fhi = *(const s16x4*)(gXfb + (size_t)ri * 64 + 32 * c2 + 16 + 4 * kg);
        s16x4 tlo = *(const s16x4*)(gXtb + (size_t)ri * 64 + 32 * c2 + 4 * kg);
        s16x4 thi = *(const s16x4*)(gXtb + (size_t)ri * 64 + 32 * c2 + 16 + 4 * kg);
        xfiB[c2] = __builtin_shufflevector(flo, fhi, 0, 1, 2, 3, 4, 5, 6, 7);
        xtiB[c2] = __builtin_shufflevector(tlo, thi, 0, 1, 2, 3, 4, 5, 6, 7);
    }

    f32x4 accPV[4];
#pragma unroll
    for (int ht = 0; ht < 4; ++ht) accPV[ht] = (f32x4){0.f, 0.f, 0.f, 0.f};

#pragma unroll 1
    for (int chunk = 0; chunk < 6; ++chunk) {
        int j0 = chunk * 64;
        __syncthreads();
        for (int s = tid; s < 512; s += 256) {
            int row = s >> 3, grp = s & 7;
            int j = j0 + row;
            s16x8 vf = {0, 0, 0, 0, 0, 0, 0, 0};
            s16x8 vt = {0, 0, 0, 0, 0, 0, 0, 0};
            s16x8 vn = {0, 0, 0, 0, 0, 0, 0, 0};
            if (j < N_) {
                vf = *(const s16x8*)(gXfb + (size_t)j * 64 + grp * 8);
                vt = *(const s16x8*)(gXtb + (size_t)j * 64 + grp * 8);
            }
            if (j0 + grp * 8 + 8 <= 344)
                vn = *(const s16x8*)(gNTb + (size_t)row * 344 + j0 + grp * 8);
            *(s16x8*)(&sXf[row * 72 + grp * 8]) = vf;
            *(s16x8*)(&sXt[row * 72 + grp * 8]) = vt;
            *(s16x8*)(&sNT[row * 72 + grp * 8]) = vn;
        }
        __syncthreads();
        int npair = (chunk == 5) ? 1 : 2;
#pragma unroll 1
        for (int pr = 0; pr < npair; ++pr) {
            s16x8 pa;
#pragma unroll
            for (int sub = 0; sub < 2; ++sub) {
                int arow = (pr * 2 + sub) * 16 + m;
                f32x4 sf = (f32x4){0.f, 0.f, 0.f, 0.f};
                f32x4 st = (f32x4){0.f, 0.f, 0.f, 0.f};
#pragma unroll
                for (int hc = 0; hc < 2; ++hc) {
                    int h0 = hc * 32;
                    s16x4 alo = *(const s16x4*)(&sXf[arow * 72 + h0 + 4 * kg]);
                    s16x4 ahi = *(const s16x4*)(&sXf[arow * 72 + h0 + 16 + 4 * kg]);
                    s16x8 av = __builtin_shufflevector(alo, ahi, 0, 1, 2, 3, 4, 5, 6, 7);
                    sf = __builtin_amdgcn_mfma_f32_16x16x32_bf16(av, xfiB[hc], sf, 0, 0, 0);
                    s16x4 blo = *(const s16x4*)(&sXt[arow * 72 + h0 + 4 * kg]);
                    s16x4 bhi = *(const s16x4*)(&sXt[arow * 72 + h0 + 16 + 4 * kg]);
                    s16x8 bv = __builtin_shufflevector(blo, bhi, 0, 1, 2, 3, 4, 5, 6, 7);
                    st = __builtin_amdgcn_mfma_f32_16x16x32_bf16(bv, xtiB[hc], st, 0, 0, 0);
                }
#pragma unroll
                for (int r = 0; r < 4; ++r) {
                    float v = fmaxf(sf[r], st[r]);
                    v = (v > THRESH) ? v : 0.f;
                    pa[sub * 4 + r] = (short)f2bf(v);
                }
            }
            int jl0 = pr * 32;
#pragma unroll
            for (int ht = 0; ht < 4; ++ht) {
                s16x4 nlo = *(const s16x4*)(&sNT[(ht * 16 + m) * 72 + jl0 + 4 * kg]);
                s16x4 nhi = *(const s16x4*)(&sNT[(ht * 16 + m) * 72 + jl0 + 16 + 4 * kg]);
                s16x8 nv = __builtin_shufflevector(nlo, nhi, 0, 1, 2, 3, 4, 5, 6, 7);
                accPV[ht] = __builtin_amdgcn_mfma_f32_16x16x32_bf16(pa, nv, accPV[ht], 0, 0, 0);
            }
        }
    }
    __syncthreads();
    for (int t = tid; t < 64 * 8; t += 256) {
        int row = t >> 3, grp = t & 7;
        *(s16x8*)&sXt[row * 72 + grp * 8] = *(const s16x8*)(gWs1b + row * 64 + grp * 8);
    }
    int R = wv * 16;
#pragma unroll
    for (int ht = 0; ht < 4; ++ht)
#pragma unroll
        for (int r = 0; r < 4; ++r)
            sXf[(R + 4 * kg + r) * 72 + ht * 16 + m] = (short)f2bf(accPV[ht][r]);
    __syncthreads();
    f32x4 h4[4];
#pragma unroll
    for (int ht = 0; ht < 4; ++ht) h4[ht] = (f32x4){0.f, 0.f, 0.f, 0.f};
#pragma unroll
    for (int kc = 0; kc < 2; ++kc) {
        s16x4 alo = *(const s16x4*)&sXf[(R + m) * 72 + kc * 32 + 4 * kg];
        s16x4 ahi = *(const s16x4*)&sXf[(R + m) * 72 + kc * 32 + 16 + 4 * kg];
        s16x8 av = __builtin_shufflevector(alo, ahi, 0, 1, 2, 3, 4, 5, 6, 7);
#pragma unroll
        for (int ht = 0; ht < 4; ++ht) {
            s16x4 blo = *(const s16x4*)&sXt[(ht * 16 + m) * 72 + kc * 32 + 4 * kg];
            s16x4 bhi = *(const s16x4*)&sXt[(ht * 16 + m) * 72 + kc * 32 + 16 + 4 * kg];
            s16x8 bv = __builtin_shufflevector(blo, bhi, 0, 1, 2, 3, 4, 5, 6, 7);
            h4[ht] = __builtin_amdgcn_mfma_f32_16x16x32_bf16(av, bv, h4[ht], 0, 0, 0);
        }
    }
#pragma unroll
    for (int ht = 0; ht < 4; ++ht) {
        float b1 = bs1[ht * 16 + m];
#pragma unroll
        for (int r = 0; r < 4; ++r)
            sNT[(R + 4 * kg + r) * 72 + ht * 16 + m] = (short)f2bf(fmaxf(h4[ht][r] + b1, 0.f));
    }
    __syncthreads();
    for (int t = tid; t < 64 * 8; t += 256) {
        int row = t >> 3, grp = t & 7;
        *(s16x8*)&sXt[row * 72 + grp * 8] = *(const s16x8*)(gWs2b + row * 64 + grp * 8);
    }
    __syncthreads();
    f32x4 sp4[4];
#pragma unroll
    for (int ht = 0; ht < 4; ++ht) sp4[ht] = (f32x4){0.f, 0.f, 0.f, 0.f};
#pragma unroll
    for (int kc = 0; kc < 2; ++kc) {
        s16x4 alo = *(const s16x4*)&sNT[(R + m) * 72 + kc * 32 + 4 * kg];
        s16x4 ahi = *(const s16x4*)&sNT[(R + m) * 72 + kc * 32 + 16 + 4 * kg];
        s16x8 av = __builtin_shufflevector(alo, ahi, 0, 1, 2, 3, 4, 5, 6, 7);
#pragma unroll
        for (int ht = 0; ht < 4; ++ht) {
            s16x4 blo = *(const s16x4*)&sXt[(ht * 16 + m) * 72 + kc * 32 + 4 * kg];
            s16x4 bhi = *(const s16x4*)&sXt[(ht * 16 + m) * 72 + kc * 32 + 16 + 4 * kg];
            s16x8 bv = __builtin_shufflevector(blo, bhi, 0, 1, 2, 3, 4, 5, 6, 7);
            sp4[ht] = __builtin_amdgcn_mfma_f32_16x16x32_bf16(av, bv, sp4[ht], 0, 0, 0);
        }
    }
#pragma unroll
    for (int ht = 0; ht < 4; ++ht) {
        float b2 = bs2[ht * 16 + m];
        float s = 0.f;
#pragma unroll
        for (int r = 0; r < 4; ++r) {
            int i = i0 + R + 4 * kg + r;
            s += (i < N_) ? (sp4[ht][r] + b2) : 0.f;
        }
        s += __shfl_xor(s, 16); s += __shfl_xor(s, 32);
        if (l < 16) atomicAdd(&spec[b * 64 + ht * 16 + m], s);
    }
}

// per-batch sort + scans. grid = 2*B: block (b, dir). Sort is duplicated (CUs idle anyway);
// dir=0 does suffix scans (+ ssort store), dir=1 does prefix scans -> 2x scan parallelism.
#define NSEG 16
#define SEGSZ 22
__global__ __launch_bounds__(1024) void k_sortscan(
    const float* __restrict__ ssrc, const float* __restrict__ xw,
    float* __restrict__ ssort, float* __restrict__ SufE, float* __restrict__ PreE,
    float* __restrict__ SufD, float* __restrict__ PreD)
{
    __shared__ float sv[512];
    __shared__ int   si[512];
    __shared__ float wL[344];
    __shared__ float segT[NSEG * 64];
    __shared__ float segD[NSEG];
    int tid = threadIdx.x;
    int b = blockIdx.x >> 1, dir = blockIdx.x & 1;
    for (int q = tid; q < 512; q += 1024) {
        sv[q] = (q < N_) ? ssrc[b * N_ + q] : 3.0e38f;
        si[q] = q;
    }
    __syncthreads();
    for (int k = 2; k <= 512; k <<= 1)
        for (int j = k >> 1; j > 0; j >>= 1) {
            for (int e = tid; e < 512; e += 1024) {
                int l = e ^ j;
                if (l > e) {
                    float a = sv[e], c = sv[l];
                    bool up = ((e & k) == 0);
                    if (up ? (a > c) : (a < c)) {
                        sv[e] = c; sv[l] = a;
                        int t = si[e]; si[e] = si[l]; si[l] = t;
                    }
                }
            }
            __syncthreads();
        }
    if (tid < N_) {
        float v = sv[tid];
        wL[tid] = dir ? __expf(0.2f * v) : __expf(v);
        if (!dir) ssort[(size_t)b * 344 + tid] = v;
    }
    __syncthreads();
    int t = tid >> 6, h = tid & 63;
    int qs = t * SEGSZ, qe = min(qs + SEGSZ, N_);
    const float* xwb = xw + (size_t)b * N_ * 64;
    size_t base = (size_t)b * 344;
    if (dir == 0) {
        // ---- suffix sums with w1 = exp(s) ----
        float r = 0.f, rd = 0.f;
        for (int q = qe - 1; q >= qs; --q) {
            float w = wL[q];
            r += w * xwb[(size_t)si[q] * 64 + h];
            rd += w;
        }
        segT[t * 64 + h] = r; if (h == 0) segD[t] = rd;
        __syncthreads();
        float bsum = 0.f, bden = 0.f;
        for (int t2 = t + 1; t2 < NSEG; ++t2) { bsum += segT[t2 * 64 + h]; bden += segD[t2]; }
        r = bsum; rd = bden;
        for (int q = qe - 1; q >= qs; --q) {
            float w = wL[q];
            r += w * xwb[(size_t)si[q] * 64 + h];
            rd += w;
            SufE[(base + q) * 64 + h] = r;
            if (h == 0) SufD[base + q] = rd;
        }
        if (t == 0) { SufE[(base + 343) * 64 + h] = 0.f; if (h == 0) SufD[base + 343] = 0.f; }
    } else {
        // ---- prefix sums with w2 = exp(0.2 s) ----
        float r = 0.f, rd = 0.f;
        for (int q = qs; q < qe; ++q) {
            float w = wL[q];
            r += w * xwb[(size_t)si[q] * 64 + h];
            rd += w;
        }
        segT[t * 64 + h] = r; if (h == 0) segD[t] = rd;
        __syncthreads();
        float bsum = 0.f, bden = 0.f;
        for (int t2 = 0; t2 < t; ++t2) { bsum += segT[t2 * 64 + h]; bden += segD[t2]; }
        r = bsum; rd = bden;
        for (int q = qs; q < qe; ++q) {
            PreE[(base + q) * 64 + h] = r;
            if (h == 0) PreD[base + q] = rd;
            float w = wL[q];
            r += w * xwb[(size_t)si[q] * 64 + h];
            rd += w;
        }
        if (t == NSEG - 1) { PreE[(base + 343) * 64 + h] = r; if (h == 0) PreD[base + 343] = rd; }
    }
}

// GAT finisher: block = (batch, 1/16 of rows). Binary searches + scalars precomputed
// lane-per-row; main loop is pure coalesced loads + FMA. 1 atomic/lane/block.
#define GSEG 16
#define GROWS 22
template <int FUSE_XW>
__global__ __launch_bounds__(256) void k_gatfuse(
    const float* __restrict__ sdst, const float* __restrict__ ssort,
    const float* __restrict__ SufE, const float* __restrict__ PreE,
    const float* __restrict__ SufD, const float* __restrict__ PreD,
    const float* __restrict__ bg, const float* __restrict__ hw, const float* __restrict__ hb,
    const float* __restrict__ WgT, const float* __restrict__ as_, const float* __restrict__ ad_,
    float* __restrict__ xw2, float* __restrict__ ssrc2, float* __restrict__ sdst2,
    float* __restrict__ spatial, int soff)
{
    __shared__ float sW[4096];     // FUSE_XW only
    __shared__ float xs[4][64];
    __shared__ float accL[4][64];
    __shared__ float ssL[344];
    __shared__ float pEd[GROWS], pE2[GROWS], pInv[GROWS];
    __shared__ int   pP[GROWS];
    int tid = threadIdx.x, wv = tid >> 6, ln = tid & 63;
    int b = blockIdx.x >> 4, seg = blockIdx.x & 15;
    if (FUSE_XW)
        for (int t = tid; t < 1024; t += 256) ((float4*)sW)[t] = ((const float4*)WgT)[t];
    for (int t = tid; t < N_; t += 256) ssL[t] = ssort[(size_t)b * 344 + t];
    __syncthreads();
    int start = seg * GROWS, end = min(start + GROWS, N_);
    int cnt = end - start;
    if (tid < cnt) {   // lane-per-row precompute: search + exp + denominator
        float di = sdst[b * N_ + start + tid];
        float key = -di;
        int lo = 0, hi = N_;
        while (lo < hi) { int mid = (lo + hi) >> 1; if (ssL[mid] >= key) hi = mid; else lo = mid + 1; }
        float ed = __expf(di), e2 = __expf(0.2f * di);
        size_t base = (size_t)b * 344 + lo;
        float den = ed * SufD[base] + e2 * PreD[base];
        pP[tid] = lo; pEd[tid] = ed; pE2[tid] = e2; pInv[tid] = 1.f / den;
    }
    __syncthreads();
    float bgv = bg[ln], hbv = hb[ln];
    int k = ln >> 4;
    float asv = 0.f, adv = 0.f;
    if (FUSE_XW) { asv = as_[ln]; adv = ad_[ln]; }
    float hwr[16];
#pragma unroll
    for (int d = 0; d < 16; ++d) hwr[d] = hw[ln * 16 + d];
    float spacc = 0.f;
    for (int r = wv; r < cnt; r += 4) {
        int i = start + r;
        int idx = b * N_ + i;
        float ed = pEd[r], e2 = pE2[r], inv = pInv[r];
        size_t base = (size_t)b * 344 + pP[r];
        float g = (ed * SufE[base * 64 + ln] + e2 * PreE[base * 64 + ln]) * inv + bgv;
        float y = hbv;
#pragma unroll
        for (int d = 0; d < 16; ++d) y += hwr[d] * __shfl(g, (k << 4) | d);
        float ssum = y * y;
#pragma unroll
        for (int s = 1; s < 64; s <<= 1) ssum += __shfl_xor(ssum, s);
        float rr = 1.f / fmaxf(sqrtf(ssum), 1e-12f);
        y = fmaxf(y * rr, 0.f);
        spacc += y;
        if (FUSE_XW) {
            xs[wv][ln] = y;   // wave-private row; LDS w->r within wave is ordered
            float a0 = 0.f, a1 = 0.f, a2 = 0.f, a3 = 0.f;
#pragma unroll 4
            for (int h = 0; h < 64; h += 4) {
                a0 += xs[wv][h]     * sW[h * 64 + ln];
                a1 += xs[wv][h + 1] * sW[(h + 1) * 64 + ln];
                a2 += xs[wv][h + 2] * sW[(h + 2) * 64 + ln];
                a3 += xs[wv][h + 3] * sW[(h + 3) * 64 + ln];
            }
            float a = (a0 + a1) + (a2 + a3);
            xw2[(size_t)idx * 64 + ln] = a;
            float ps = a * asv, pd = a * adv;
#pragma unroll
            for (int s = 1; s < 64; s <<= 1) { ps += __shfl_xor(ps, s); pd += __shfl_xor(pd, s); }
            if (ln == 0) { ssrc2[idx] = ps; sdst2[idx] = pd; }
        }
    }
    accL[wv][ln] = spacc;
    __syncthreads();
    if (wv == 0) {
        float s = accL[0][ln] + accL[1][ln] + accL[2][ln] + accL[3][ln];
        atomicAdd(&spatial[b * 128 + soff + ln], s);
    }
}

__global__ void k_final(const float* __restrict__ spatial, const float* __restrict__ spectral,
                        const float* __restrict__ Wf, const float* __restrict__ bf_,
                        float* __restrict__ out)
{
    int b = blockIdx.x, ln = threadIdx.x;  // 64 threads
    float inv = 1.f / (float)N_;
    float e0 = spatial[b * 128 + ln] * inv;
    float e1 = spatial[b * 128 + 64 + ln] * inv;
    float e2 = spectral[b * 64 + ln] * inv;
#pragma unroll
    for (int c = 0; c < 2; c++) {
        float a = e0 * Wf[c * 192 + ln] + e1 * Wf[c * 192 + 64 + ln] + e2 * Wf[c * 192 + 128 + ln];
#pragma unroll
        for (int s = 1; s < 64; s <<= 1) a += __shfl_xor(a, s);
        if (ln == 0) out[b * 2 + c] = a + bf_[c];
    }
}

extern "C" void kernel_launch(void* const* d_in, const int* in_sizes, int n_in,
                              void* d_out, int out_size, void* d_ws, size_t ws_size,
                              hipStream_t stream)
{
    const float* reps = (const float*)d_in[0];
    const float* Wm1  = (const float*)d_in[1];
    const float* bm1  = (const float*)d_in[2];
    const float* Wm2  = (const float*)d_in[3];
    const float* bm2  = (const float*)d_in[4];
    const float* Wg1  = (const float*)d_in[5];
    const float* a1s  = (const float*)d_in[6];
    const float* a1d  = (const float*)d_in[7];
    const float* bg1  = (const float*)d_in[8];
    const float* hw1  = (const float*)d_in[9];
    const float* hb1  = (const float*)d_in[10];
    const float* Wg2  = (const float*)d_in[11];
    const float* a2s  = (const float*)d_in[12];
    const float* a2d  = (const float*)d_in[13];
    const float* bg2  = (const float*)d_in[14];
    const float* hw3  = (const float*)d_in[15];
    const float* hb3  = (const float*)d_in[16];
    const float* Ws1  = (const float*)d_in[17];
    const float* bs1  = (const float*)d_in[18];
    const float* Ws2  = (const float*)d_in[19];
    const float* bs2  = (const float*)d_in[20];
    const float* Wf   = (const float*)d_in[21];
    const float* bf_  = (const float*)d_in[22];

    float* ws = (float*)d_ws;
    float* Wg2T = ws + OFF_WG2T;
    ushort_t* gWm1b = (ushort_t*)(ws + OFF_WM1B);
    ushort_t* gWm2b = (ushort_t*)(ws + OFF_WM2B);
    ushort_t* gWg1b = (ushort_t*)(ws + OFF_WG1B);
    ushort_t* gWs1b = (ushort_t*)(ws + OFF_WS1B);
    ushort_t* gWs2b = (ushort_t*)(ws + OFF_WS2B);
    float* spat = ws + OFF_SPAT;
    float* spec = ws + OFF_SPEC;
    float* ssrc = ws + OFF_SSRC;
    float* sdst = ws + OFF_SDST;
    float* ssort= ws + OFF_SSORT;
    float* SufD = ws + OFF_SUFD;
    float* PreD = ws + OFF_PRED;
    float* SufE = ws + OFF_SUFE;
    float* PreE = ws + OFF_PREE;
    float* xwb  = ws + OFF_XW;
    ushort_t* gXf16 = (ushort_t*)(ws + OFF_SUFE);   // dead after k_sim (SufE overwrites)
    ushort_t* gXt16 = (ushort_t*)(ws + OFF_PREE);   // dead after k_sim
    ushort_t* gNT16 = (ushort_t*)(ws + OFF_OUT1);   // dead after k_sim

    hipMemsetAsync(spat, 0, (16384 + 8192) * sizeof(float), stream);
    k_prep<<<32, 256, 0, stream>>>(Wm1, Wm2, Wg1, Wg2, Ws1, Ws2,
                                   Wg2T, gWm1b, gWm2b, gWg1b, gWs1b, gWs2b);
    k_node_mfma<<<B_ * 6, 256, 0, stream>>>(reps, gWm1b, bm1, gWm2b, bm2,
                                            gWg1b, a1s, a1d,
                                            gXf16, gXt16, gNT16, xwb, ssrc, sdst);
    k_sim_mfma<<<B_ * 6, 256, 0, stream>>>(gXf16, gXt16, gNT16,
                                           gWs1b, bs1, gWs2b, bs2, spec);
    // ---- GAT layer 1 (xw/ssrc/sdst from k_node_mfma); fused layer-2 xw ----
    k_sortscan<<<B_ * 2, 1024, 0, stream>>>(ssrc, xwb, ssort, SufE, PreE, SufD, PreD);
    k_gatfuse<1><<<B_ * GSEG, 256, 0, stream>>>(sdst, ssort, SufE, PreE, SufD, PreD,
                                                bg1, hw1, hb1, Wg2T, a2s, a2d,
                                                xwb, ssrc, sdst, spat, 0);
    // ---- GAT layer 2 ----
    k_sortscan<<<B_ * 2, 1024, 0, stream>>>(ssrc, xwb, ssort, SufE, PreE, SufD, PreD);
    k_gatfuse<0><<<B_ * GSEG, 256, 0, stream>>>(sdst, ssort, SufE, PreE, SufD, PreD,
                                                bg2, hw3, hb3, nullptr, nullptr, nullptr,
                                                nullptr, nullptr, nullptr, spat, 64);
    k_final<<<B_, 64, 0, stream>>>(spat, spec, Wf, bf_, (float*)d_out);
}